// Round 10
// baseline (468.927 us; speedup 1.0000x reference)
//
#include <hip/hip_runtime.h>

typedef _Float16 half_t;
typedef _Float16 half8  __attribute__((ext_vector_type(8)));
typedef _Float16 half4v __attribute__((ext_vector_type(4)));
typedef float    f32x4  __attribute__((ext_vector_type(4)));

constexpr int N_NODES = 32768;
constexpr int NPG_    = 512;

#define MFMA16(a, b, c) __builtin_amdgcn_mfma_f32_16x16x32_f16((a), (b), (c), 0, 0, 0)

__device__ __forceinline__ void gload_lds16(const half_t* g, half_t* l) {
  __builtin_amdgcn_global_load_lds(
      (const __attribute__((address_space(1))) void*)g,
      (__attribute__((address_space(3))) void*)l, 16, 0, 0);
}

// ---------------- CSR build ----------------
__global__ void k_hist(const int* __restrict__ dst, int* __restrict__ deg, int E) {
  int i = blockIdx.x * 256 + threadIdx.x;
  if (i < E) atomicAdd(&deg[dst[i]], 1);
}

// scan + self-loop placement fused (thread t already holds rowptr values)
__global__ __launch_bounds__(1024) void k_scan(const int* __restrict__ deg,
                                               int* __restrict__ rowptr,
                                               int* __restrict__ fill,
                                               int* __restrict__ col) {
  __shared__ int part[1024];
  int t = threadIdx.x;
  int base = t * 32;
  int s = 0;
  #pragma unroll
  for (int i = 0; i < 32; i++) s += deg[base + i];
  part[t] = s;
  __syncthreads();
  for (int off = 1; off < 1024; off <<= 1) {
    int add = (t >= off) ? part[t - off] : 0;
    __syncthreads();
    part[t] += add;
    __syncthreads();
  }
  int run = (t == 0) ? 0 : part[t - 1];
  for (int i = 0; i < 32; i++) {
    rowptr[base + i] = run;
    fill[base + i] = 1;          // self-loop occupies slot 0
    col[run] = base + i;
    run += deg[base + i];
  }
  if (t == 1023) rowptr[N_NODES] = run;
}

__global__ void k_scatter(const int* __restrict__ src, const int* __restrict__ dst,
                          const int* __restrict__ rowptr, int* __restrict__ fill,
                          int* __restrict__ col, int E) {
  int i = blockIdx.x * 256 + threadIdx.x;
  if (i < E) {
    int d = dst[i];
    int pos = rowptr[d] + atomicAdd(&fill[d], 1);
    col[pos] = src[i];
  }
}

// ---------------- fused conversions + deg init (one launch) ----------------
__global__ void k_convert(
    const float* __restrict__ x,  half_t* __restrict__ x_h,
    const float* __restrict__ W1, half_t* __restrict__ W1t,
    const float* __restrict__ W2, half_t* __restrict__ W2t,
    const float* __restrict__ W3, half_t* __restrict__ W3t,
    const float* __restrict__ Wi, half_t* __restrict__ Wi_h,
    const float* __restrict__ Wo, half_t* __restrict__ Wo_h,
    int* __restrict__ deg)
{
  int bid = blockIdx.x, t = threadIdx.x;
  if (bid < 16384) {
    int i = bid * 256 + t;
    x_h[i] = (half_t)x[i];
  } else if (bid < 16512) {            // W1t[o*128+k] = W1[k*256+o]
    int i = (bid - 16384) * 256 + t;
    int o = i >> 7, k = i & 127;
    W1t[i] = (half_t)W1[k * 256 + o];
  } else if (bid < 16768) {            // W2t[o*256+k] = W2[k*256+o]
    int i = (bid - 16512) * 256 + t;
    int o = i >> 8, k = i & 255;
    W2t[i] = (half_t)W2[k * 256 + o];
  } else if (bid < 16896) {            // W3t[o*256+k] = W3[k*128+o]
    int i = (bid - 16768) * 256 + t;
    int o = i >> 8, k = i & 255;
    W3t[i] = (half_t)W3[k * 128 + o];
  } else if (bid < 17664) {
    int i = (bid - 16896) * 256 + t;
    Wi_h[i] = (half_t)Wi[i];
  } else if (bid < 17920) {
    int i = (bid - 17664) * 256 + t;
    Wo_h[i] = (half_t)Wo[i];
  } else {
    deg[(bid - 17920) * 256 + t] = 1;  // self-loop counts as 1
  }
}

// ---------------- GEMM + optional fused GAT-score epilogue ----------------
// C[M,Nc] = A[M,K] @ Bt[Nc,K]^T (+bias). BK=64, source-side XOR swizzle.
__global__ __launch_bounds__(256) void k_gemm(
    const half_t* __restrict__ A, const half_t* __restrict__ Bt,
    const float* __restrict__ bias, int bias_per_row,
    half_t* __restrict__ outh, float* __restrict__ outf,
    int M, int Nc, int K,
    const float* __restrict__ aS, const float* __restrict__ aD,
    float* __restrict__ es, float* __restrict__ ed, int H)
{
  __shared__ __align__(16) half_t As[128 * 64];
  __shared__ __align__(16) half_t Bs[128 * 64];
  __shared__ float sRed[2][4][64];     // H==1 cross-wave partials
  int w = threadIdx.x >> 6, lane = threadIdx.x & 63;
  int r = lane & 15, q = lane >> 4;
  int m0 = blockIdx.y * 128, n0 = blockIdx.x * 128;
  int mh = (w & 1) * 64, nh = (w >> 1) * 64;
  f32x4 acc[4][4];
  #pragma unroll
  for (int i = 0; i < 4; i++)
    #pragma unroll
    for (int j = 0; j < 4; j++) acc[i][j] = f32x4{0.f, 0.f, 0.f, 0.f};

  int srow = lane >> 3;          // 0..7 rows per gload
  int sc   = lane & 7;           // 16B chunk slot 0..7

  for (int k0 = 0; k0 < K; k0 += 64) {
    __syncthreads();
    #pragma unroll
    for (int i = 0; i < 4; i++) {
      int R0 = w * 32 + i * 8;
      int row = R0 + srow;
      int cg = sc ^ (row & 7);
      gload_lds16(A  + (size_t)(m0 + row) * K + k0 + cg * 8, &As[R0 * 64]);
      gload_lds16(Bt + (size_t)(n0 + row) * K + k0 + cg * 8, &Bs[R0 * 64]);
    }
    __syncthreads();
    #pragma unroll
    for (int kk = 0; kk < 2; kk++) {
      half8 af[4], bf[4];
      #pragma unroll
      for (int t = 0; t < 4; t++) {
        int rr = mh + t * 16 + r;
        af[t] = *(const half8*)&As[rr * 64 + (((kk * 4 + q) ^ (rr & 7)) << 3)];
      }
      #pragma unroll
      for (int t = 0; t < 4; t++) {
        int rr = nh + t * 16 + r;
        bf[t] = *(const half8*)&Bs[rr * 64 + (((kk * 4 + q) ^ (rr & 7)) << 3)];
      }
      #pragma unroll
      for (int ti = 0; ti < 4; ti++)
        #pragma unroll
        for (int tj = 0; tj < 4; tj++)
          acc[ti][tj] = MFMA16(af[ti], bf[tj], acc[ti][tj]);
    }
  }

  // C store
  #pragma unroll
  for (int tj = 0; tj < 4; tj++) {
    int colc = n0 + nh + tj * 16 + r;
    #pragma unroll
    for (int ti = 0; ti < 4; ti++) {
      #pragma unroll
      for (int i = 0; i < 4; i++) {
        int row = m0 + mh + ti * 16 + q * 4 + i;
        float bv = bias ? (bias_per_row ? bias[row] : bias[colc]) : 0.f;
        float v = acc[ti][tj][i] + bv;
        size_t idx = (size_t)row * Nc + colc;
        if (outf) outf[idx] = v;
        if (outh) outh[idx] = (half_t)v;
      }
    }
  }

  // fused score epilogue
  if (es) {
    if (H == 4) {
      int head = (n0 >> 6) + (nh >> 6);
      float aSv[4], aDv[4];
      #pragma unroll
      for (int tj = 0; tj < 4; tj++) {
        int cl = tj * 16 + r;
        aSv[tj] = aS[head * 64 + cl];
        aDv[tj] = aD[head * 64 + cl];
      }
      #pragma unroll
      for (int ti = 0; ti < 4; ti++) {
        #pragma unroll
        for (int i = 0; i < 4; i++) {
          float ps = 0.f, pd = 0.f;
          #pragma unroll
          for (int tj = 0; tj < 4; tj++) {
            float av = acc[ti][tj][i];
            ps += av * aSv[tj];
            pd += av * aDv[tj];
          }
          #pragma unroll
          for (int off = 1; off < 16; off <<= 1) {
            ps += __shfl_xor(ps, off);
            pd += __shfl_xor(pd, off);
          }
          if (r == 0) {
            int row = m0 + mh + ti * 16 + q * 4 + i;
            es[(size_t)row * 4 + head] = ps;
            ed[(size_t)row * 4 + head] = pd;
          }
        }
      }
    } else {   // H == 1, Nc == 128
      float aSv[4], aDv[4];
      #pragma unroll
      for (int tj = 0; tj < 4; tj++) {
        int c = nh + tj * 16 + r;
        aSv[tj] = aS[c];
        aDv[tj] = aD[c];
      }
      #pragma unroll
      for (int ti = 0; ti < 4; ti++) {
        #pragma unroll
        for (int i = 0; i < 4; i++) {
          float ps = 0.f, pd = 0.f;
          #pragma unroll
          for (int tj = 0; tj < 4; tj++) {
            float av = acc[ti][tj][i];
            ps += av * aSv[tj];
            pd += av * aDv[tj];
          }
          #pragma unroll
          for (int off = 1; off < 16; off <<= 1) {
            ps += __shfl_xor(ps, off);
            pd += __shfl_xor(pd, off);
          }
          if (r == 0) {
            int ri = ti * 16 + q * 4 + i;
            sRed[0][w][ri] = ps;
            sRed[1][w][ri] = pd;
          }
        }
      }
      __syncthreads();
      if (threadIdx.x < 128) {
        int row = threadIdx.x;
        int wlo = row >> 6, ri = row & 63;
        es[m0 + row] = sRed[0][wlo][ri] + sRed[0][wlo + 2][ri];
        ed[m0 + row] = sRed[1][wlo][ri] + sRed[1][wlo + 2][ri];
      }
    }
  }
}

// ---------------- fused Wo-GEMM + residual + LayerNorm ----------------
__global__ __launch_bounds__(256) void k_gemm_ln(
    const half_t* __restrict__ A, const half_t* __restrict__ Bt,
    const float* __restrict__ bias, const half_t* __restrict__ res,
    const float* __restrict__ gamma, const float* __restrict__ beta,
    half_t* __restrict__ outh)
{
  __shared__ __align__(16) half_t As[64 * 64];
  __shared__ __align__(16) half_t Bs[256 * 64];
  __shared__ float sSum[4][64], sSq[4][64];
  __shared__ float sMR[64][2];
  int w = threadIdx.x >> 6, lane = threadIdx.x & 63;
  int r = lane & 15, q = lane >> 4;
  int m0 = blockIdx.x * 64;
  int nh = w * 64;
  f32x4 acc[4][4];
  #pragma unroll
  for (int i = 0; i < 4; i++)
    #pragma unroll
    for (int j = 0; j < 4; j++) acc[i][j] = f32x4{0.f, 0.f, 0.f, 0.f};

  int srow = lane >> 3, sc = lane & 7;

  for (int k0 = 0; k0 < 256; k0 += 64) {
    __syncthreads();
    #pragma unroll
    for (int i = 0; i < 2; i++) {          // As: 64 rows
      int R0 = w * 16 + i * 8;
      int row = R0 + srow;
      int cg = sc ^ (row & 7);
      gload_lds16(A + (size_t)(m0 + row) * 256 + k0 + cg * 8, &As[R0 * 64]);
    }
    #pragma unroll
    for (int i = 0; i < 8; i++) {          // Bs: 256 rows (full Wo)
      int R0 = w * 64 + i * 8;
      int row = R0 + srow;
      int cg = sc ^ (row & 7);
      gload_lds16(Bt + (size_t)row * 256 + k0 + cg * 8, &Bs[R0 * 64]);
    }
    __syncthreads();
    #pragma unroll
    for (int kk = 0; kk < 2; kk++) {
      half8 af[4], bf[4];
      #pragma unroll
      for (int t = 0; t < 4; t++) {
        int rr = t * 16 + r;
        af[t] = *(const half8*)&As[rr * 64 + (((kk * 4 + q) ^ (rr & 7)) << 3)];
      }
      #pragma unroll
      for (int t = 0; t < 4; t++) {
        int rr = nh + t * 16 + r;
        bf[t] = *(const half8*)&Bs[rr * 64 + (((kk * 4 + q) ^ (rr & 7)) << 3)];
      }
      #pragma unroll
      for (int ti = 0; ti < 4; ti++)
        #pragma unroll
        for (int tj = 0; tj < 4; tj++)
          acc[ti][tj] = MFMA16(af[ti], bf[tj], acc[ti][tj]);
    }
  }

  float gv[4], bv[4];
  #pragma unroll
  for (int tj = 0; tj < 4; tj++) {
    int col = nh + tj * 16 + r;
    gv[tj] = gamma[col];
    bv[tj] = beta[col];
  }
  #pragma unroll
  for (int ti = 0; ti < 4; ti++) {
    #pragma unroll
    for (int i = 0; i < 4; i++) {
      int row = ti * 16 + q * 4 + i;
      float s = 0.f, ss = 0.f;
      #pragma unroll
      for (int tj = 0; tj < 4; tj++) {
        int col = nh + tj * 16 + r;
        float v = acc[ti][tj][i] + bias[col]
                + (float)res[(size_t)(m0 + row) * 256 + col];
        acc[ti][tj][i] = v;
        s += v;
        ss += v * v;
      }
      #pragma unroll
      for (int off = 1; off < 16; off <<= 1) {
        s  += __shfl_xor(s, off);
        ss += __shfl_xor(ss, off);
      }
      if (r == 0) { sSum[w][row] = s; sSq[w][row] = ss; }
    }
  }
  __syncthreads();
  if (threadIdx.x < 64) {
    int row = threadIdx.x;
    float s  = sSum[0][row] + sSum[1][row] + sSum[2][row] + sSum[3][row];
    float ss = sSq[0][row] + sSq[1][row] + sSq[2][row] + sSq[3][row];
    float mean = s * (1.f / 256.f);
    float var  = ss * (1.f / 256.f) - mean * mean;
    sMR[row][0] = mean;
    sMR[row][1] = rsqrtf(var + 1e-5f);
  }
  __syncthreads();
  #pragma unroll
  for (int ti = 0; ti < 4; ti++) {
    #pragma unroll
    for (int i = 0; i < 4; i++) {
      int row = ti * 16 + q * 4 + i;
      float mean = sMR[row][0], rstd = sMR[row][1];
      #pragma unroll
      for (int tj = 0; tj < 4; tj++) {
        int col = nh + tj * 16 + r;
        outh[(size_t)(m0 + row) * 256 + col] =
            (half_t)((acc[ti][tj][i] - mean) * rstd * gv[tj] + bv[tj]);
      }
    }
  }
}

// ---------------- edge-softmax aggregation (one wave per dst) ----------------
template<int HC, int H, bool FP16ACC>
__global__ __launch_bounds__(256) void k_agg(
    const half_t* __restrict__ h, const float* __restrict__ es,
    const float* __restrict__ ed, const float* __restrict__ bias,
    const int* __restrict__ rowptr, const int* __restrict__ col, int elu,
    float* __restrict__ outf, half_t* __restrict__ outh)
{
  constexpr int VPT = HC / 16;        // channels per lane (16 or 8)
  constexpr int NV8 = VPT / 8;        // half8 regs per slot (2 or 1)
  constexpr int C = HC / H;
  int lane = threadIdx.x & 63;
  int g = lane >> 4, li = lane & 15;
  int n = blockIdx.x * 4 + (threadIdx.x >> 6);
  int cbase = li * VPT;
  int hl = cbase / C;
  float edn = ed[(size_t)n * H + hl];
  int j0 = rowptr[n], j1 = rowptr[n + 1];
  const half_t* hb = h + cbase;

  float sum0 = 0.f, sum1 = 0.f;

  if constexpr (FP16ACC) {
    half8 acc0[NV8], acc1[NV8];
    #pragma unroll
    for (int i = 0; i < NV8; i++) {
      acc0[i] = half8{0, 0, 0, 0, 0, 0, 0, 0};
      acc1[i] = half8{0, 0, 0, 0, 0, 0, 0, 0};
    }
    for (int j = j0 + g; j < j1; j += 8) {
      int jb = j + 4;
      int s0 = col[j];
      int s1 = col[(jb < j1) ? jb : j];
      float e0 = es[(size_t)s0 * H + hl] + edn;
      e0 = fmaxf(e0, 0.2f * e0);
      float e1 = es[(size_t)s1 * H + hl] + edn;
      e1 = fmaxf(e1, 0.2f * e1);
      e1 = (jb < j1) ? e1 : -1e30f;
      const half_t* hp0 = hb + (size_t)s0 * HC;
      const half_t* hp1 = hb + (size_t)s1 * HC;
      float p0 = exp2f(e0 * 1.44269504f - 8.65617025f);
      float p1 = exp2f(e1 * 1.44269504f - 8.65617025f);
      sum0 += p0; sum1 += p1;
      half_t q0 = (half_t)p0, q1 = (half_t)p1;
      half8 pv0 = {q0, q0, q0, q0, q0, q0, q0, q0};
      half8 pv1 = {q1, q1, q1, q1, q1, q1, q1, q1};
      #pragma unroll
      for (int i = 0; i < NV8; i++) {
        half8 v0 = *(const half8*)(hp0 + i * 8);
        half8 v1 = *(const half8*)(hp1 + i * 8);
        acc0[i] += pv0 * v0;        // v_pk_fma_f16
        acc1[i] += pv1 * v1;
      }
    }
    float sum = sum0 + sum1;
    sum += __shfl_xor(sum, 16);
    sum += __shfl_xor(sum, 32);
    float av[VPT];
    #pragma unroll
    for (int i = 0; i < VPT; i++) {
      av[i] = (float)acc0[i >> 3][i & 7] + (float)acc1[i >> 3][i & 7];
      av[i] += __shfl_xor(av[i], 16);
      av[i] += __shfl_xor(av[i], 32);
    }
    float inv = 1.f / sum;
    float v[VPT];
    #pragma unroll
    for (int i = 0; i < VPT; i++) {
      float t = av[i] * inv + bias[cbase + i];
      if (elu) t = (t > 0.f) ? t : __expf(t) - 1.f;
      v[i] = t;
    }
    if (g == 0) {
      size_t obase = (size_t)n * HC + cbase;
      if (outh) {
        #pragma unroll
        for (int p8 = 0; p8 < NV8; p8++) {
          half8 hv;
          #pragma unroll
          for (int i = 0; i < 8; i++) hv[i] = (half_t)v[p8 * 8 + i];
          *(half8*)(outh + obase + p8 * 8) = hv;
        }
      }
      if (outf) {
        #pragma unroll
        for (int p4 = 0; p4 < VPT / 4; p4++) {
          float4 fv = {v[p4 * 4], v[p4 * 4 + 1], v[p4 * 4 + 2], v[p4 * 4 + 3]};
          *(float4*)(outf + obase + p4 * 4) = fv;
        }
      }
    }
  } else {
    float acc0[VPT], acc1[VPT];
    #pragma unroll
    for (int i = 0; i < VPT; i++) { acc0[i] = 0.f; acc1[i] = 0.f; }
    for (int j = j0 + g; j < j1; j += 8) {
      int jb = j + 4;
      int s0 = col[j];
      int s1 = col[(jb < j1) ? jb : j];
      float e0 = es[(size_t)s0 * H + hl] + edn;
      e0 = fmaxf(e0, 0.2f * e0);
      float e1 = es[(size_t)s1 * H + hl] + edn;
      e1 = fmaxf(e1, 0.2f * e1);
      e1 = (jb < j1) ? e1 : -1e30f;
      const half_t* hp0 = hb + (size_t)s0 * HC;
      const half_t* hp1 = hb + (size_t)s1 * HC;
      float p0 = __expf(e0), p1 = __expf(e1);
      sum0 += p0; sum1 += p1;
      #pragma unroll
      for (int c8 = 0; c8 < NV8; c8++) {
        half8 a0 = *(const half8*)(hp0 + c8 * 8);
        half8 a1 = *(const half8*)(hp1 + c8 * 8);
        #pragma unroll
        for (int i = 0; i < 8; i++) {
          acc0[c8 * 8 + i] += p0 * (float)a0[i];
          acc1[c8 * 8 + i] += p1 * (float)a1[i];
        }
      }
    }
    float sum = sum0 + sum1;
    sum += __shfl_xor(sum, 16);
    sum += __shfl_xor(sum, 32);
    float av[VPT];
    #pragma unroll
    for (int i = 0; i < VPT; i++) {
      av[i] = acc0[i] + acc1[i];
      av[i] += __shfl_xor(av[i], 16);
      av[i] += __shfl_xor(av[i], 32);
    }
    float inv = 1.f / sum;
    float v[VPT];
    #pragma unroll
    for (int i = 0; i < VPT; i++) {
      float t = av[i] * inv + bias[cbase + i];
      if (elu) t = (t > 0.f) ? t : __expf(t) - 1.f;
      v[i] = t;
    }
    if (g == 0) {
      size_t obase = (size_t)n * HC + cbase;
      if (outh) {
        #pragma unroll
        for (int p8 = 0; p8 < NV8; p8++) {
          half8 hv;
          #pragma unroll
          for (int i = 0; i < 8; i++) hv[i] = (half_t)v[p8 * 8 + i];
          *(half8*)(outh + obase + p8 * 8) = hv;
        }
      }
      if (outf) {
        #pragma unroll
        for (int p4 = 0; p4 < VPT / 4; p4++) {
          float4 fv = {v[p4 * 4], v[p4 * 4 + 1], v[p4 * 4 + 2], v[p4 * 4 + 3]};
          *(float4*)(outf + obase + p4 * 4) = fv;
        }
      }
    }
  }
}

// ---------------- MHA core: register-path prefetch, aged staging ----------------
// Block = (pair, 64 q-rows), 2048 blocks; 64-key tiles. Tile kt+1 is loaded
// into REGISTERS at the top of tile kt's compute; by the time the pre-write
// barrier's compiler-emitted vmcnt(0) drain runs, the loads have aged through
// ~1-2k cycles of compute -> no stall (R7-R9 invariance showed the stall was
// the immediate drain of just-issued global_load_lds).
__global__ __launch_bounds__(256) void k_attn(
    const half_t* __restrict__ qk, const half_t* __restrict__ vt,
    half_t* __restrict__ o)
{
  __shared__ __align__(16) half_t Kt[64 * 64];        // K tile [key][64]
  __shared__ __align__(16) half_t Vt[64 * 64];        // V^T tile [d][64 keys]
  __shared__ __align__(16) half_t Pb[4][16][72];      // per-wave P [q][key+pad]

  int pair = blockIdx.x;
  int b = pair >> 2, hh = pair & 3;
  int q0 = blockIdx.y * 64;
  int w = threadIdx.x >> 6, lane = threadIdx.x & 63;
  int cc = lane & 15, qq = lane >> 4;

  const half_t* Qp = qk + ((size_t)(b * NPG_ + q0 + w * 16 + cc) * 512 + hh * 64);
  half8 qa0 = *(const half8*)(Qp + qq * 8);
  half8 qa1 = *(const half8*)(Qp + 32 + qq * 8);

  f32x4 oacc[4];
  #pragma unroll
  for (int t = 0; t < 4; t++) oacc[t] = f32x4{0.f, 0.f, 0.f, 0.f};
  float rs = 0.f;

  const half_t* kb = qk + ((size_t)(b * NPG_) * 512 + 256 + hh * 64);
  const half_t* vb = vt + ((size_t)(hh * 64) * 32768 + b * NPG_);

  // per-lane staging coordinates: 2 slabs of 8 rows; lane -> (row, chunk)
  int krow = lane >> 3, ksl = lane & 7;
  int kr0 = w * 16 + krow, kr1 = w * 16 + 8 + krow;
  int sw0 = (ksl ^ (kr0 & 7)) * 8, sw1 = (ksl ^ (kr1 & 7)) * 8;
  half_t* dK0 = &Kt[(w * 16) * 64 + lane * 8];
  half_t* dK1 = &Kt[(w * 16 + 8) * 64 + lane * 8];
  half_t* dV0 = &Vt[(w * 16) * 64 + lane * 8];
  half_t* dV1 = &Vt[(w * 16 + 8) * 64 + lane * 8];

  // preload tile 0 through registers
  half8 pk0 = *(const half8*)(kb + (size_t)kr0 * 512 + sw0);
  half8 pk1 = *(const half8*)(kb + (size_t)kr1 * 512 + sw1);
  half8 pv0 = *(const half8*)(vb + (size_t)kr0 * 32768 + sw0);
  half8 pv1 = *(const half8*)(vb + (size_t)kr1 * 32768 + sw1);
  *(half8*)dK0 = pk0; *(half8*)dK1 = pk1;
  *(half8*)dV0 = pv0; *(half8*)dV1 = pv1;
  __syncthreads();

  for (int kt = 0; kt < 8; kt++) {
    // prefetch tile kt+1 into registers (ages during compute below)
    if (kt < 7) {
      int kn = (kt + 1) * 64;
      pk0 = *(const half8*)(kb + (size_t)(kn + kr0) * 512 + sw0);
      pk1 = *(const half8*)(kb + (size_t)(kn + kr1) * 512 + sw1);
      pv0 = *(const half8*)(vb + (size_t)kr0 * 32768 + kn + sw0);
      pv1 = *(const half8*)(vb + (size_t)kr1 * 32768 + kn + sw1);
    }

    // S^T = K Q^T ; exp ; pack to wave-private P[q][key] (A-operand layout)
    #pragma unroll
    for (int mt = 0; mt < 4; mt++) {
      int key = mt * 16 + cc;
      half8 k0 = *(const half8*)&Kt[key * 64 + ((qq ^ (key & 7)) << 3)];
      half8 k1 = *(const half8*)&Kt[key * 64 + (((qq + 4) ^ (key & 7)) << 3)];
      f32x4 s = f32x4{0.f, 0.f, 0.f, 0.f};
      s = MFMA16(k0, qa0, s);
      s = MFMA16(k1, qa1, s);
      half4v ph;
      #pragma unroll
      for (int i = 0; i < 4; i++) {
        float p = exp2f(s[i] * 0.180336886f - 11.54156033f);
        rs += p;
        ph[i] = (half_t)p;
      }
      *(half4v*)&Pb[w][cc][mt * 16 + qq * 4] = ph;
    }

    // O += P V
    #pragma unroll
    for (int kc = 0; kc < 2; kc++) {
      half8 a = *(const half8*)&Pb[w][cc][kc * 32 + qq * 8];
      #pragma unroll
      for (int nt = 0; nt < 4; nt++) {
        int d = nt * 16 + cc;
        half8 bb = *(const half8*)&Vt[d * 64 + (((kc * 4 + qq) ^ (d & 7)) << 3)];
        oacc[nt] = MFMA16(a, bb, oacc[nt]);
      }
    }

    if (kt < 7) {
      __syncthreads();                 // all waves done reading tile kt
      *(half8*)dK0 = pk0; *(half8*)dK1 = pk1;   // vmcnt wait here is ~free
      *(half8*)dV0 = pv0; *(half8*)dV1 = pv1;
      __syncthreads();                 // writes visible
    }
  }

  rs += __shfl_xor(rs, 16);
  rs += __shfl_xor(rs, 32);
  #pragma unroll
  for (int i = 0; i < 4; i++) {
    float rsv = __shfl(rs, qq * 4 + i);
    float inv = 1.f / rsv;
    int node = b * NPG_ + q0 + w * 16 + qq * 4 + i;
    #pragma unroll
    for (int nt = 0; nt < 4; nt++)
      o[(size_t)node * 256 + hh * 64 + nt * 16 + cc] = (half_t)(oacc[nt][i] * inv);
  }
}

// ---------------- host ----------------
extern "C" void kernel_launch(void* const* d_in, const int* in_sizes, int n_in,
                              void* d_out, int out_size, void* d_ws, size_t ws_size,
                              hipStream_t stream)
{
  const float* x    = (const float*)d_in[0];
  const int*   ei   = (const int*)d_in[1];
  const float* W1   = (const float*)d_in[3];
  const float* aS1  = (const float*)d_in[4];
  const float* aD1  = (const float*)d_in[5];
  const float* b1   = (const float*)d_in[6];
  const float* W2   = (const float*)d_in[7];
  const float* aS2  = (const float*)d_in[8];
  const float* aD2  = (const float*)d_in[9];
  const float* b2   = (const float*)d_in[10];
  const float* W3   = (const float*)d_in[11];
  const float* aS3  = (const float*)d_in[12];
  const float* aD3  = (const float*)d_in[13];
  const float* b3   = (const float*)d_in[14];
  const float* Wi   = (const float*)d_in[15];
  const float* bi   = (const float*)d_in[16];
  const float* Wo   = (const float*)d_in[17];
  const float* bo   = (const float*)d_in[18];
  const float* gam  = (const float*)d_in[19];
  const float* bet  = (const float*)d_in[20];
  float* out = (float*)d_out;
  const int N = N_NODES;
  int E = in_sizes[1] / 2;

  char* ws = (char*)d_ws;
  size_t off = 0;
  auto alloc = [&](size_t bytes) -> void* {
    void* p = ws + off;
    off = (off + bytes + 255) & ~(size_t)255;
    return p;
  };
  half_t* x_h    = (half_t*)alloc((size_t)N * 128 * 2);
  half_t* h_h    = (half_t*)alloc((size_t)N * 256 * 2);   // h1/h2/h3
  half_t* x1_h   = (half_t*)alloc((size_t)N * 256 * 2);
  half_t* x2_h   = (half_t*)alloc((size_t)N * 256 * 2);
  half_t* qk_h   = (half_t*)alloc((size_t)N * 512 * 2);
  half_t* vt_h   = (half_t*)alloc((size_t)256 * N * 2);   // V^T: [256][32768]
  half_t* o_h    = (half_t*)alloc((size_t)N * 256 * 2);
  half_t* x2a_h  = (half_t*)alloc((size_t)N * 256 * 2);
  half_t* W1t    = (half_t*)alloc(256 * 128 * 2);
  half_t* W2t    = (half_t*)alloc(256 * 256 * 2);
  half_t* W3t    = (half_t*)alloc(128 * 256 * 2);
  half_t* Wi_h   = (half_t*)alloc(768 * 256 * 2);
  half_t* Wo_h   = (half_t*)alloc(256 * 256 * 2);
  float*  es     = (float*) alloc((size_t)N * 4 * 4);
  float*  ed     = (float*) alloc((size_t)N * 4 * 4);
  int*    deg    = (int*)   alloc((size_t)N * 4);
  int*    fill   = (int*)   alloc((size_t)N * 4);
  int*    rowptr = (int*)   alloc(((size_t)N + 1) * 4);
  int*    col    = (int*)   alloc((size_t)(N + E) * 4);

  const int* srcE = ei;
  const int* dstE = ei + E;

  // conversions + deg init (one launch), then CSR (selfloop fused into scan)
  k_convert<<<18048, 256, 0, stream>>>(x, x_h, W1, W1t, W2, W2t, W3, W3t,
                                       Wi, Wi_h, Wo, Wo_h, deg);
  k_hist<<<(E + 255) / 256, 256, 0, stream>>>(dstE, deg, E);
  k_scan<<<1, 1024, 0, stream>>>(deg, rowptr, fill, col);
  k_scatter<<<(E + 255) / 256, 256, 0, stream>>>(srcE, dstE, rowptr, fill, col, E);

  // ---- GAT1: h1 = x @ W1 (+fused es/ed) ; aggregate+ELU -> x1 ----
  k_gemm<<<dim3(2, N / 128), 256, 0, stream>>>(x_h, W1t, nullptr, 0, h_h, nullptr,
                                               N, 256, 128, aS1, aD1, es, ed, 4);
  k_agg<256, 4, true><<<N / 4, 256, 0, stream>>>(h_h, es, ed, b1, rowptr, col, 1, nullptr, x1_h);

  // ---- GAT2 -> x2 (fp16) ----
  k_gemm<<<dim3(2, N / 128), 256, 0, stream>>>(x1_h, W2t, nullptr, 0, h_h, nullptr,
                                               N, 256, 256, aS2, aD2, es, ed, 4);
  k_agg<256, 4, true><<<N / 4, 256, 0, stream>>>(h_h, es, ed, b2, rowptr, col, 1, nullptr, x2_h);

  // ---- MHA ----
  k_gemm<<<dim3(4, N / 128), 256, 0, stream>>>(x2_h, Wi_h, bi, 0, qk_h, nullptr,
                                               N, 512, 256, nullptr, nullptr, nullptr, nullptr, 0);
  k_gemm<<<dim3(N / 128, 2), 256, 0, stream>>>(Wi_h + 512 * 256, x2_h, bi + 512, 1,
                                               vt_h, nullptr, 256, N, 256,
                                               nullptr, nullptr, nullptr, nullptr, 0);
  k_attn<<<dim3(256, 8), 256, 0, stream>>>(qk_h, vt_h, o_h);

  // ---- Wo-GEMM + residual + LayerNorm fused -> x2a (fp16) ----
  k_gemm_ln<<<N / 64, 256, 0, stream>>>(o_h, Wo_h, bo, x2_h, gam, bet, x2a_h);

  // ---- GAT3 (H=1, C=128, fp32 accumulation) -> d_out fp32 ----
  k_gemm<<<dim3(1, N / 128), 256, 0, stream>>>(x2a_h, W3t, nullptr, 0, h_h, nullptr,
                                               N, 128, 256, aS3, aD3, es, ed, 1);
  k_agg<128, 1, false><<<N / 4, 256, 0, stream>>>(h_h, es, ed, b3, rowptr, col, 0, out, nullptr);
}

// Round 11
// 442.331 us; speedup vs baseline: 1.0601x; 1.0601x over previous
//
#include <hip/hip_runtime.h>

typedef _Float16 half_t;
typedef _Float16 half8  __attribute__((ext_vector_type(8)));
typedef _Float16 half4v __attribute__((ext_vector_type(4)));
typedef float    f32x4  __attribute__((ext_vector_type(4)));

constexpr int N_NODES = 32768;
constexpr int NPG_    = 512;

#define MFMA16(a, b, c) __builtin_amdgcn_mfma_f32_16x16x32_f16((a), (b), (c), 0, 0, 0)

__device__ __forceinline__ void gload_lds16(const half_t* g, half_t* l) {
  __builtin_amdgcn_global_load_lds(
      (const __attribute__((address_space(1))) void*)g,
      (__attribute__((address_space(3))) void*)l, 16, 0, 0);
}

// ---------------- CSR build ----------------
__global__ void k_hist(const int* __restrict__ dst, int* __restrict__ deg, int E) {
  int i = blockIdx.x * 256 + threadIdx.x;
  if (i < E) atomicAdd(&deg[dst[i]], 1);
}

// phase 1: per-block (256-elem) exclusive scan + block totals. 128 blocks.
__global__ __launch_bounds__(256) void k_scan1(const int* __restrict__ deg,
                                               int* __restrict__ partial,
                                               int* __restrict__ blockSums) {
  __shared__ int sd[256];
  int t = threadIdx.x;
  int i = blockIdx.x * 256 + t;
  int v = deg[i];
  sd[t] = v;
  __syncthreads();
  int acc = v;
  for (int off = 1; off < 256; off <<= 1) {
    int add = (t >= off) ? sd[t - off] : 0;
    __syncthreads();
    acc += add;
    sd[t] = acc;
    __syncthreads();
  }
  partial[i] = acc - v;                 // exclusive within block
  if (t == 255) blockSums[blockIdx.x] = acc;
}

// phase 2: exclusive scan of 128 block sums (1 tiny block)
__global__ __launch_bounds__(128) void k_scan2(const int* __restrict__ blockSums,
                                               int* __restrict__ blockOff,
                                               int* __restrict__ rowptr) {
  __shared__ int sd[128];
  int t = threadIdx.x;
  int v = blockSums[t];
  sd[t] = v;
  __syncthreads();
  int acc = v;
  for (int off = 1; off < 128; off <<= 1) {
    int add = (t >= off) ? sd[t - off] : 0;
    __syncthreads();
    acc += add;
    sd[t] = acc;
    __syncthreads();
  }
  blockOff[t] = acc - v;                // exclusive
  if (t == 127) rowptr[N_NODES] = acc;  // grand total
}

// phase 3: emit rowptr, fill=1, self-loop in slot 0. 128 blocks.
__global__ __launch_bounds__(256) void k_scan3(const int* __restrict__ partial,
                                               const int* __restrict__ blockOff,
                                               int* __restrict__ rowptr,
                                               int* __restrict__ fill,
                                               int* __restrict__ col) {
  int i = blockIdx.x * 256 + threadIdx.x;
  int rp = partial[i] + blockOff[blockIdx.x];
  rowptr[i] = rp;
  fill[i] = 1;                          // self-loop occupies slot 0
  col[rp] = i;
}

__global__ void k_scatter(const int* __restrict__ src, const int* __restrict__ dst,
                          const int* __restrict__ rowptr, int* __restrict__ fill,
                          int* __restrict__ col, int E) {
  int i = blockIdx.x * 256 + threadIdx.x;
  if (i < E) {
    int d = dst[i];
    int pos = rowptr[d] + atomicAdd(&fill[d], 1);
    col[pos] = src[i];
  }
}

// ---------------- fused conversions + deg init (one launch) ----------------
__global__ void k_convert(
    const float* __restrict__ x,  half_t* __restrict__ x_h,
    const float* __restrict__ W1, half_t* __restrict__ W1t,
    const float* __restrict__ W2, half_t* __restrict__ W2t,
    const float* __restrict__ W3, half_t* __restrict__ W3t,
    const float* __restrict__ Wi, half_t* __restrict__ Wi_h,
    const float* __restrict__ Wo, half_t* __restrict__ Wo_h,
    int* __restrict__ deg)
{
  int bid = blockIdx.x, t = threadIdx.x;
  if (bid < 16384) {
    int i = bid * 256 + t;
    x_h[i] = (half_t)x[i];
  } else if (bid < 16512) {            // W1t[o*128+k] = W1[k*256+o]
    int i = (bid - 16384) * 256 + t;
    int o = i >> 7, k = i & 127;
    W1t[i] = (half_t)W1[k * 256 + o];
  } else if (bid < 16768) {            // W2t[o*256+k] = W2[k*256+o]
    int i = (bid - 16512) * 256 + t;
    int o = i >> 8, k = i & 255;
    W2t[i] = (half_t)W2[k * 256 + o];
  } else if (bid < 16896) {            // W3t[o*256+k] = W3[k*128+o]
    int i = (bid - 16768) * 256 + t;
    int o = i >> 8, k = i & 255;
    W3t[i] = (half_t)W3[k * 128 + o];
  } else if (bid < 17664) {
    int i = (bid - 16896) * 256 + t;
    Wi_h[i] = (half_t)Wi[i];
  } else if (bid < 17920) {
    int i = (bid - 17664) * 256 + t;
    Wo_h[i] = (half_t)Wo[i];
  } else {
    deg[(bid - 17920) * 256 + t] = 1;  // self-loop counts as 1
  }
}

// ---------------- GEMM + optional fused GAT-score epilogue ----------------
// C[M,Nc] = A[M,K] @ Bt[Nc,K]^T (+bias). BK=64, source-side XOR swizzle.
__global__ __launch_bounds__(256) void k_gemm(
    const half_t* __restrict__ A, const half_t* __restrict__ Bt,
    const float* __restrict__ bias, int bias_per_row,
    half_t* __restrict__ outh, float* __restrict__ outf,
    int M, int Nc, int K,
    const float* __restrict__ aS, const float* __restrict__ aD,
    float* __restrict__ es, float* __restrict__ ed, int H)
{
  __shared__ __align__(16) half_t As[128 * 64];
  __shared__ __align__(16) half_t Bs[128 * 64];
  __shared__ float sRed[2][4][64];     // H==1 cross-wave partials
  int w = threadIdx.x >> 6, lane = threadIdx.x & 63;
  int r = lane & 15, q = lane >> 4;
  int m0 = blockIdx.y * 128, n0 = blockIdx.x * 128;
  int mh = (w & 1) * 64, nh = (w >> 1) * 64;
  f32x4 acc[4][4];
  #pragma unroll
  for (int i = 0; i < 4; i++)
    #pragma unroll
    for (int j = 0; j < 4; j++) acc[i][j] = f32x4{0.f, 0.f, 0.f, 0.f};

  int srow = lane >> 3;          // 0..7 rows per gload
  int sc   = lane & 7;           // 16B chunk slot 0..7

  for (int k0 = 0; k0 < K; k0 += 64) {
    __syncthreads();
    #pragma unroll
    for (int i = 0; i < 4; i++) {
      int R0 = w * 32 + i * 8;
      int row = R0 + srow;
      int cg = sc ^ (row & 7);
      gload_lds16(A  + (size_t)(m0 + row) * K + k0 + cg * 8, &As[R0 * 64]);
      gload_lds16(Bt + (size_t)(n0 + row) * K + k0 + cg * 8, &Bs[R0 * 64]);
    }
    __syncthreads();
    #pragma unroll
    for (int kk = 0; kk < 2; kk++) {
      half8 af[4], bf[4];
      #pragma unroll
      for (int t = 0; t < 4; t++) {
        int rr = mh + t * 16 + r;
        af[t] = *(const half8*)&As[rr * 64 + (((kk * 4 + q) ^ (rr & 7)) << 3)];
      }
      #pragma unroll
      for (int t = 0; t < 4; t++) {
        int rr = nh + t * 16 + r;
        bf[t] = *(const half8*)&Bs[rr * 64 + (((kk * 4 + q) ^ (rr & 7)) << 3)];
      }
      #pragma unroll
      for (int ti = 0; ti < 4; ti++)
        #pragma unroll
        for (int tj = 0; tj < 4; tj++)
          acc[ti][tj] = MFMA16(af[ti], bf[tj], acc[ti][tj]);
    }
  }

  // C store
  #pragma unroll
  for (int tj = 0; tj < 4; tj++) {
    int colc = n0 + nh + tj * 16 + r;
    #pragma unroll
    for (int ti = 0; ti < 4; ti++) {
      #pragma unroll
      for (int i = 0; i < 4; i++) {
        int row = m0 + mh + ti * 16 + q * 4 + i;
        float bv = bias ? (bias_per_row ? bias[row] : bias[colc]) : 0.f;
        float v = acc[ti][tj][i] + bv;
        size_t idx = (size_t)row * Nc + colc;
        if (outf) outf[idx] = v;
        if (outh) outh[idx] = (half_t)v;
      }
    }
  }

  // fused score epilogue
  if (es) {
    if (H == 4) {
      int head = (n0 >> 6) + (nh >> 6);
      float aSv[4], aDv[4];
      #pragma unroll
      for (int tj = 0; tj < 4; tj++) {
        int cl = tj * 16 + r;
        aSv[tj] = aS[head * 64 + cl];
        aDv[tj] = aD[head * 64 + cl];
      }
      #pragma unroll
      for (int ti = 0; ti < 4; ti++) {
        #pragma unroll
        for (int i = 0; i < 4; i++) {
          float ps = 0.f, pd = 0.f;
          #pragma unroll
          for (int tj = 0; tj < 4; tj++) {
            float av = acc[ti][tj][i];
            ps += av * aSv[tj];
            pd += av * aDv[tj];
          }
          #pragma unroll
          for (int off = 1; off < 16; off <<= 1) {
            ps += __shfl_xor(ps, off);
            pd += __shfl_xor(pd, off);
          }
          if (r == 0) {
            int row = m0 + mh + ti * 16 + q * 4 + i;
            es[(size_t)row * 4 + head] = ps;
            ed[(size_t)row * 4 + head] = pd;
          }
        }
      }
    } else {   // H == 1, Nc == 128
      float aSv[4], aDv[4];
      #pragma unroll
      for (int tj = 0; tj < 4; tj++) {
        int c = nh + tj * 16 + r;
        aSv[tj] = aS[c];
        aDv[tj] = aD[c];
      }
      #pragma unroll
      for (int ti = 0; ti < 4; ti++) {
        #pragma unroll
        for (int i = 0; i < 4; i++) {
          float ps = 0.f, pd = 0.f;
          #pragma unroll
          for (int tj = 0; tj < 4; tj++) {
            float av = acc[ti][tj][i];
            ps += av * aSv[tj];
            pd += av * aDv[tj];
          }
          #pragma unroll
          for (int off = 1; off < 16; off <<= 1) {
            ps += __shfl_xor(ps, off);
            pd += __shfl_xor(pd, off);
          }
          if (r == 0) {
            int ri = ti * 16 + q * 4 + i;
            sRed[0][w][ri] = ps;
            sRed[1][w][ri] = pd;
          }
        }
      }
      __syncthreads();
      if (threadIdx.x < 128) {
        int row = threadIdx.x;
        int wlo = row >> 6, ri = row & 63;
        es[m0 + row] = sRed[0][wlo][ri] + sRed[0][wlo + 2][ri];
        ed[m0 + row] = sRed[1][wlo][ri] + sRed[1][wlo + 2][ri];
      }
    }
  }
}

// ---------------- fused Wo-GEMM + residual + LayerNorm ----------------
__global__ __launch_bounds__(256) void k_gemm_ln(
    const half_t* __restrict__ A, const half_t* __restrict__ Bt,
    const float* __restrict__ bias, const half_t* __restrict__ res,
    const float* __restrict__ gamma, const float* __restrict__ beta,
    half_t* __restrict__ outh)
{
  __shared__ __align__(16) half_t As[64 * 64];
  __shared__ __align__(16) half_t Bs[256 * 64];
  __shared__ float sSum[4][64], sSq[4][64];
  __shared__ float sMR[64][2];
  int w = threadIdx.x >> 6, lane = threadIdx.x & 63;
  int r = lane & 15, q = lane >> 4;
  int m0 = blockIdx.x * 64;
  int nh = w * 64;
  f32x4 acc[4][4];
  #pragma unroll
  for (int i = 0; i < 4; i++)
    #pragma unroll
    for (int j = 0; j < 4; j++) acc[i][j] = f32x4{0.f, 0.f, 0.f, 0.f};

  int srow = lane >> 3, sc = lane & 7;

  for (int k0 = 0; k0 < 256; k0 += 64) {
    __syncthreads();
    #pragma unroll
    for (int i = 0; i < 2; i++) {          // As: 64 rows
      int R0 = w * 16 + i * 8;
      int row = R0 + srow;
      int cg = sc ^ (row & 7);
      gload_lds16(A + (size_t)(m0 + row) * 256 + k0 + cg * 8, &As[R0 * 64]);
    }
    #pragma unroll
    for (int i = 0; i < 8; i++) {          // Bs: 256 rows (full Wo)
      int R0 = w * 64 + i * 8;
      int row = R0 + srow;
      int cg = sc ^ (row & 7);
      gload_lds16(Bt + (size_t)row * 256 + k0 + cg * 8, &Bs[R0 * 64]);
    }
    __syncthreads();
    #pragma unroll
    for (int kk = 0; kk < 2; kk++) {
      half8 af[4], bf[4];
      #pragma unroll
      for (int t = 0; t < 4; t++) {
        int rr = t * 16 + r;
        af[t] = *(const half8*)&As[rr * 64 + (((kk * 4 + q) ^ (rr & 7)) << 3)];
      }
      #pragma unroll
      for (int t = 0; t < 4; t++) {
        int rr = nh + t * 16 + r;
        bf[t] = *(const half8*)&Bs[rr * 64 + (((kk * 4 + q) ^ (rr & 7)) << 3)];
      }
      #pragma unroll
      for (int ti = 0; ti < 4; ti++)
        #pragma unroll
        for (int tj = 0; tj < 4; tj++)
          acc[ti][tj] = MFMA16(af[ti], bf[tj], acc[ti][tj]);
    }
  }

  float gv[4], bv[4];
  #pragma unroll
  for (int tj = 0; tj < 4; tj++) {
    int col = nh + tj * 16 + r;
    gv[tj] = gamma[col];
    bv[tj] = beta[col];
  }
  #pragma unroll
  for (int ti = 0; ti < 4; ti++) {
    #pragma unroll
    for (int i = 0; i < 4; i++) {
      int row = ti * 16 + q * 4 + i;
      float s = 0.f, ss = 0.f;
      #pragma unroll
      for (int tj = 0; tj < 4; tj++) {
        int col = nh + tj * 16 + r;
        float v = acc[ti][tj][i] + bias[col]
                + (float)res[(size_t)(m0 + row) * 256 + col];
        acc[ti][tj][i] = v;
        s += v;
        ss += v * v;
      }
      #pragma unroll
      for (int off = 1; off < 16; off <<= 1) {
        s  += __shfl_xor(s, off);
        ss += __shfl_xor(ss, off);
      }
      if (r == 0) { sSum[w][row] = s; sSq[w][row] = ss; }
    }
  }
  __syncthreads();
  if (threadIdx.x < 64) {
    int row = threadIdx.x;
    float s  = sSum[0][row] + sSum[1][row] + sSum[2][row] + sSum[3][row];
    float ss = sSq[0][row] + sSq[1][row] + sSq[2][row] + sSq[3][row];
    float mean = s * (1.f / 256.f);
    float var  = ss * (1.f / 256.f) - mean * mean;
    sMR[row][0] = mean;
    sMR[row][1] = rsqrtf(var + 1e-5f);
  }
  __syncthreads();
  #pragma unroll
  for (int ti = 0; ti < 4; ti++) {
    #pragma unroll
    for (int i = 0; i < 4; i++) {
      int row = ti * 16 + q * 4 + i;
      float mean = sMR[row][0], rstd = sMR[row][1];
      #pragma unroll
      for (int tj = 0; tj < 4; tj++) {
        int col = nh + tj * 16 + r;
        outh[(size_t)(m0 + row) * 256 + col] =
            (half_t)((acc[ti][tj][i] - mean) * rstd * gv[tj] + bv[tj]);
      }
    }
  }
}

// ---------------- edge-softmax aggregation (one wave per dst) ----------------
template<int HC, int H, bool FP16ACC>
__global__ __launch_bounds__(256) void k_agg(
    const half_t* __restrict__ h, const float* __restrict__ es,
    const float* __restrict__ ed, const float* __restrict__ bias,
    const int* __restrict__ rowptr, const int* __restrict__ col, int elu,
    float* __restrict__ outf, half_t* __restrict__ outh)
{
  constexpr int VPT = HC / 16;        // channels per lane (16 or 8)
  constexpr int NV8 = VPT / 8;        // half8 regs per slot (2 or 1)
  constexpr int C = HC / H;
  int lane = threadIdx.x & 63;
  int g = lane >> 4, li = lane & 15;
  int n = blockIdx.x * 4 + (threadIdx.x >> 6);
  int cbase = li * VPT;
  int hl = cbase / C;
  float edn = ed[(size_t)n * H + hl];
  int j0 = rowptr[n], j1 = rowptr[n + 1];
  const half_t* hb = h + cbase;

  float sum0 = 0.f, sum1 = 0.f;

  if constexpr (FP16ACC) {
    half8 acc0[NV8], acc1[NV8];
    #pragma unroll
    for (int i = 0; i < NV8; i++) {
      acc0[i] = half8{0, 0, 0, 0, 0, 0, 0, 0};
      acc1[i] = half8{0, 0, 0, 0, 0, 0, 0, 0};
    }
    for (int j = j0 + g; j < j1; j += 8) {
      int jb = j + 4;
      int s0 = col[j];
      int s1 = col[(jb < j1) ? jb : j];
      float e0 = es[(size_t)s0 * H + hl] + edn;
      e0 = fmaxf(e0, 0.2f * e0);
      float e1 = es[(size_t)s1 * H + hl] + edn;
      e1 = fmaxf(e1, 0.2f * e1);
      e1 = (jb < j1) ? e1 : -1e30f;
      const half_t* hp0 = hb + (size_t)s0 * HC;
      const half_t* hp1 = hb + (size_t)s1 * HC;
      float p0 = exp2f(e0 * 1.44269504f - 8.65617025f);
      float p1 = exp2f(e1 * 1.44269504f - 8.65617025f);
      sum0 += p0; sum1 += p1;
      half_t q0 = (half_t)p0, q1 = (half_t)p1;
      half8 pv0 = {q0, q0, q0, q0, q0, q0, q0, q0};
      half8 pv1 = {q1, q1, q1, q1, q1, q1, q1, q1};
      #pragma unroll
      for (int i = 0; i < NV8; i++) {
        half8 v0 = *(const half8*)(hp0 + i * 8);
        half8 v1 = *(const half8*)(hp1 + i * 8);
        acc0[i] += pv0 * v0;        // v_pk_fma_f16
        acc1[i] += pv1 * v1;
      }
    }
    float sum = sum0 + sum1;
    sum += __shfl_xor(sum, 16);
    sum += __shfl_xor(sum, 32);
    float av[VPT];
    #pragma unroll
    for (int i = 0; i < VPT; i++) {
      av[i] = (float)acc0[i >> 3][i & 7] + (float)acc1[i >> 3][i & 7];
      av[i] += __shfl_xor(av[i], 16);
      av[i] += __shfl_xor(av[i], 32);
    }
    float inv = 1.f / sum;
    float v[VPT];
    #pragma unroll
    for (int i = 0; i < VPT; i++) {
      float t = av[i] * inv + bias[cbase + i];
      if (elu) t = (t > 0.f) ? t : __expf(t) - 1.f;
      v[i] = t;
    }
    if (g == 0) {
      size_t obase = (size_t)n * HC + cbase;
      if (outh) {
        #pragma unroll
        for (int p8 = 0; p8 < NV8; p8++) {
          half8 hv;
          #pragma unroll
          for (int i = 0; i < 8; i++) hv[i] = (half_t)v[p8 * 8 + i];
          *(half8*)(outh + obase + p8 * 8) = hv;
        }
      }
      if (outf) {
        #pragma unroll
        for (int p4 = 0; p4 < VPT / 4; p4++) {
          float4 fv = {v[p4 * 4], v[p4 * 4 + 1], v[p4 * 4 + 2], v[p4 * 4 + 3]};
          *(float4*)(outf + obase + p4 * 4) = fv;
        }
      }
    }
  } else {
    float acc0[VPT], acc1[VPT];
    #pragma unroll
    for (int i = 0; i < VPT; i++) { acc0[i] = 0.f; acc1[i] = 0.f; }
    for (int j = j0 + g; j < j1; j += 8) {
      int jb = j + 4;
      int s0 = col[j];
      int s1 = col[(jb < j1) ? jb : j];
      float e0 = es[(size_t)s0 * H + hl] + edn;
      e0 = fmaxf(e0, 0.2f * e0);
      float e1 = es[(size_t)s1 * H + hl] + edn;
      e1 = fmaxf(e1, 0.2f * e1);
      e1 = (jb < j1) ? e1 : -1e30f;
      const half_t* hp0 = hb + (size_t)s0 * HC;
      const half_t* hp1 = hb + (size_t)s1 * HC;
      float p0 = __expf(e0), p1 = __expf(e1);
      sum0 += p0; sum1 += p1;
      #pragma unroll
      for (int c8 = 0; c8 < NV8; c8++) {
        half8 a0 = *(const half8*)(hp0 + c8 * 8);
        half8 a1 = *(const half8*)(hp1 + c8 * 8);
        #pragma unroll
        for (int i = 0; i < 8; i++) {
          acc0[c8 * 8 + i] += p0 * (float)a0[i];
          acc1[c8 * 8 + i] += p1 * (float)a1[i];
        }
      }
    }
    float sum = sum0 + sum1;
    sum += __shfl_xor(sum, 16);
    sum += __shfl_xor(sum, 32);
    float av[VPT];
    #pragma unroll
    for (int i = 0; i < VPT; i++) {
      av[i] = acc0[i] + acc1[i];
      av[i] += __shfl_xor(av[i], 16);
      av[i] += __shfl_xor(av[i], 32);
    }
    float inv = 1.f / sum;
    float v[VPT];
    #pragma unroll
    for (int i = 0; i < VPT; i++) {
      float t = av[i] * inv + bias[cbase + i];
      if (elu) t = (t > 0.f) ? t : __expf(t) - 1.f;
      v[i] = t;
    }
    if (g == 0) {
      size_t obase = (size_t)n * HC + cbase;
      if (outh) {
        #pragma unroll
        for (int p8 = 0; p8 < NV8; p8++) {
          half8 hv;
          #pragma unroll
          for (int i = 0; i < 8; i++) hv[i] = (half_t)v[p8 * 8 + i];
          *(half8*)(outh + obase + p8 * 8) = hv;
        }
      }
      if (outf) {
        #pragma unroll
        for (int p4 = 0; p4 < VPT / 4; p4++) {
          float4 fv = {v[p4 * 4], v[p4 * 4 + 1], v[p4 * 4 + 2], v[p4 * 4 + 3]};
          *(float4*)(outf + obase + p4 * 4) = fv;
        }
      }
    }
  }
}

// ---------------- MHA core (R9 known-good: 64-key tiles, 25 KB LDS) ----------------
__global__ __launch_bounds__(256) void k_attn(
    const half_t* __restrict__ qk, const half_t* __restrict__ vt,
    half_t* __restrict__ o)
{
  __shared__ __align__(16) half_t Kt[64 * 64];        // K tile [key][64]
  __shared__ __align__(16) half_t Vt[64 * 64];        // V^T tile [d][64 keys]
  __shared__ __align__(16) half_t Pb[4][16][72];      // per-wave P [q][key+pad]

  int pair = blockIdx.x;
  int b = pair >> 2, hh = pair & 3;
  int q0 = blockIdx.y * 64;
  int w = threadIdx.x >> 6, lane = threadIdx.x & 63;
  int cc = lane & 15, qq = lane >> 4;

  const half_t* Qp = qk + ((size_t)(b * NPG_ + q0 + w * 16 + cc) * 512 + hh * 64);
  half8 qa0 = *(const half8*)(Qp + qq * 8);
  half8 qa1 = *(const half8*)(Qp + 32 + qq * 8);

  f32x4 oacc[4];
  #pragma unroll
  for (int t = 0; t < 4; t++) oacc[t] = f32x4{0.f, 0.f, 0.f, 0.f};
  float rs = 0.f;

  const half_t* kb = qk + ((size_t)(b * NPG_) * 512 + 256 + hh * 64);
  const half_t* vb = vt + ((size_t)(hh * 64) * 32768 + b * NPG_);

  int krow = lane >> 3, ksl = lane & 7;

  for (int kt = 0; kt < 8; kt++) {
    __syncthreads();
    #pragma unroll
    for (int i = 0; i < 2; i++) {
      int R = w * 16 + i * 8;           // 8-row slab (1 KB) per gload
      int kr = R + krow;
      gload_lds16(kb + (size_t)(kt * 64 + kr) * 512 + ((ksl ^ (kr & 7)) * 8),
                  &Kt[R * 64]);
      gload_lds16(vb + (size_t)kr * 32768 + kt * 64 + ((ksl ^ (kr & 7)) * 8),
                  &Vt[R * 64]);
    }
    __syncthreads();

    // S^T = K Q^T ; exp ; pack to wave-private P[q][key] (A-operand layout)
    #pragma unroll
    for (int mt = 0; mt < 4; mt++) {
      int key = mt * 16 + cc;
      half8 k0 = *(const half8*)&Kt[key * 64 + ((qq ^ (key & 7)) << 3)];
      half8 k1 = *(const half8*)&Kt[key * 64 + (((qq + 4) ^ (key & 7)) << 3)];
      f32x4 s = f32x4{0.f, 0.f, 0.f, 0.f};
      s = MFMA16(k0, qa0, s);
      s = MFMA16(k1, qa1, s);
      half4v ph;
      #pragma unroll
      for (int i = 0; i < 4; i++) {
        float p = exp2f(s[i] * 0.180336886f - 11.54156033f);
        rs += p;
        ph[i] = (half_t)p;
      }
      *(half4v*)&Pb[w][cc][mt * 16 + qq * 4] = ph;
    }

    // O += P V
    #pragma unroll
    for (int kc = 0; kc < 2; kc++) {
      half8 a = *(const half8*)&Pb[w][cc][kc * 32 + qq * 8];
      #pragma unroll
      for (int nt = 0; nt < 4; nt++) {
        int d = nt * 16 + cc;
        half8 bb = *(const half8*)&Vt[d * 64 + (((kc * 4 + qq) ^ (d & 7)) << 3)];
        oacc[nt] = MFMA16(a, bb, oacc[nt]);
      }
    }
  }

  rs += __shfl_xor(rs, 16);
  rs += __shfl_xor(rs, 32);
  #pragma unroll
  for (int i = 0; i < 4; i++) {
    float rsv = __shfl(rs, qq * 4 + i);
    float inv = 1.f / rsv;
    int node = b * NPG_ + q0 + w * 16 + qq * 4 + i;
    #pragma unroll
    for (int nt = 0; nt < 4; nt++)
      o[(size_t)node * 256 + hh * 64 + nt * 16 + cc] = (half_t)(oacc[nt][i] * inv);
  }
}

// ---------------- host ----------------
extern "C" void kernel_launch(void* const* d_in, const int* in_sizes, int n_in,
                              void* d_out, int out_size, void* d_ws, size_t ws_size,
                              hipStream_t stream)
{
  const float* x    = (const float*)d_in[0];
  const int*   ei   = (const int*)d_in[1];
  const float* W1   = (const float*)d_in[3];
  const float* aS1  = (const float*)d_in[4];
  const float* aD1  = (const float*)d_in[5];
  const float* b1   = (const float*)d_in[6];
  const float* W2   = (const float*)d_in[7];
  const float* aS2  = (const float*)d_in[8];
  const float* aD2  = (const float*)d_in[9];
  const float* b2   = (const float*)d_in[10];
  const float* W3   = (const float*)d_in[11];
  const float* aS3  = (const float*)d_in[12];
  const float* aD3  = (const float*)d_in[13];
  const float* b3   = (const float*)d_in[14];
  const float* Wi   = (const float*)d_in[15];
  const float* bi   = (const float*)d_in[16];
  const float* Wo   = (const float*)d_in[17];
  const float* bo   = (const float*)d_in[18];
  const float* gam  = (const float*)d_in[19];
  const float* bet  = (const float*)d_in[20];
  float* out = (float*)d_out;
  const int N = N_NODES;
  int E = in_sizes[1] / 2;

  char* ws = (char*)d_ws;
  size_t off = 0;
  auto alloc = [&](size_t bytes) -> void* {
    void* p = ws + off;
    off = (off + bytes + 255) & ~(size_t)255;
    return p;
  };
  half_t* x_h    = (half_t*)alloc((size_t)N * 128 * 2);
  half_t* h_h    = (half_t*)alloc((size_t)N * 256 * 2);   // h1/h2/h3
  half_t* x1_h   = (half_t*)alloc((size_t)N * 256 * 2);
  half_t* x2_h   = (half_t*)alloc((size_t)N * 256 * 2);
  half_t* qk_h   = (half_t*)alloc((size_t)N * 512 * 2);
  half_t* vt_h   = (half_t*)alloc((size_t)256 * N * 2);   // V^T: [256][32768]
  half_t* o_h    = (half_t*)alloc((size_t)N * 256 * 2);
  half_t* x2a_h  = (half_t*)alloc((size_t)N * 256 * 2);
  half_t* W1t    = (half_t*)alloc(256 * 128 * 2);
  half_t* W2t    = (half_t*)alloc(256 * 256 * 2);
  half_t* W3t    = (half_t*)alloc(128 * 256 * 2);
  half_t* Wi_h   = (half_t*)alloc(768 * 256 * 2);
  half_t* Wo_h   = (half_t*)alloc(256 * 256 * 2);
  float*  es     = (float*) alloc((size_t)N * 4 * 4);
  float*  ed     = (float*) alloc((size_t)N * 4 * 4);
  int*    deg    = (int*)   alloc((size_t)N * 4);
  int*    fill   = (int*)   alloc((size_t)N * 4);
  int*    rowptr = (int*)   alloc(((size_t)N + 1) * 4);
  int*    col    = (int*)   alloc((size_t)(N + E) * 4);
  int*    part   = (int*)   alloc((size_t)N * 4);
  int*    bsum   = (int*)   alloc(128 * 4);
  int*    boff   = (int*)   alloc(128 * 4);

  const int* srcE = ei;
  const int* dstE = ei + E;

  // conversions + deg init (one launch), then parallel CSR build
  k_convert<<<18048, 256, 0, stream>>>(x, x_h, W1, W1t, W2, W2t, W3, W3t,
                                       Wi, Wi_h, Wo, Wo_h, deg);
  k_hist<<<(E + 255) / 256, 256, 0, stream>>>(dstE, deg, E);
  k_scan1<<<128, 256, 0, stream>>>(deg, part, bsum);
  k_scan2<<<1, 128, 0, stream>>>(bsum, boff, rowptr);
  k_scan3<<<128, 256, 0, stream>>>(part, boff, rowptr, fill, col);
  k_scatter<<<(E + 255) / 256, 256, 0, stream>>>(srcE, dstE, rowptr, fill, col, E);

  // ---- GAT1: h1 = x @ W1 (+fused es/ed) ; aggregate+ELU -> x1 ----
  k_gemm<<<dim3(2, N / 128), 256, 0, stream>>>(x_h, W1t, nullptr, 0, h_h, nullptr,
                                               N, 256, 128, aS1, aD1, es, ed, 4);
  k_agg<256, 4, true><<<N / 4, 256, 0, stream>>>(h_h, es, ed, b1, rowptr, col, 1, nullptr, x1_h);

  // ---- GAT2 -> x2 (fp16) ----
  k_gemm<<<dim3(2, N / 128), 256, 0, stream>>>(x1_h, W2t, nullptr, 0, h_h, nullptr,
                                               N, 256, 256, aS2, aD2, es, ed, 4);
  k_agg<256, 4, true><<<N / 4, 256, 0, stream>>>(h_h, es, ed, b2, rowptr, col, 1, nullptr, x2_h);

  // ---- MHA ----
  k_gemm<<<dim3(4, N / 128), 256, 0, stream>>>(x2_h, Wi_h, bi, 0, qk_h, nullptr,
                                               N, 512, 256, nullptr, nullptr, nullptr, nullptr, 0);
  k_gemm<<<dim3(N / 128, 2), 256, 0, stream>>>(Wi_h + 512 * 256, x2_h, bi + 512, 1,
                                               vt_h, nullptr, 256, N, 256,
                                               nullptr, nullptr, nullptr, nullptr, 0);
  k_attn<<<dim3(256, 8), 256, 0, stream>>>(qk_h, vt_h, o_h);

  // ---- Wo-GEMM + residual + LayerNorm fused -> x2a (fp16) ----
  k_gemm_ln<<<N / 64, 256, 0, stream>>>(o_h, Wo_h, bo, x2_h, gam, bet, x2a_h);

  // ---- GAT3 (H=1, C=128, fp32 accumulation) -> d_out fp32 ----
  k_gemm<<<dim3(1, N / 128), 256, 0, stream>>>(x2a_h, W3t, nullptr, 0, h_h, nullptr,
                                               N, 128, 256, aS3, aD3, es, ed, 1);
  k_agg<128, 1, false><<<N / 4, 256, 0, stream>>>(h_h, es, ed, b3, rowptr, col, 0, out, nullptr);
}

// Round 12
// 428.957 us; speedup vs baseline: 1.0932x; 1.0312x over previous
//
#include <hip/hip_runtime.h>

typedef _Float16 half_t;
typedef _Float16 half8  __attribute__((ext_vector_type(8)));
typedef _Float16 half4v __attribute__((ext_vector_type(4)));
typedef float    f32x4  __attribute__((ext_vector_type(4)));

constexpr int N_NODES = 32768;
constexpr int NPG_    = 512;

#define MFMA16(a, b, c) __builtin_amdgcn_mfma_f32_16x16x32_f16((a), (b), (c), 0, 0, 0)

__device__ __forceinline__ void gload_lds16(const half_t* g, half_t* l) {
  __builtin_amdgcn_global_load_lds(
      (const __attribute__((address_space(1))) void*)g,
      (__attribute__((address_space(3))) void*)l, 16, 0, 0);
}

// ---------------- CSR build ----------------
__global__ void k_hist(const int* __restrict__ dst, int* __restrict__ deg, int E) {
  int i = blockIdx.x * 256 + threadIdx.x;
  if (i < E) atomicAdd(&deg[dst[i]], 1);
}

// phase 1: per-block (256-elem) exclusive scan + block totals. 128 blocks.
__global__ __launch_bounds__(256) void k_scan1(const int* __restrict__ deg,
                                               int* __restrict__ partial,
                                               int* __restrict__ blockSums) {
  __shared__ int sd[256];
  int t = threadIdx.x;
  int i = blockIdx.x * 256 + t;
  int v = deg[i];
  sd[t] = v;
  __syncthreads();
  int acc = v;
  for (int off = 1; off < 256; off <<= 1) {
    int add = (t >= off) ? sd[t - off] : 0;
    __syncthreads();
    acc += add;
    sd[t] = acc;
    __syncthreads();
  }
  partial[i] = acc - v;                 // exclusive within block
  if (t == 255) blockSums[blockIdx.x] = acc;
}

// phase 2: exclusive scan of 128 block sums (1 tiny block)
__global__ __launch_bounds__(128) void k_scan2(const int* __restrict__ blockSums,
                                               int* __restrict__ blockOff,
                                               int* __restrict__ rowptr) {
  __shared__ int sd[128];
  int t = threadIdx.x;
  int v = blockSums[t];
  sd[t] = v;
  __syncthreads();
  int acc = v;
  for (int off = 1; off < 128; off <<= 1) {
    int add = (t >= off) ? sd[t - off] : 0;
    __syncthreads();
    acc += add;
    sd[t] = acc;
    __syncthreads();
  }
  blockOff[t] = acc - v;                // exclusive
  if (t == 127) rowptr[N_NODES] = acc;  // grand total
}

// phase 3: emit rowptr, fill=1, self-loop in slot 0. 128 blocks.
__global__ __launch_bounds__(256) void k_scan3(const int* __restrict__ partial,
                                               const int* __restrict__ blockOff,
                                               int* __restrict__ rowptr,
                                               int* __restrict__ fill,
                                               int* __restrict__ col) {
  int i = blockIdx.x * 256 + threadIdx.x;
  int rp = partial[i] + blockOff[blockIdx.x];
  rowptr[i] = rp;
  fill[i] = 1;                          // self-loop occupies slot 0
  col[rp] = i;
}

__global__ void k_scatter(const int* __restrict__ src, const int* __restrict__ dst,
                          const int* __restrict__ rowptr, int* __restrict__ fill,
                          int* __restrict__ col, int E) {
  int i = blockIdx.x * 256 + threadIdx.x;
  if (i < E) {
    int d = dst[i];
    int pos = rowptr[d] + atomicAdd(&fill[d], 1);
    col[pos] = src[i];
  }
}

// ---------------- fused conversions + deg init (one launch) ----------------
__global__ void k_convert(
    const float* __restrict__ x,  half_t* __restrict__ x_h,
    const float* __restrict__ W1, half_t* __restrict__ W1t,
    const float* __restrict__ W2, half_t* __restrict__ W2t,
    const float* __restrict__ W3, half_t* __restrict__ W3t,
    const float* __restrict__ Wi, half_t* __restrict__ Wi_h,
    const float* __restrict__ Wo, half_t* __restrict__ Wo_h,
    int* __restrict__ deg)
{
  int bid = blockIdx.x, t = threadIdx.x;
  if (bid < 16384) {
    int i = bid * 256 + t;
    x_h[i] = (half_t)x[i];
  } else if (bid < 16512) {            // W1t[o*128+k] = W1[k*256+o]
    int i = (bid - 16384) * 256 + t;
    int o = i >> 7, k = i & 127;
    W1t[i] = (half_t)W1[k * 256 + o];
  } else if (bid < 16768) {            // W2t[o*256+k] = W2[k*256+o]
    int i = (bid - 16512) * 256 + t;
    int o = i >> 8, k = i & 255;
    W2t[i] = (half_t)W2[k * 256 + o];
  } else if (bid < 16896) {            // W3t[o*256+k] = W3[k*128+o]
    int i = (bid - 16768) * 256 + t;
    int o = i >> 8, k = i & 255;
    W3t[i] = (half_t)W3[k * 128 + o];
  } else if (bid < 17664) {
    int i = (bid - 16896) * 256 + t;
    Wi_h[i] = (half_t)Wi[i];
  } else if (bid < 17920) {
    int i = (bid - 17664) * 256 + t;
    Wo_h[i] = (half_t)Wo[i];
  } else {
    deg[(bid - 17920) * 256 + t] = 1;  // self-loop counts as 1
  }
}

// ---------------- GEMM + optional fused GAT-score epilogue ----------------
// C[M,Nc] = A[M,K] @ Bt[Nc,K]^T (+bias). BK=64, source-side XOR swizzle.
__global__ __launch_bounds__(256) void k_gemm(
    const half_t* __restrict__ A, const half_t* __restrict__ Bt,
    const float* __restrict__ bias, int bias_per_row,
    half_t* __restrict__ outh, float* __restrict__ outf,
    int M, int Nc, int K,
    const float* __restrict__ aS, const float* __restrict__ aD,
    float* __restrict__ es, float* __restrict__ ed, int H)
{
  __shared__ __align__(16) half_t As[128 * 64];
  __shared__ __align__(16) half_t Bs[128 * 64];
  __shared__ float sRed[2][4][64];     // H==1 cross-wave partials
  int w = threadIdx.x >> 6, lane = threadIdx.x & 63;
  int r = lane & 15, q = lane >> 4;
  int m0 = blockIdx.y * 128, n0 = blockIdx.x * 128;
  int mh = (w & 1) * 64, nh = (w >> 1) * 64;
  f32x4 acc[4][4];
  #pragma unroll
  for (int i = 0; i < 4; i++)
    #pragma unroll
    for (int j = 0; j < 4; j++) acc[i][j] = f32x4{0.f, 0.f, 0.f, 0.f};

  int srow = lane >> 3;          // 0..7 rows per gload
  int sc   = lane & 7;           // 16B chunk slot 0..7

  for (int k0 = 0; k0 < K; k0 += 64) {
    __syncthreads();
    #pragma unroll
    for (int i = 0; i < 4; i++) {
      int R0 = w * 32 + i * 8;
      int row = R0 + srow;
      int cg = sc ^ (row & 7);
      gload_lds16(A  + (size_t)(m0 + row) * K + k0 + cg * 8, &As[R0 * 64]);
      gload_lds16(Bt + (size_t)(n0 + row) * K + k0 + cg * 8, &Bs[R0 * 64]);
    }
    __syncthreads();
    #pragma unroll
    for (int kk = 0; kk < 2; kk++) {
      half8 af[4], bf[4];
      #pragma unroll
      for (int t = 0; t < 4; t++) {
        int rr = mh + t * 16 + r;
        af[t] = *(const half8*)&As[rr * 64 + (((kk * 4 + q) ^ (rr & 7)) << 3)];
      }
      #pragma unroll
      for (int t = 0; t < 4; t++) {
        int rr = nh + t * 16 + r;
        bf[t] = *(const half8*)&Bs[rr * 64 + (((kk * 4 + q) ^ (rr & 7)) << 3)];
      }
      #pragma unroll
      for (int ti = 0; ti < 4; ti++)
        #pragma unroll
        for (int tj = 0; tj < 4; tj++)
          acc[ti][tj] = MFMA16(af[ti], bf[tj], acc[ti][tj]);
    }
  }

  // C store
  #pragma unroll
  for (int tj = 0; tj < 4; tj++) {
    int colc = n0 + nh + tj * 16 + r;
    #pragma unroll
    for (int ti = 0; ti < 4; ti++) {
      #pragma unroll
      for (int i = 0; i < 4; i++) {
        int row = m0 + mh + ti * 16 + q * 4 + i;
        float bv = bias ? (bias_per_row ? bias[row] : bias[colc]) : 0.f;
        float v = acc[ti][tj][i] + bv;
        size_t idx = (size_t)row * Nc + colc;
        if (outf) outf[idx] = v;
        if (outh) outh[idx] = (half_t)v;
      }
    }
  }

  // fused score epilogue
  if (es) {
    if (H == 4) {
      int head = (n0 >> 6) + (nh >> 6);
      float aSv[4], aDv[4];
      #pragma unroll
      for (int tj = 0; tj < 4; tj++) {
        int cl = tj * 16 + r;
        aSv[tj] = aS[head * 64 + cl];
        aDv[tj] = aD[head * 64 + cl];
      }
      #pragma unroll
      for (int ti = 0; ti < 4; ti++) {
        #pragma unroll
        for (int i = 0; i < 4; i++) {
          float ps = 0.f, pd = 0.f;
          #pragma unroll
          for (int tj = 0; tj < 4; tj++) {
            float av = acc[ti][tj][i];
            ps += av * aSv[tj];
            pd += av * aDv[tj];
          }
          #pragma unroll
          for (int off = 1; off < 16; off <<= 1) {
            ps += __shfl_xor(ps, off);
            pd += __shfl_xor(pd, off);
          }
          if (r == 0) {
            int row = m0 + mh + ti * 16 + q * 4 + i;
            es[(size_t)row * 4 + head] = ps;
            ed[(size_t)row * 4 + head] = pd;
          }
        }
      }
    } else {   // H == 1, Nc == 128
      float aSv[4], aDv[4];
      #pragma unroll
      for (int tj = 0; tj < 4; tj++) {
        int c = nh + tj * 16 + r;
        aSv[tj] = aS[c];
        aDv[tj] = aD[c];
      }
      #pragma unroll
      for (int ti = 0; ti < 4; ti++) {
        #pragma unroll
        for (int i = 0; i < 4; i++) {
          float ps = 0.f, pd = 0.f;
          #pragma unroll
          for (int tj = 0; tj < 4; tj++) {
            float av = acc[ti][tj][i];
            ps += av * aSv[tj];
            pd += av * aDv[tj];
          }
          #pragma unroll
          for (int off = 1; off < 16; off <<= 1) {
            ps += __shfl_xor(ps, off);
            pd += __shfl_xor(pd, off);
          }
          if (r == 0) {
            int ri = ti * 16 + q * 4 + i;
            sRed[0][w][ri] = ps;
            sRed[1][w][ri] = pd;
          }
        }
      }
      __syncthreads();
      if (threadIdx.x < 128) {
        int row = threadIdx.x;
        int wlo = row >> 6, ri = row & 63;
        es[m0 + row] = sRed[0][wlo][ri] + sRed[0][wlo + 2][ri];
        ed[m0 + row] = sRed[1][wlo][ri] + sRed[1][wlo + 2][ri];
      }
    }
  }
}

// ---------------- residency-first GEMM (no epilogue): tile 128x64, BK=64 ----------------
// Wave computes 64x32 (acc 4x2). LDS 24 KB, ~80 VGPR -> ~5-6 resident
// blocks/CU; grid 2-8x larger than the 128x128 shape. Built for the skinny
// QKV / V^T GEMMs where the 128x128 kernel is latency-bound at 1-2 blocks/CU.
__global__ __launch_bounds__(256) void k_gemm_wide(
    const half_t* __restrict__ A, const half_t* __restrict__ Bt,
    const float* __restrict__ bias, int bias_per_row,
    half_t* __restrict__ outh, int M, int Nc, int K)
{
  __shared__ __align__(16) half_t As[128 * 64];
  __shared__ __align__(16) half_t Bs[64 * 64];
  int w = threadIdx.x >> 6, lane = threadIdx.x & 63;
  int r = lane & 15, q = lane >> 4;
  int m0 = blockIdx.y * 128, n0 = blockIdx.x * 64;
  int mh = (w & 1) * 64, nh = (w >> 1) * 32;
  f32x4 acc[4][2];
  #pragma unroll
  for (int i = 0; i < 4; i++)
    #pragma unroll
    for (int j = 0; j < 2; j++) acc[i][j] = f32x4{0.f, 0.f, 0.f, 0.f};

  int srow = lane >> 3, sc = lane & 7;

  for (int k0 = 0; k0 < K; k0 += 64) {
    __syncthreads();
    #pragma unroll
    for (int i = 0; i < 4; i++) {          // As: 128 rows, 32/wave
      int R0 = w * 32 + i * 8;
      int row = R0 + srow;
      int cg = sc ^ (row & 7);
      gload_lds16(A + (size_t)(m0 + row) * K + k0 + cg * 8, &As[R0 * 64]);
    }
    #pragma unroll
    for (int i = 0; i < 2; i++) {          // Bs: 64 rows, 16/wave
      int R0 = w * 16 + i * 8;
      int row = R0 + srow;
      int cg = sc ^ (row & 7);
      gload_lds16(Bt + (size_t)(n0 + row) * K + k0 + cg * 8, &Bs[R0 * 64]);
    }
    __syncthreads();
    #pragma unroll
    for (int kk = 0; kk < 2; kk++) {
      half8 af[4], bf[2];
      #pragma unroll
      for (int t = 0; t < 4; t++) {
        int rr = mh + t * 16 + r;
        af[t] = *(const half8*)&As[rr * 64 + (((kk * 4 + q) ^ (rr & 7)) << 3)];
      }
      #pragma unroll
      for (int t = 0; t < 2; t++) {
        int rr = nh + t * 16 + r;
        bf[t] = *(const half8*)&Bs[rr * 64 + (((kk * 4 + q) ^ (rr & 7)) << 3)];
      }
      #pragma unroll
      for (int ti = 0; ti < 4; ti++)
        #pragma unroll
        for (int tj = 0; tj < 2; tj++)
          acc[ti][tj] = MFMA16(af[ti], bf[tj], acc[ti][tj]);
    }
  }

  #pragma unroll
  for (int tj = 0; tj < 2; tj++) {
    int colc = n0 + nh + tj * 16 + r;
    float bc = bias_per_row ? 0.f : bias[colc];
    #pragma unroll
    for (int ti = 0; ti < 4; ti++) {
      #pragma unroll
      for (int i = 0; i < 4; i++) {
        int row = m0 + mh + ti * 16 + q * 4 + i;
        float bv = bias_per_row ? bias[row] : bc;
        outh[(size_t)row * Nc + colc] = (half_t)(acc[ti][tj][i] + bv);
      }
    }
  }
}

// ---------------- fused Wo-GEMM + residual + LayerNorm ----------------
__global__ __launch_bounds__(256) void k_gemm_ln(
    const half_t* __restrict__ A, const half_t* __restrict__ Bt,
    const float* __restrict__ bias, const half_t* __restrict__ res,
    const float* __restrict__ gamma, const float* __restrict__ beta,
    half_t* __restrict__ outh)
{
  __shared__ __align__(16) half_t As[64 * 64];
  __shared__ __align__(16) half_t Bs[256 * 64];
  __shared__ float sSum[4][64], sSq[4][64];
  __shared__ float sMR[64][2];
  int w = threadIdx.x >> 6, lane = threadIdx.x & 63;
  int r = lane & 15, q = lane >> 4;
  int m0 = blockIdx.x * 64;
  int nh = w * 64;
  f32x4 acc[4][4];
  #pragma unroll
  for (int i = 0; i < 4; i++)
    #pragma unroll
    for (int j = 0; j < 4; j++) acc[i][j] = f32x4{0.f, 0.f, 0.f, 0.f};

  int srow = lane >> 3, sc = lane & 7;

  for (int k0 = 0; k0 < 256; k0 += 64) {
    __syncthreads();
    #pragma unroll
    for (int i = 0; i < 2; i++) {          // As: 64 rows
      int R0 = w * 16 + i * 8;
      int row = R0 + srow;
      int cg = sc ^ (row & 7);
      gload_lds16(A + (size_t)(m0 + row) * 256 + k0 + cg * 8, &As[R0 * 64]);
    }
    #pragma unroll
    for (int i = 0; i < 8; i++) {          // Bs: 256 rows (full Wo)
      int R0 = w * 64 + i * 8;
      int row = R0 + srow;
      int cg = sc ^ (row & 7);
      gload_lds16(Bt + (size_t)row * 256 + k0 + cg * 8, &Bs[R0 * 64]);
    }
    __syncthreads();
    #pragma unroll
    for (int kk = 0; kk < 2; kk++) {
      half8 af[4], bf[4];
      #pragma unroll
      for (int t = 0; t < 4; t++) {
        int rr = t * 16 + r;
        af[t] = *(const half8*)&As[rr * 64 + (((kk * 4 + q) ^ (rr & 7)) << 3)];
      }
      #pragma unroll
      for (int t = 0; t < 4; t++) {
        int rr = nh + t * 16 + r;
        bf[t] = *(const half8*)&Bs[rr * 64 + (((kk * 4 + q) ^ (rr & 7)) << 3)];
      }
      #pragma unroll
      for (int ti = 0; ti < 4; ti++)
        #pragma unroll
        for (int tj = 0; tj < 4; tj++)
          acc[ti][tj] = MFMA16(af[ti], bf[tj], acc[ti][tj]);
    }
  }

  float gv[4], bv[4];
  #pragma unroll
  for (int tj = 0; tj < 4; tj++) {
    int col = nh + tj * 16 + r;
    gv[tj] = gamma[col];
    bv[tj] = beta[col];
  }
  #pragma unroll
  for (int ti = 0; ti < 4; ti++) {
    #pragma unroll
    for (int i = 0; i < 4; i++) {
      int row = ti * 16 + q * 4 + i;
      float s = 0.f, ss = 0.f;
      #pragma unroll
      for (int tj = 0; tj < 4; tj++) {
        int col = nh + tj * 16 + r;
        float v = acc[ti][tj][i] + bias[col]
                + (float)res[(size_t)(m0 + row) * 256 + col];
        acc[ti][tj][i] = v;
        s += v;
        ss += v * v;
      }
      #pragma unroll
      for (int off = 1; off < 16; off <<= 1) {
        s  += __shfl_xor(s, off);
        ss += __shfl_xor(ss, off);
      }
      if (r == 0) { sSum[w][row] = s; sSq[w][row] = ss; }
    }
  }
  __syncthreads();
  if (threadIdx.x < 64) {
    int row = threadIdx.x;
    float s  = sSum[0][row] + sSum[1][row] + sSum[2][row] + sSum[3][row];
    float ss = sSq[0][row] + sSq[1][row] + sSq[2][row] + sSq[3][row];
    float mean = s * (1.f / 256.f);
    float var  = ss * (1.f / 256.f) - mean * mean;
    sMR[row][0] = mean;
    sMR[row][1] = rsqrtf(var + 1e-5f);
  }
  __syncthreads();
  #pragma unroll
  for (int ti = 0; ti < 4; ti++) {
    #pragma unroll
    for (int i = 0; i < 4; i++) {
      int row = ti * 16 + q * 4 + i;
      float mean = sMR[row][0], rstd = sMR[row][1];
      #pragma unroll
      for (int tj = 0; tj < 4; tj++) {
        int col = nh + tj * 16 + r;
        outh[(size_t)(m0 + row) * 256 + col] =
            (half_t)((acc[ti][tj][i] - mean) * rstd * gv[tj] + bv[tj]);
      }
    }
  }
}

// ---------------- edge-softmax aggregation (one wave per dst) ----------------
template<int HC, int H, bool FP16ACC>
__global__ __launch_bounds__(256) void k_agg(
    const half_t* __restrict__ h, const float* __restrict__ es,
    const float* __restrict__ ed, const float* __restrict__ bias,
    const int* __restrict__ rowptr, const int* __restrict__ col, int elu,
    float* __restrict__ outf, half_t* __restrict__ outh)
{
  constexpr int VPT = HC / 16;        // channels per lane (16 or 8)
  constexpr int NV8 = VPT / 8;        // half8 regs per slot (2 or 1)
  constexpr int C = HC / H;
  int lane = threadIdx.x & 63;
  int g = lane >> 4, li = lane & 15;
  int n = blockIdx.x * 4 + (threadIdx.x >> 6);
  int cbase = li * VPT;
  int hl = cbase / C;
  float edn = ed[(size_t)n * H + hl];
  int j0 = rowptr[n], j1 = rowptr[n + 1];
  const half_t* hb = h + cbase;

  float sum0 = 0.f, sum1 = 0.f;

  if constexpr (FP16ACC) {
    half8 acc0[NV8], acc1[NV8];
    #pragma unroll
    for (int i = 0; i < NV8; i++) {
      acc0[i] = half8{0, 0, 0, 0, 0, 0, 0, 0};
      acc1[i] = half8{0, 0, 0, 0, 0, 0, 0, 0};
    }
    for (int j = j0 + g; j < j1; j += 8) {
      int jb = j + 4;
      int s0 = col[j];
      int s1 = col[(jb < j1) ? jb : j];
      float e0 = es[(size_t)s0 * H + hl] + edn;
      e0 = fmaxf(e0, 0.2f * e0);
      float e1 = es[(size_t)s1 * H + hl] + edn;
      e1 = fmaxf(e1, 0.2f * e1);
      e1 = (jb < j1) ? e1 : -1e30f;
      const half_t* hp0 = hb + (size_t)s0 * HC;
      const half_t* hp1 = hb + (size_t)s1 * HC;
      float p0 = exp2f(e0 * 1.44269504f - 8.65617025f);
      float p1 = exp2f(e1 * 1.44269504f - 8.65617025f);
      sum0 += p0; sum1 += p1;
      half_t q0 = (half_t)p0, q1 = (half_t)p1;
      half8 pv0 = {q0, q0, q0, q0, q0, q0, q0, q0};
      half8 pv1 = {q1, q1, q1, q1, q1, q1, q1, q1};
      #pragma unroll
      for (int i = 0; i < NV8; i++) {
        half8 v0 = *(const half8*)(hp0 + i * 8);
        half8 v1 = *(const half8*)(hp1 + i * 8);
        acc0[i] += pv0 * v0;        // v_pk_fma_f16
        acc1[i] += pv1 * v1;
      }
    }
    float sum = sum0 + sum1;
    sum += __shfl_xor(sum, 16);
    sum += __shfl_xor(sum, 32);
    float av[VPT];
    #pragma unroll
    for (int i = 0; i < VPT; i++) {
      av[i] = (float)acc0[i >> 3][i & 7] + (float)acc1[i >> 3][i & 7];
      av[i] += __shfl_xor(av[i], 16);
      av[i] += __shfl_xor(av[i], 32);
    }
    float inv = 1.f / sum;
    float v[VPT];
    #pragma unroll
    for (int i = 0; i < VPT; i++) {
      float t = av[i] * inv + bias[cbase + i];
      if (elu) t = (t > 0.f) ? t : __expf(t) - 1.f;
      v[i] = t;
    }
    if (g == 0) {
      size_t obase = (size_t)n * HC + cbase;
      if (outh) {
        #pragma unroll
        for (int p8 = 0; p8 < NV8; p8++) {
          half8 hv;
          #pragma unroll
          for (int i = 0; i < 8; i++) hv[i] = (half_t)v[p8 * 8 + i];
          *(half8*)(outh + obase + p8 * 8) = hv;
        }
      }
      if (outf) {
        #pragma unroll
        for (int p4 = 0; p4 < VPT / 4; p4++) {
          float4 fv = {v[p4 * 4], v[p4 * 4 + 1], v[p4 * 4 + 2], v[p4 * 4 + 3]};
          *(float4*)(outf + obase + p4 * 4) = fv;
        }
      }
    }
  } else {
    float acc0[VPT], acc1[VPT];
    #pragma unroll
    for (int i = 0; i < VPT; i++) { acc0[i] = 0.f; acc1[i] = 0.f; }
    for (int j = j0 + g; j < j1; j += 8) {
      int jb = j + 4;
      int s0 = col[j];
      int s1 = col[(jb < j1) ? jb : j];
      float e0 = es[(size_t)s0 * H + hl] + edn;
      e0 = fmaxf(e0, 0.2f * e0);
      float e1 = es[(size_t)s1 * H + hl] + edn;
      e1 = fmaxf(e1, 0.2f * e1);
      e1 = (jb < j1) ? e1 : -1e30f;
      const half_t* hp0 = hb + (size_t)s0 * HC;
      const half_t* hp1 = hb + (size_t)s1 * HC;
      float p0 = __expf(e0), p1 = __expf(e1);
      sum0 += p0; sum1 += p1;
      #pragma unroll
      for (int c8 = 0; c8 < NV8; c8++) {
        half8 a0 = *(const half8*)(hp0 + c8 * 8);
        half8 a1 = *(const half8*)(hp1 + c8 * 8);
        #pragma unroll
        for (int i = 0; i < 8; i++) {
          acc0[c8 * 8 + i] += p0 * (float)a0[i];
          acc1[c8 * 8 + i] += p1 * (float)a1[i];
        }
      }
    }
    float sum = sum0 + sum1;
    sum += __shfl_xor(sum, 16);
    sum += __shfl_xor(sum, 32);
    float av[VPT];
    #pragma unroll
    for (int i = 0; i < VPT; i++) {
      av[i] = acc0[i] + acc1[i];
      av[i] += __shfl_xor(av[i], 16);
      av[i] += __shfl_xor(av[i], 32);
    }
    float inv = 1.f / sum;
    float v[VPT];
    #pragma unroll
    for (int i = 0; i < VPT; i++) {
      float t = av[i] * inv + bias[cbase + i];
      if (elu) t = (t > 0.f) ? t : __expf(t) - 1.f;
      v[i] = t;
    }
    if (g == 0) {
      size_t obase = (size_t)n * HC + cbase;
      if (outh) {
        #pragma unroll
        for (int p8 = 0; p8 < NV8; p8++) {
          half8 hv;
          #pragma unroll
          for (int i = 0; i < 8; i++) hv[i] = (half_t)v[p8 * 8 + i];
          *(half8*)(outh + obase + p8 * 8) = hv;
        }
      }
      if (outf) {
        #pragma unroll
        for (int p4 = 0; p4 < VPT / 4; p4++) {
          float4 fv = {v[p4 * 4], v[p4 * 4 + 1], v[p4 * 4 + 2], v[p4 * 4 + 3]};
          *(float4*)(outf + obase + p4 * 4) = fv;
        }
      }
    }
  }
}

// ---------------- MHA core (R9 known-good: 64-key tiles, 25 KB LDS) ----------------
__global__ __launch_bounds__(256) void k_attn(
    const half_t* __restrict__ qk, const half_t* __restrict__ vt,
    half_t* __restrict__ o)
{
  __shared__ __align__(16) half_t Kt[64 * 64];        // K tile [key][64]
  __shared__ __align__(16) half_t Vt[64 * 64];        // V^T tile [d][64 keys]
  __shared__ __align__(16) half_t Pb[4][16][72];      // per-wave P [q][key+pad]

  int pair = blockIdx.x;
  int b = pair >> 2, hh = pair & 3;
  int q0 = blockIdx.y * 64;
  int w = threadIdx.x >> 6, lane = threadIdx.x & 63;
  int cc = lane & 15, qq = lane >> 4;

  const half_t* Qp = qk + ((size_t)(b * NPG_ + q0 + w * 16 + cc) * 512 + hh * 64);
  half8 qa0 = *(const half8*)(Qp + qq * 8);
  half8 qa1 = *(const half8*)(Qp + 32 + qq * 8);

  f32x4 oacc[4];
  #pragma unroll
  for (int t = 0; t < 4; t++) oacc[t] = f32x4{0.f, 0.f, 0.f, 0.f};
  float rs = 0.f;

  const half_t* kb = qk + ((size_t)(b * NPG_) * 512 + 256 + hh * 64);
  const half_t* vb = vt + ((size_t)(hh * 64) * 32768 + b * NPG_);

  int krow = lane >> 3, ksl = lane & 7;

  for (int kt = 0; kt < 8; kt++) {
    __syncthreads();
    #pragma unroll
    for (int i = 0; i < 2; i++) {
      int R = w * 16 + i * 8;           // 8-row slab (1 KB) per gload
      int kr = R + krow;
      gload_lds16(kb + (size_t)(kt * 64 + kr) * 512 + ((ksl ^ (kr & 7)) * 8),
                  &Kt[R * 64]);
      gload_lds16(vb + (size_t)kr * 32768 + kt * 64 + ((ksl ^ (kr & 7)) * 8),
                  &Vt[R * 64]);
    }
    __syncthreads();

    // S^T = K Q^T ; exp ; pack to wave-private P[q][key] (A-operand layout)
    #pragma unroll
    for (int mt = 0; mt < 4; mt++) {
      int key = mt * 16 + cc;
      half8 k0 = *(const half8*)&Kt[key * 64 + ((qq ^ (key & 7)) << 3)];
      half8 k1 = *(const half8*)&Kt[key * 64 + (((qq + 4) ^ (key & 7)) << 3)];
      f32x4 s = f32x4{0.f, 0.f, 0.f, 0.f};
      s = MFMA16(k0, qa0, s);
      s = MFMA16(k1, qa1, s);
      half4v ph;
      #pragma unroll
      for (int i = 0; i < 4; i++) {
        float p = exp2f(s[i] * 0.180336886f - 11.54156033f);
        rs += p;
        ph[i] = (half_t)p;
      }
      *(half4v*)&Pb[w][cc][mt * 16 + qq * 4] = ph;
    }

    // O += P V
    #pragma unroll
    for (int kc = 0; kc < 2; kc++) {
      half8 a = *(const half8*)&Pb[w][cc][kc * 32 + qq * 8];
      #pragma unroll
      for (int nt = 0; nt < 4; nt++) {
        int d = nt * 16 + cc;
        half8 bb = *(const half8*)&Vt[d * 64 + (((kc * 4 + qq) ^ (d & 7)) << 3)];
        oacc[nt] = MFMA16(a, bb, oacc[nt]);
      }
    }
  }

  rs += __shfl_xor(rs, 16);
  rs += __shfl_xor(rs, 32);
  #pragma unroll
  for (int i = 0; i < 4; i++) {
    float rsv = __shfl(rs, qq * 4 + i);
    float inv = 1.f / rsv;
    int node = b * NPG_ + q0 + w * 16 + qq * 4 + i;
    #pragma unroll
    for (int nt = 0; nt < 4; nt++)
      o[(size_t)node * 256 + hh * 64 + nt * 16 + cc] = (half_t)(oacc[nt][i] * inv);
  }
}

// ---------------- host ----------------
extern "C" void kernel_launch(void* const* d_in, const int* in_sizes, int n_in,
                              void* d_out, int out_size, void* d_ws, size_t ws_size,
                              hipStream_t stream)
{
  const float* x    = (const float*)d_in[0];
  const int*   ei   = (const int*)d_in[1];
  const float* W1   = (const float*)d_in[3];
  const float* aS1  = (const float*)d_in[4];
  const float* aD1  = (const float*)d_in[5];
  const float* b1   = (const float*)d_in[6];
  const float* W2   = (const float*)d_in[7];
  const float* aS2  = (const float*)d_in[8];
  const float* aD2  = (const float*)d_in[9];
  const float* b2   = (const float*)d_in[10];
  const float* W3   = (const float*)d_in[11];
  const float* aS3  = (const float*)d_in[12];
  const float* aD3  = (const float*)d_in[13];
  const float* b3   = (const float*)d_in[14];
  const float* Wi   = (const float*)d_in[15];
  const float* bi   = (const float*)d_in[16];
  const float* Wo   = (const float*)d_in[17];
  const float* bo   = (const float*)d_in[18];
  const float* gam  = (const float*)d_in[19];
  const float* bet  = (const float*)d_in[20];
  float* out = (float*)d_out;
  const int N = N_NODES;
  int E = in_sizes[1] / 2;

  char* ws = (char*)d_ws;
  size_t off = 0;
  auto alloc = [&](size_t bytes) -> void* {
    void* p = ws + off;
    off = (off + bytes + 255) & ~(size_t)255;
    return p;
  };
  half_t* x_h    = (half_t*)alloc((size_t)N * 128 * 2);
  half_t* h_h    = (half_t*)alloc((size_t)N * 256 * 2);   // h1/h2/h3
  half_t* x1_h   = (half_t*)alloc((size_t)N * 256 * 2);
  half_t* x2_h   = (half_t*)alloc((size_t)N * 256 * 2);
  half_t* qk_h   = (half_t*)alloc((size_t)N * 512 * 2);
  half_t* vt_h   = (half_t*)alloc((size_t)256 * N * 2);   // V^T: [256][32768]
  half_t* o_h    = (half_t*)alloc((size_t)N * 256 * 2);
  half_t* x2a_h  = (half_t*)alloc((size_t)N * 256 * 2);
  half_t* W1t    = (half_t*)alloc(256 * 128 * 2);
  half_t* W2t    = (half_t*)alloc(256 * 256 * 2);
  half_t* W3t    = (half_t*)alloc(128 * 256 * 2);
  half_t* Wi_h   = (half_t*)alloc(768 * 256 * 2);
  half_t* Wo_h   = (half_t*)alloc(256 * 256 * 2);
  float*  es     = (float*) alloc((size_t)N * 4 * 4);
  float*  ed     = (float*) alloc((size_t)N * 4 * 4);
  int*    deg    = (int*)   alloc((size_t)N * 4);
  int*    fill   = (int*)   alloc((size_t)N * 4);
  int*    rowptr = (int*)   alloc(((size_t)N + 1) * 4);
  int*    col    = (int*)   alloc((size_t)(N + E) * 4);
  int*    part   = (int*)   alloc((size_t)N * 4);
  int*    bsum   = (int*)   alloc(128 * 4);
  int*    boff   = (int*)   alloc(128 * 4);

  const int* srcE = ei;
  const int* dstE = ei + E;

  // conversions + deg init (one launch), then parallel CSR build
  k_convert<<<18048, 256, 0, stream>>>(x, x_h, W1, W1t, W2, W2t, W3, W3t,
                                       Wi, Wi_h, Wo, Wo_h, deg);
  k_hist<<<(E + 255) / 256, 256, 0, stream>>>(dstE, deg, E);
  k_scan1<<<128, 256, 0, stream>>>(deg, part, bsum);
  k_scan2<<<1, 128, 0, stream>>>(bsum, boff, rowptr);
  k_scan3<<<128, 256, 0, stream>>>(part, boff, rowptr, fill, col);
  k_scatter<<<(E + 255) / 256, 256, 0, stream>>>(srcE, dstE, rowptr, fill, col, E);

  // ---- GAT1: h1 = x @ W1 (+fused es/ed) ; aggregate+ELU -> x1 ----
  k_gemm<<<dim3(2, N / 128), 256, 0, stream>>>(x_h, W1t, nullptr, 0, h_h, nullptr,
                                               N, 256, 128, aS1, aD1, es, ed, 4);
  k_agg<256, 4, true><<<N / 4, 256, 0, stream>>>(h_h, es, ed, b1, rowptr, col, 1, nullptr, x1_h);

  // ---- GAT2 -> x2 (fp16) ----
  k_gemm<<<dim3(2, N / 128), 256, 0, stream>>>(x1_h, W2t, nullptr, 0, h_h, nullptr,
                                               N, 256, 256, aS2, aD2, es, ed, 4);
  k_agg<256, 4, true><<<N / 4, 256, 0, stream>>>(h_h, es, ed, b2, rowptr, col, 1, nullptr, x2_h);

  // ---- MHA: residency-first GEMMs for QK and V^T projections ----
  k_gemm_wide<<<dim3(8, N / 128), 256, 0, stream>>>(x2_h, Wi_h, bi, 0, qk_h,
                                                    N, 512, 256);
  k_gemm_wide<<<dim3(N / 64, 2), 256, 0, stream>>>(Wi_h + 512 * 256, x2_h, bi + 512, 1,
                                                   vt_h, 256, N, 256);
  k_attn<<<dim3(256, 8), 256, 0, stream>>>(qk_h, vt_h, o_h);

  // ---- Wo-GEMM + residual + LayerNorm fused -> x2a (fp16) ----
  k_gemm_ln<<<N / 64, 256, 0, stream>>>(o_h, Wo_h, bo, x2_h, gam, bet, x2a_h);

  // ---- GAT3 (H=1, C=128, fp32 accumulation) -> d_out fp32 ----
  k_gemm<<<dim3(1, N / 128), 256, 0, stream>>>(x2a_h, W3t, nullptr, 0, h_h, nullptr,
                                               N, 128, 256, aS3, aD3, es, ed, 1);
  k_agg<128, 1, false><<<N / 4, 256, 0, stream>>>(h_h, es, ed, b3, rowptr, col, 0, out, nullptr);
}

// Round 13
// 408.877 us; speedup vs baseline: 1.1469x; 1.0491x over previous
//
#include <hip/hip_runtime.h>

typedef _Float16 half_t;
typedef _Float16 half8  __attribute__((ext_vector_type(8)));
typedef _Float16 half4v __attribute__((ext_vector_type(4)));
typedef float    f32x4  __attribute__((ext_vector_type(4)));

constexpr int N_NODES = 32768;
constexpr int NPG_    = 512;

#define MFMA16(a, b, c) __builtin_amdgcn_mfma_f32_16x16x32_f16((a), (b), (c), 0, 0, 0)

__device__ __forceinline__ void gload_lds16(const half_t* g, half_t* l) {
  __builtin_amdgcn_global_load_lds(
      (const __attribute__((address_space(1))) void*)g,
      (__attribute__((address_space(3))) void*)l, 16, 0, 0);
}

// ---------------- CSR build ----------------
__global__ void k_hist(const int* __restrict__ dst, int* __restrict__ deg, int E) {
  int i = blockIdx.x * 256 + threadIdx.x;
  if (i < E) atomicAdd(&deg[dst[i]], 1);
}

// phase 1: per-block (256-elem) exclusive scan + block totals. 128 blocks.
__global__ __launch_bounds__(256) void k_scan1(const int* __restrict__ deg,
                                               int* __restrict__ partial,
                                               int* __restrict__ blockSums) {
  __shared__ int sd[256];
  int t = threadIdx.x;
  int i = blockIdx.x * 256 + t;
  int v = deg[i];
  sd[t] = v;
  __syncthreads();
  int acc = v;
  for (int off = 1; off < 256; off <<= 1) {
    int add = (t >= off) ? sd[t - off] : 0;
    __syncthreads();
    acc += add;
    sd[t] = acc;
    __syncthreads();
  }
  partial[i] = acc - v;                 // exclusive within block
  if (t == 255) blockSums[blockIdx.x] = acc;
}

// phase 2: exclusive scan of 128 block sums (1 tiny block)
__global__ __launch_bounds__(128) void k_scan2(const int* __restrict__ blockSums,
                                               int* __restrict__ blockOff,
                                               int* __restrict__ rowptr) {
  __shared__ int sd[128];
  int t = threadIdx.x;
  int v = blockSums[t];
  sd[t] = v;
  __syncthreads();
  for (int off = 1; off < 128; off <<= 1) {
    int add = (t >= off) ? sd[t - off] : 0;
    __syncthreads();
    sd[t] += add;
    __syncthreads();
  }
  blockOff[t] = sd[t] - v;              // exclusive
  if (t == 127) rowptr[N_NODES] = sd[t];
}

// phase 3: emit rowptr, fill=1, self-loop in slot 0. 128 blocks.
__global__ __launch_bounds__(256) void k_scan3(const int* __restrict__ partial,
                                               const int* __restrict__ blockOff,
                                               int* __restrict__ rowptr,
                                               int* __restrict__ fill,
                                               int* __restrict__ col) {
  int i = blockIdx.x * 256 + threadIdx.x;
  int rp = partial[i] + blockOff[blockIdx.x];
  rowptr[i] = rp;
  fill[i] = 1;                          // self-loop occupies slot 0
  col[rp] = i;
}

__global__ void k_scatter(const int* __restrict__ src, const int* __restrict__ dst,
                          const int* __restrict__ rowptr, int* __restrict__ fill,
                          int* __restrict__ col, int E) {
  int i = blockIdx.x * 256 + threadIdx.x;
  if (i < E) {
    int d = dst[i];
    int pos = rowptr[d] + atomicAdd(&fill[d], 1);
    col[pos] = src[i];
  }
}

// ---------------- fused conversions + deg init (one launch) ----------------
__global__ void k_convert(
    const float* __restrict__ x,  half_t* __restrict__ x_h,
    const float* __restrict__ W1, half_t* __restrict__ W1t,
    const float* __restrict__ W2, half_t* __restrict__ W2t,
    const float* __restrict__ W3, half_t* __restrict__ W3t,
    const float* __restrict__ Wi, half_t* __restrict__ Wi_h,
    const float* __restrict__ Wo, half_t* __restrict__ Wo_h,
    int* __restrict__ deg)
{
  int bid = blockIdx.x, t = threadIdx.x;
  if (bid < 16384) {
    int i = bid * 256 + t;
    x_h[i] = (half_t)x[i];
  } else if (bid < 16512) {            // W1t[o*128+k] = W1[k*256+o]
    int i = (bid - 16384) * 256 + t;
    int o = i >> 7, k = i & 127;
    W1t[i] = (half_t)W1[k * 256 + o];
  } else if (bid < 16768) {            // W2t[o*256+k] = W2[k*256+o]
    int i = (bid - 16512) * 256 + t;
    int o = i >> 8, k = i & 255;
    W2t[i] = (half_t)W2[k * 256 + o];
  } else if (bid < 16896) {            // W3t[o*256+k] = W3[k*128+o]
    int i = (bid - 16768) * 256 + t;
    int o = i >> 8, k = i & 255;
    W3t[i] = (half_t)W3[k * 128 + o];
  } else if (bid < 17664) {
    int i = (bid - 16896) * 256 + t;
    Wi_h[i] = (half_t)Wi[i];
  } else if (bid < 17920) {
    int i = (bid - 17664) * 256 + t;
    Wo_h[i] = (half_t)Wo[i];
  } else {
    deg[(bid - 17920) * 256 + t] = 1;  // self-loop counts as 1
  }
}

// ---------------- residency-first GEMM (no epilogue): tile 128x64, BK=64 ----------------
__global__ __launch_bounds__(256) void k_gemm_wide(
    const half_t* __restrict__ A, const half_t* __restrict__ Bt,
    const float* __restrict__ bias, int bias_per_row,
    half_t* __restrict__ outh, int M, int Nc, int K)
{
  __shared__ __align__(16) half_t As[128 * 64];
  __shared__ __align__(16) half_t Bs[64 * 64];
  int w = threadIdx.x >> 6, lane = threadIdx.x & 63;
  int r = lane & 15, q = lane >> 4;
  int m0 = blockIdx.y * 128, n0 = blockIdx.x * 64;
  int mh = (w & 1) * 64, nh = (w >> 1) * 32;
  f32x4 acc[4][2];
  #pragma unroll
  for (int i = 0; i < 4; i++)
    #pragma unroll
    for (int j = 0; j < 2; j++) acc[i][j] = f32x4{0.f, 0.f, 0.f, 0.f};

  int srow = lane >> 3, sc = lane & 7;

  for (int k0 = 0; k0 < K; k0 += 64) {
    __syncthreads();
    #pragma unroll
    for (int i = 0; i < 4; i++) {          // As: 128 rows, 32/wave
      int R0 = w * 32 + i * 8;
      int row = R0 + srow;
      int cg = sc ^ (row & 7);
      gload_lds16(A + (size_t)(m0 + row) * K + k0 + cg * 8, &As[R0 * 64]);
    }
    #pragma unroll
    for (int i = 0; i < 2; i++) {          // Bs: 64 rows, 16/wave
      int R0 = w * 16 + i * 8;
      int row = R0 + srow;
      int cg = sc ^ (row & 7);
      gload_lds16(Bt + (size_t)(n0 + row) * K + k0 + cg * 8, &Bs[R0 * 64]);
    }
    __syncthreads();
    #pragma unroll
    for (int kk = 0; kk < 2; kk++) {
      half8 af[4], bf[2];
      #pragma unroll
      for (int t = 0; t < 4; t++) {
        int rr = mh + t * 16 + r;
        af[t] = *(const half8*)&As[rr * 64 + (((kk * 4 + q) ^ (rr & 7)) << 3)];
      }
      #pragma unroll
      for (int t = 0; t < 2; t++) {
        int rr = nh + t * 16 + r;
        bf[t] = *(const half8*)&Bs[rr * 64 + (((kk * 4 + q) ^ (rr & 7)) << 3)];
      }
      #pragma unroll
      for (int ti = 0; ti < 4; ti++)
        #pragma unroll
        for (int tj = 0; tj < 2; tj++)
          acc[ti][tj] = MFMA16(af[ti], bf[tj], acc[ti][tj]);
    }
  }

  #pragma unroll
  for (int tj = 0; tj < 2; tj++) {
    int colc = n0 + nh + tj * 16 + r;
    float bc = bias_per_row ? 0.f : bias[colc];
    #pragma unroll
    for (int ti = 0; ti < 4; ti++) {
      #pragma unroll
      for (int i = 0; i < 4; i++) {
        int row = m0 + mh + ti * 16 + q * 4 + i;
        float bv = bias_per_row ? bias[row] : bc;
        outh[(size_t)row * Nc + colc] = (half_t)(acc[ti][tj][i] + bv);
      }
    }
  }
}

// ---------------- residency-first GAT GEMM: 128x64 tile + fused es/ed ----------------
// H==4: 64-col block == one head (head = n0>>6); wave 32-col partials ->
// 16-lane shfl -> 2-wave LDS combine -> direct write.
// H==1: dot spans both col-blocks -> per-block partial atomicAdd into es/ed
// (zero-initialized by k_gemm_ln, which runs immediately before GAT3).
template<int NC, int H>
__global__ __launch_bounds__(256) void k_gemm_gat(
    const half_t* __restrict__ A, const half_t* __restrict__ Bt,
    half_t* __restrict__ outh, int K,
    const float* __restrict__ aS, const float* __restrict__ aD,
    float* __restrict__ es, float* __restrict__ ed)
{
  __shared__ __align__(16) half_t As[128 * 64];
  __shared__ __align__(16) half_t Bs[64 * 64];
  __shared__ float sRed[2][4][64];
  int w = threadIdx.x >> 6, lane = threadIdx.x & 63;
  int cc = lane & 15, qq = lane >> 4;
  int m0 = blockIdx.y * 128, n0 = blockIdx.x * 64;
  int mh = (w & 1) * 64, nh = (w >> 1) * 32;
  f32x4 acc[4][2];
  #pragma unroll
  for (int i = 0; i < 4; i++)
    #pragma unroll
    for (int j = 0; j < 2; j++) acc[i][j] = f32x4{0.f, 0.f, 0.f, 0.f};

  int srow = lane >> 3, sc = lane & 7;

  for (int k0 = 0; k0 < K; k0 += 64) {
    __syncthreads();
    #pragma unroll
    for (int i = 0; i < 4; i++) {
      int R0 = w * 32 + i * 8;
      int row = R0 + srow;
      int cg = sc ^ (row & 7);
      gload_lds16(A + (size_t)(m0 + row) * K + k0 + cg * 8, &As[R0 * 64]);
    }
    #pragma unroll
    for (int i = 0; i < 2; i++) {
      int R0 = w * 16 + i * 8;
      int row = R0 + srow;
      int cg = sc ^ (row & 7);
      gload_lds16(Bt + (size_t)(n0 + row) * K + k0 + cg * 8, &Bs[R0 * 64]);
    }
    __syncthreads();
    #pragma unroll
    for (int kk = 0; kk < 2; kk++) {
      half8 af[4], bf[2];
      #pragma unroll
      for (int t = 0; t < 4; t++) {
        int rr = mh + t * 16 + cc;
        af[t] = *(const half8*)&As[rr * 64 + (((kk * 4 + qq) ^ (rr & 7)) << 3)];
      }
      #pragma unroll
      for (int t = 0; t < 2; t++) {
        int rr = nh + t * 16 + cc;
        bf[t] = *(const half8*)&Bs[rr * 64 + (((kk * 4 + qq) ^ (rr & 7)) << 3)];
      }
      #pragma unroll
      for (int ti = 0; ti < 4; ti++)
        #pragma unroll
        for (int tj = 0; tj < 2; tj++)
          acc[ti][tj] = MFMA16(af[ti], bf[tj], acc[ti][tj]);
    }
  }

  // epilogue: store C (fp16) + per-row score partials over this wave's 32 cols
  float aSv[2], aDv[2];
  #pragma unroll
  for (int tj = 0; tj < 2; tj++) {
    int colg = n0 + nh + tj * 16 + cc;
    aSv[tj] = aS[colg];
    aDv[tj] = aD[colg];
  }
  #pragma unroll
  for (int ti = 0; ti < 4; ti++) {
    #pragma unroll
    for (int i = 0; i < 4; i++) {
      int rloc = mh + ti * 16 + qq * 4 + i;      // 0..127
      float ps = 0.f, pd = 0.f;
      #pragma unroll
      for (int tj = 0; tj < 2; tj++) {
        int colg = n0 + nh + tj * 16 + cc;
        float v = acc[ti][tj][i];
        outh[(size_t)(m0 + rloc) * NC + colg] = (half_t)v;
        ps += v * aSv[tj];
        pd += v * aDv[tj];
      }
      #pragma unroll
      for (int off = 1; off < 16; off <<= 1) {
        ps += __shfl_xor(ps, off);
        pd += __shfl_xor(pd, off);
      }
      if (cc == 0) {
        sRed[0][w][ti * 16 + qq * 4 + i] = ps;
        sRed[1][w][ti * 16 + qq * 4 + i] = pd;
      }
    }
  }
  __syncthreads();
  if (threadIdx.x < 128) {
    int row = threadIdx.x;
    int wlo = row >> 6, ri = row & 63;
    float ps = sRed[0][wlo][ri] + sRed[0][wlo + 2][ri];
    float pd = sRed[1][wlo][ri] + sRed[1][wlo + 2][ri];
    if (H == 4) {
      int head = n0 >> 6;
      es[(size_t)(m0 + row) * 4 + head] = ps;
      ed[(size_t)(m0 + row) * 4 + head] = pd;
    } else {
      atomicAdd(&es[m0 + row], ps);
      atomicAdd(&ed[m0 + row], pd);
    }
  }
}

// ---------------- fused Wo-GEMM + residual + LayerNorm (+ es/ed zeroing) ----------------
__global__ __launch_bounds__(256) void k_gemm_ln(
    const half_t* __restrict__ A, const half_t* __restrict__ Bt,
    const float* __restrict__ bias, const half_t* __restrict__ res,
    const float* __restrict__ gamma, const float* __restrict__ beta,
    half_t* __restrict__ outh, float* __restrict__ es0, float* __restrict__ ed0)
{
  __shared__ __align__(16) half_t As[64 * 64];
  __shared__ __align__(16) half_t Bs[256 * 64];
  __shared__ float sSum[4][64], sSq[4][64];
  __shared__ float sMR[64][2];
  int w = threadIdx.x >> 6, lane = threadIdx.x & 63;
  int r = lane & 15, q = lane >> 4;
  int m0 = blockIdx.x * 64;
  int nh = w * 64;

  // zero es/ed for GAT3's atomic score accumulation (this kernel runs just before)
  if (threadIdx.x < 64) es0[m0 + threadIdx.x] = 0.f;
  else if (threadIdx.x < 128) ed0[m0 + threadIdx.x - 64] = 0.f;

  f32x4 acc[4][4];
  #pragma unroll
  for (int i = 0; i < 4; i++)
    #pragma unroll
    for (int j = 0; j < 4; j++) acc[i][j] = f32x4{0.f, 0.f, 0.f, 0.f};

  int srow = lane >> 3, sc = lane & 7;

  for (int k0 = 0; k0 < 256; k0 += 64) {
    __syncthreads();
    #pragma unroll
    for (int i = 0; i < 2; i++) {          // As: 64 rows
      int R0 = w * 16 + i * 8;
      int row = R0 + srow;
      int cg = sc ^ (row & 7);
      gload_lds16(A + (size_t)(m0 + row) * 256 + k0 + cg * 8, &As[R0 * 64]);
    }
    #pragma unroll
    for (int i = 0; i < 8; i++) {          // Bs: 256 rows (full Wo)
      int R0 = w * 64 + i * 8;
      int row = R0 + srow;
      int cg = sc ^ (row & 7);
      gload_lds16(Bt + (size_t)row * 256 + k0 + cg * 8, &Bs[R0 * 64]);
    }
    __syncthreads();
    #pragma unroll
    for (int kk = 0; kk < 2; kk++) {
      half8 af[4], bf[4];
      #pragma unroll
      for (int t = 0; t < 4; t++) {
        int rr = t * 16 + r;
        af[t] = *(const half8*)&As[rr * 64 + (((kk * 4 + q) ^ (rr & 7)) << 3)];
      }
      #pragma unroll
      for (int t = 0; t < 4; t++) {
        int rr = nh + t * 16 + r;
        bf[t] = *(const half8*)&Bs[rr * 64 + (((kk * 4 + q) ^ (rr & 7)) << 3)];
      }
      #pragma unroll
      for (int ti = 0; ti < 4; ti++)
        #pragma unroll
        for (int tj = 0; tj < 4; tj++)
          acc[ti][tj] = MFMA16(af[ti], bf[tj], acc[ti][tj]);
    }
  }

  float gv[4], bv[4];
  #pragma unroll
  for (int tj = 0; tj < 4; tj++) {
    int col = nh + tj * 16 + r;
    gv[tj] = gamma[col];
    bv[tj] = beta[col];
  }
  #pragma unroll
  for (int ti = 0; ti < 4; ti++) {
    #pragma unroll
    for (int i = 0; i < 4; i++) {
      int row = ti * 16 + q * 4 + i;
      float s = 0.f, ss = 0.f;
      #pragma unroll
      for (int tj = 0; tj < 4; tj++) {
        int col = nh + tj * 16 + r;
        float v = acc[ti][tj][i] + bias[col]
                + (float)res[(size_t)(m0 + row) * 256 + col];
        acc[ti][tj][i] = v;
        s += v;
        ss += v * v;
      }
      #pragma unroll
      for (int off = 1; off < 16; off <<= 1) {
        s  += __shfl_xor(s, off);
        ss += __shfl_xor(ss, off);
      }
      if (r == 0) { sSum[w][row] = s; sSq[w][row] = ss; }
    }
  }
  __syncthreads();
  if (threadIdx.x < 64) {
    int row = threadIdx.x;
    float s  = sSum[0][row] + sSum[1][row] + sSum[2][row] + sSum[3][row];
    float ss = sSq[0][row] + sSq[1][row] + sSq[2][row] + sSq[3][row];
    float mean = s * (1.f / 256.f);
    float var  = ss * (1.f / 256.f) - mean * mean;
    sMR[row][0] = mean;
    sMR[row][1] = rsqrtf(var + 1e-5f);
  }
  __syncthreads();
  #pragma unroll
  for (int ti = 0; ti < 4; ti++) {
    #pragma unroll
    for (int i = 0; i < 4; i++) {
      int row = ti * 16 + q * 4 + i;
      float mean = sMR[row][0], rstd = sMR[row][1];
      #pragma unroll
      for (int tj = 0; tj < 4; tj++) {
        int col = nh + tj * 16 + r;
        outh[(size_t)(m0 + row) * 256 + col] =
            (half_t)((acc[ti][tj][i] - mean) * rstd * gv[tj] + bv[tj]);
      }
    }
  }
}

// ---------------- edge-softmax aggregation (one wave per dst) ----------------
template<int HC, int H, bool FP16ACC>
__global__ __launch_bounds__(256) void k_agg(
    const half_t* __restrict__ h, const float* __restrict__ es,
    const float* __restrict__ ed, const float* __restrict__ bias,
    const int* __restrict__ rowptr, const int* __restrict__ col, int elu,
    float* __restrict__ outf, half_t* __restrict__ outh)
{
  constexpr int VPT = HC / 16;        // channels per lane (16 or 8)
  constexpr int NV8 = VPT / 8;        // half8 regs per slot (2 or 1)
  constexpr int C = HC / H;
  int lane = threadIdx.x & 63;
  int g = lane >> 4, li = lane & 15;
  int n = blockIdx.x * 4 + (threadIdx.x >> 6);
  int cbase = li * VPT;
  int hl = cbase / C;
  float edn = ed[(size_t)n * H + hl];
  int j0 = rowptr[n], j1 = rowptr[n + 1];
  const half_t* hb = h + cbase;

  float sum0 = 0.f, sum1 = 0.f;

  if constexpr (FP16ACC) {
    half8 acc0[NV8], acc1[NV8];
    #pragma unroll
    for (int i = 0; i < NV8; i++) {
      acc0[i] = half8{0, 0, 0, 0, 0, 0, 0, 0};
      acc1[i] = half8{0, 0, 0, 0, 0, 0, 0, 0};
    }
    for (int j = j0 + g; j < j1; j += 8) {
      int jb = j + 4;
      int s0 = col[j];
      int s1 = col[(jb < j1) ? jb : j];
      float e0 = es[(size_t)s0 * H + hl] + edn;
      e0 = fmaxf(e0, 0.2f * e0);
      float e1 = es[(size_t)s1 * H + hl] + edn;
      e1 = fmaxf(e1, 0.2f * e1);
      e1 = (jb < j1) ? e1 : -1e30f;
      const half_t* hp0 = hb + (size_t)s0 * HC;
      const half_t* hp1 = hb + (size_t)s1 * HC;
      float p0 = exp2f(e0 * 1.44269504f - 8.65617025f);
      float p1 = exp2f(e1 * 1.44269504f - 8.65617025f);
      sum0 += p0; sum1 += p1;
      half_t q0 = (half_t)p0, q1 = (half_t)p1;
      half8 pv0 = {q0, q0, q0, q0, q0, q0, q0, q0};
      half8 pv1 = {q1, q1, q1, q1, q1, q1, q1, q1};
      #pragma unroll
      for (int i = 0; i < NV8; i++) {
        half8 v0 = *(const half8*)(hp0 + i * 8);
        half8 v1 = *(const half8*)(hp1 + i * 8);
        acc0[i] += pv0 * v0;        // v_pk_fma_f16
        acc1[i] += pv1 * v1;
      }
    }
    float sum = sum0 + sum1;
    sum += __shfl_xor(sum, 16);
    sum += __shfl_xor(sum, 32);
    float av[VPT];
    #pragma unroll
    for (int i = 0; i < VPT; i++) {
      av[i] = (float)acc0[i >> 3][i & 7] + (float)acc1[i >> 3][i & 7];
      av[i] += __shfl_xor(av[i], 16);
      av[i] += __shfl_xor(av[i], 32);
    }
    float inv = 1.f / sum;
    float v[VPT];
    #pragma unroll
    for (int i = 0; i < VPT; i++) {
      float t = av[i] * inv + bias[cbase + i];
      if (elu) t = (t > 0.f) ? t : __expf(t) - 1.f;
      v[i] = t;
    }
    if (g == 0) {
      size_t obase = (size_t)n * HC + cbase;
      if (outh) {
        #pragma unroll
        for (int p8 = 0; p8 < NV8; p8++) {
          half8 hv;
          #pragma unroll
          for (int i = 0; i < 8; i++) hv[i] = (half_t)v[p8 * 8 + i];
          *(half8*)(outh + obase + p8 * 8) = hv;
        }
      }
      if (outf) {
        #pragma unroll
        for (int p4 = 0; p4 < VPT / 4; p4++) {
          float4 fv = {v[p4 * 4], v[p4 * 4 + 1], v[p4 * 4 + 2], v[p4 * 4 + 3]};
          *(float4*)(outf + obase + p4 * 4) = fv;
        }
      }
    }
  } else {
    float acc0[VPT], acc1[VPT];
    #pragma unroll
    for (int i = 0; i < VPT; i++) { acc0[i] = 0.f; acc1[i] = 0.f; }
    for (int j = j0 + g; j < j1; j += 8) {
      int jb = j + 4;
      int s0 = col[j];
      int s1 = col[(jb < j1) ? jb : j];
      float e0 = es[(size_t)s0 * H + hl] + edn;
      e0 = fmaxf(e0, 0.2f * e0);
      float e1 = es[(size_t)s1 * H + hl] + edn;
      e1 = fmaxf(e1, 0.2f * e1);
      e1 = (jb < j1) ? e1 : -1e30f;
      const half_t* hp0 = hb + (size_t)s0 * HC;
      const half_t* hp1 = hb + (size_t)s1 * HC;
      float p0 = __expf(e0), p1 = __expf(e1);
      sum0 += p0; sum1 += p1;
      #pragma unroll
      for (int c8 = 0; c8 < NV8; c8++) {
        half8 a0 = *(const half8*)(hp0 + c8 * 8);
        half8 a1 = *(const half8*)(hp1 + c8 * 8);
        #pragma unroll
        for (int i = 0; i < 8; i++) {
          acc0[c8 * 8 + i] += p0 * (float)a0[i];
          acc1[c8 * 8 + i] += p1 * (float)a1[i];
        }
      }
    }
    float sum = sum0 + sum1;
    sum += __shfl_xor(sum, 16);
    sum += __shfl_xor(sum, 32);
    float av[VPT];
    #pragma unroll
    for (int i = 0; i < VPT; i++) {
      av[i] = acc0[i] + acc1[i];
      av[i] += __shfl_xor(av[i], 16);
      av[i] += __shfl_xor(av[i], 32);
    }
    float inv = 1.f / sum;
    float v[VPT];
    #pragma unroll
    for (int i = 0; i < VPT; i++) {
      float t = av[i] * inv + bias[cbase + i];
      if (elu) t = (t > 0.f) ? t : __expf(t) - 1.f;
      v[i] = t;
    }
    if (g == 0) {
      size_t obase = (size_t)n * HC + cbase;
      if (outh) {
        #pragma unroll
        for (int p8 = 0; p8 < NV8; p8++) {
          half8 hv;
          #pragma unroll
          for (int i = 0; i < 8; i++) hv[i] = (half_t)v[p8 * 8 + i];
          *(half8*)(outh + obase + p8 * 8) = hv;
        }
      }
      if (outf) {
        #pragma unroll
        for (int p4 = 0; p4 < VPT / 4; p4++) {
          float4 fv = {v[p4 * 4], v[p4 * 4 + 1], v[p4 * 4 + 2], v[p4 * 4 + 3]};
          *(float4*)(outf + obase + p4 * 4) = fv;
        }
      }
    }
  }
}

// ---------------- MHA core (R9 known-good: 64-key tiles, 25 KB LDS) ----------------
__global__ __launch_bounds__(256) void k_attn(
    const half_t* __restrict__ qk, const half_t* __restrict__ vt,
    half_t* __restrict__ o)
{
  __shared__ __align__(16) half_t Kt[64 * 64];        // K tile [key][64]
  __shared__ __align__(16) half_t Vt[64 * 64];        // V^T tile [d][64 keys]
  __shared__ __align__(16) half_t Pb[4][16][72];      // per-wave P [q][key+pad]

  int pair = blockIdx.x;
  int b = pair >> 2, hh = pair & 3;
  int q0 = blockIdx.y * 64;
  int w = threadIdx.x >> 6, lane = threadIdx.x & 63;
  int cc = lane & 15, qq = lane >> 4;

  const half_t* Qp = qk + ((size_t)(b * NPG_ + q0 + w * 16 + cc) * 512 + hh * 64);
  half8 qa0 = *(const half8*)(Qp + qq * 8);
  half8 qa1 = *(const half8*)(Qp + 32 + qq * 8);

  f32x4 oacc[4];
  #pragma unroll
  for (int t = 0; t < 4; t++) oacc[t] = f32x4{0.f, 0.f, 0.f, 0.f};
  float rs = 0.f;

  const half_t* kb = qk + ((size_t)(b * NPG_) * 512 + 256 + hh * 64);
  const half_t* vb = vt + ((size_t)(hh * 64) * 32768 + b * NPG_);

  int krow = lane >> 3, ksl = lane & 7;

  for (int kt = 0; kt < 8; kt++) {
    __syncthreads();
    #pragma unroll
    for (int i = 0; i < 2; i++) {
      int R = w * 16 + i * 8;           // 8-row slab (1 KB) per gload
      int kr = R + krow;
      gload_lds16(kb + (size_t)(kt * 64 + kr) * 512 + ((ksl ^ (kr & 7)) * 8),
                  &Kt[R * 64]);
      gload_lds16(vb + (size_t)kr * 32768 + kt * 64 + ((ksl ^ (kr & 7)) * 8),
                  &Vt[R * 64]);
    }
    __syncthreads();

    // S^T = K Q^T ; exp ; pack to wave-private P[q][key] (A-operand layout)
    #pragma unroll
    for (int mt = 0; mt < 4; mt++) {
      int key = mt * 16 + cc;
      half8 k0 = *(const half8*)&Kt[key * 64 + ((qq ^ (key & 7)) << 3)];
      half8 k1 = *(const half8*)&Kt[key * 64 + (((qq + 4) ^ (key & 7)) << 3)];
      f32x4 s = f32x4{0.f, 0.f, 0.f, 0.f};
      s = MFMA16(k0, qa0, s);
      s = MFMA16(k1, qa1, s);
      half4v ph;
      #pragma unroll
      for (int i = 0; i < 4; i++) {
        float p = exp2f(s[i] * 0.180336886f - 11.54156033f);
        rs += p;
        ph[i] = (half_t)p;
      }
      *(half4v*)&Pb[w][cc][mt * 16 + qq * 4] = ph;
    }

    // O += P V
    #pragma unroll
    for (int kc = 0; kc < 2; kc++) {
      half8 a = *(const half8*)&Pb[w][cc][kc * 32 + qq * 8];
      #pragma unroll
      for (int nt = 0; nt < 4; nt++) {
        int d = nt * 16 + cc;
        half8 bb = *(const half8*)&Vt[d * 64 + (((kc * 4 + qq) ^ (d & 7)) << 3)];
        oacc[nt] = MFMA16(a, bb, oacc[nt]);
      }
    }
  }

  rs += __shfl_xor(rs, 16);
  rs += __shfl_xor(rs, 32);
  #pragma unroll
  for (int i = 0; i < 4; i++) {
    float rsv = __shfl(rs, qq * 4 + i);
    float inv = 1.f / rsv;
    int node = b * NPG_ + q0 + w * 16 + qq * 4 + i;
    #pragma unroll
    for (int nt = 0; nt < 4; nt++)
      o[(size_t)node * 256 + hh * 64 + nt * 16 + cc] = (half_t)(oacc[nt][i] * inv);
  }
}

// ---------------- host ----------------
extern "C" void kernel_launch(void* const* d_in, const int* in_sizes, int n_in,
                              void* d_out, int out_size, void* d_ws, size_t ws_size,
                              hipStream_t stream)
{
  const float* x    = (const float*)d_in[0];
  const int*   ei   = (const int*)d_in[1];
  const float* W1   = (const float*)d_in[3];
  const float* aS1  = (const float*)d_in[4];
  const float* aD1  = (const float*)d_in[5];
  const float* b1   = (const float*)d_in[6];
  const float* W2   = (const float*)d_in[7];
  const float* aS2  = (const float*)d_in[8];
  const float* aD2  = (const float*)d_in[9];
  const float* b2   = (const float*)d_in[10];
  const float* W3   = (const float*)d_in[11];
  const float* aS3  = (const float*)d_in[12];
  const float* aD3  = (const float*)d_in[13];
  const float* b3   = (const float*)d_in[14];
  const float* Wi   = (const float*)d_in[15];
  const float* bi   = (const float*)d_in[16];
  const float* Wo   = (const float*)d_in[17];
  const float* bo   = (const float*)d_in[18];
  const float* gam  = (const float*)d_in[19];
  const float* bet  = (const float*)d_in[20];
  float* out = (float*)d_out;
  const int N = N_NODES;
  int E = in_sizes[1] / 2;

  char* ws = (char*)d_ws;
  size_t off = 0;
  auto alloc = [&](size_t bytes) -> void* {
    void* p = ws + off;
    off = (off + bytes + 255) & ~(size_t)255;
    return p;
  };
  half_t* x_h    = (half_t*)alloc((size_t)N * 128 * 2);
  half_t* h_h    = (half_t*)alloc((size_t)N * 256 * 2);   // h1/h2/h3
  half_t* x1_h   = (half_t*)alloc((size_t)N * 256 * 2);
  half_t* x2_h   = (half_t*)alloc((size_t)N * 256 * 2);
  half_t* qk_h   = (half_t*)alloc((size_t)N * 512 * 2);
  half_t* vt_h   = (half_t*)alloc((size_t)256 * N * 2);   // V^T: [256][32768]
  half_t* o_h    = (half_t*)alloc((size_t)N * 256 * 2);
  half_t* x2a_h  = (half_t*)alloc((size_t)N * 256 * 2);
  half_t* W1t    = (half_t*)alloc(256 * 128 * 2);
  half_t* W2t    = (half_t*)alloc(256 * 256 * 2);
  half_t* W3t    = (half_t*)alloc(128 * 256 * 2);
  half_t* Wi_h   = (half_t*)alloc(768 * 256 * 2);
  half_t* Wo_h   = (half_t*)alloc(256 * 256 * 2);
  float*  es     = (float*) alloc((size_t)N * 4 * 4);
  float*  ed     = (float*) alloc((size_t)N * 4 * 4);
  int*    deg    = (int*)   alloc((size_t)N * 4);
  int*    fill   = (int*)   alloc((size_t)N * 4);
  int*    rowptr = (int*)   alloc(((size_t)N + 1) * 4);
  int*    col    = (int*)   alloc((size_t)(N + E) * 4);
  int*    part   = (int*)   alloc((size_t)N * 4);
  int*    bsum   = (int*)   alloc(128 * 4);
  int*    boff   = (int*)   alloc(128 * 4);

  const int* srcE = ei;
  const int* dstE = ei + E;

  // conversions + deg init (one launch), then parallel CSR build
  k_convert<<<18048, 256, 0, stream>>>(x, x_h, W1, W1t, W2, W2t, W3, W3t,
                                       Wi, Wi_h, Wo, Wo_h, deg);
  k_hist<<<(E + 255) / 256, 256, 0, stream>>>(dstE, deg, E);
  k_scan1<<<128, 256, 0, stream>>>(deg, part, bsum);
  k_scan2<<<1, 128, 0, stream>>>(bsum, boff, rowptr);
  k_scan3<<<128, 256, 0, stream>>>(part, boff, rowptr, fill, col);
  k_scatter<<<(E + 255) / 256, 256, 0, stream>>>(srcE, dstE, rowptr, fill, col, E);

  // ---- GAT1: h1 = x @ W1 (+fused es/ed) ; aggregate+ELU -> x1 ----
  k_gemm_gat<256, 4><<<dim3(4, N / 128), 256, 0, stream>>>(x_h, W1t, h_h, 128,
                                                           aS1, aD1, es, ed);
  k_agg<256, 4, true><<<N / 4, 256, 0, stream>>>(h_h, es, ed, b1, rowptr, col, 1, nullptr, x1_h);

  // ---- GAT2 -> x2 (fp16) ----
  k_gemm_gat<256, 4><<<dim3(4, N / 128), 256, 0, stream>>>(x1_h, W2t, h_h, 256,
                                                           aS2, aD2, es, ed);
  k_agg<256, 4, true><<<N / 4, 256, 0, stream>>>(h_h, es, ed, b2, rowptr, col, 1, nullptr, x2_h);

  // ---- MHA: residency-first GEMMs for QK and V^T projections ----
  k_gemm_wide<<<dim3(8, N / 128), 256, 0, stream>>>(x2_h, Wi_h, bi, 0, qk_h,
                                                    N, 512, 256);
  k_gemm_wide<<<dim3(N / 64, 2), 256, 0, stream>>>(Wi_h + 512 * 256, x2_h, bi + 512, 1,
                                                   vt_h, 256, N, 256);
  k_attn<<<dim3(256, 8), 256, 0, stream>>>(qk_h, vt_h, o_h);

  // ---- Wo-GEMM + residual + LayerNorm fused -> x2a; also zeroes es/ed ----
  k_gemm_ln<<<N / 64, 256, 0, stream>>>(o_h, Wo_h, bo, x2_h, gam, bet, x2a_h, es, ed);

  // ---- GAT3 (H=1, C=128; es/ed via cross-block atomic partials) -> d_out fp32 ----
  k_gemm_gat<128, 1><<<dim3(2, N / 128), 256, 0, stream>>>(x2a_h, W3t, h_h, 256,
                                                           aS3, aD3, es, ed);
  k_agg<128, 1, false><<<N / 4, 256, 0, stream>>>(h_h, es, ed, b3, rowptr, col, 0, out, nullptr);
}

// Round 15
// 404.377 us; speedup vs baseline: 1.1596x; 1.0111x over previous
//
#include <hip/hip_runtime.h>

typedef _Float16 half_t;
typedef _Float16 half8  __attribute__((ext_vector_type(8)));
typedef _Float16 half4v __attribute__((ext_vector_type(4)));
typedef _Float16 half2v __attribute__((ext_vector_type(2)));
typedef float    f32x4  __attribute__((ext_vector_type(4)));
typedef float    f32x2  __attribute__((ext_vector_type(2)));

constexpr int N_NODES = 32768;
constexpr int NPG_    = 512;

#define MFMA16(a, b, c) __builtin_amdgcn_mfma_f32_16x16x32_f16((a), (b), (c), 0, 0, 0)

#if defined(__has_builtin)
#  if __has_builtin(__builtin_amdgcn_cvt_pk_f16_fp8)
#    define HAVE_PK_F16_FP8 1
#  else
#    define HAVE_PK_F16_FP8 0
#  endif
#else
#  define HAVE_PK_F16_FP8 0
#endif

__device__ __forceinline__ void gload_lds16(const half_t* g, half_t* l) {
  __builtin_amdgcn_global_load_lds(
      (const __attribute__((address_space(1))) void*)g,
      (__attribute__((address_space(3))) void*)l, 16, 0, 0);
}

// decode 4 fp8 (one dword) and fma into 2 half2 accumulators with weight p
__device__ __forceinline__ void fp8x4_fma(int wrd, half2v p, half2v* acc) {
#if HAVE_PK_F16_FP8
  half2v lo = __builtin_amdgcn_cvt_pk_f16_fp8((short)(wrd & 0xffff));
  half2v hi = __builtin_amdgcn_cvt_pk_f16_fp8((short)(((unsigned)wrd) >> 16));
#else
  f32x2 flo = __builtin_amdgcn_cvt_pk_f32_fp8(wrd, false);
  f32x2 fhi = __builtin_amdgcn_cvt_pk_f32_fp8(wrd, true);
  half2v lo = {(half_t)flo.x, (half_t)flo.y};
  half2v hi = {(half_t)fhi.x, (half_t)fhi.y};
#endif
  acc[0] += p * lo;
  acc[1] += p * hi;
}

// ---------------- CSR build ----------------
__global__ void k_hist(const int* __restrict__ dst, int* __restrict__ deg, int E) {
  int i = blockIdx.x * 256 + threadIdx.x;
  if (i < E) atomicAdd(&deg[dst[i]], 1);
}

__global__ __launch_bounds__(256) void k_scan1(const int* __restrict__ deg,
                                               int* __restrict__ partial,
                                               int* __restrict__ blockSums) {
  __shared__ int sd[256];
  int t = threadIdx.x;
  int i = blockIdx.x * 256 + t;
  int v = deg[i];
  sd[t] = v;
  __syncthreads();
  int acc = v;
  for (int off = 1; off < 256; off <<= 1) {
    int add = (t >= off) ? sd[t - off] : 0;
    __syncthreads();
    acc += add;
    sd[t] = acc;
    __syncthreads();
  }
  partial[i] = acc - v;
  if (t == 255) blockSums[blockIdx.x] = acc;
}

__global__ __launch_bounds__(128) void k_scan2(const int* __restrict__ blockSums,
                                               int* __restrict__ blockOff,
                                               int* __restrict__ rowptr) {
  __shared__ int sd[128];
  int t = threadIdx.x;
  int v = blockSums[t];
  sd[t] = v;
  __syncthreads();
  for (int off = 1; off < 128; off <<= 1) {
    int add = (t >= off) ? sd[t - off] : 0;
    __syncthreads();
    sd[t] += add;
    __syncthreads();
  }
  blockOff[t] = sd[t] - v;
  if (t == 127) rowptr[N_NODES] = sd[t];
}

__global__ __launch_bounds__(256) void k_scan3(const int* __restrict__ partial,
                                               const int* __restrict__ blockOff,
                                               int* __restrict__ rowptr,
                                               int* __restrict__ fill,
                                               int* __restrict__ col) {
  int i = blockIdx.x * 256 + threadIdx.x;
  int rp = partial[i] + blockOff[blockIdx.x];
  rowptr[i] = rp;
  fill[i] = 1;
  col[rp] = i;
}

__global__ void k_scatter(const int* __restrict__ src, const int* __restrict__ dst,
                          const int* __restrict__ rowptr, int* __restrict__ fill,
                          int* __restrict__ col, int E) {
  int i = blockIdx.x * 256 + threadIdx.x;
  if (i < E) {
    int d = dst[i];
    int pos = rowptr[d] + atomicAdd(&fill[d], 1);
    col[pos] = src[i];
  }
}

// ---------------- fused conversions + deg init ----------------
__global__ void k_convert(
    const float* __restrict__ x,  half_t* __restrict__ x_h,
    const float* __restrict__ W1, half_t* __restrict__ W1t,
    const float* __restrict__ W2, half_t* __restrict__ W2t,
    const float* __restrict__ W3, half_t* __restrict__ W3t,
    const float* __restrict__ Wi, half_t* __restrict__ Wi_h,
    const float* __restrict__ Wo, half_t* __restrict__ Wo_h,
    int* __restrict__ deg)
{
  int bid = blockIdx.x, t = threadIdx.x;
  if (bid < 16384) {
    int i = bid * 256 + t;
    x_h[i] = (half_t)x[i];
  } else if (bid < 16512) {
    int i = (bid - 16384) * 256 + t;
    int o = i >> 7, k = i & 127;
    W1t[i] = (half_t)W1[k * 256 + o];
  } else if (bid < 16768) {
    int i = (bid - 16512) * 256 + t;
    int o = i >> 8, k = i & 255;
    W2t[i] = (half_t)W2[k * 256 + o];
  } else if (bid < 16896) {
    int i = (bid - 16768) * 256 + t;
    int o = i >> 8, k = i & 255;
    W3t[i] = (half_t)W3[k * 128 + o];
  } else if (bid < 17664) {
    int i = (bid - 16896) * 256 + t;
    Wi_h[i] = (half_t)Wi[i];
  } else if (bid < 17920) {
    int i = (bid - 17664) * 256 + t;
    Wo_h[i] = (half_t)Wo[i];
  } else {
    deg[(bid - 17920) * 256 + t] = 1;
  }
}

// ---------------- residency-first GEMM (no epilogue): tile 128x64, BK=64 ----------------
__global__ __launch_bounds__(256) void k_gemm_wide(
    const half_t* __restrict__ A, const half_t* __restrict__ Bt,
    const float* __restrict__ bias, int bias_per_row,
    half_t* __restrict__ outh, int M, int Nc, int K)
{
  __shared__ __align__(16) half_t As[128 * 64];
  __shared__ __align__(16) half_t Bs[64 * 64];
  int w = threadIdx.x >> 6, lane = threadIdx.x & 63;
  int r = lane & 15, q = lane >> 4;
  int m0 = blockIdx.y * 128, n0 = blockIdx.x * 64;
  int mh = (w & 1) * 64, nh = (w >> 1) * 32;
  f32x4 acc[4][2];
  #pragma unroll
  for (int i = 0; i < 4; i++)
    #pragma unroll
    for (int j = 0; j < 2; j++) acc[i][j] = f32x4{0.f, 0.f, 0.f, 0.f};

  int srow = lane >> 3, sc = lane & 7;

  for (int k0 = 0; k0 < K; k0 += 64) {
    __syncthreads();
    #pragma unroll
    for (int i = 0; i < 4; i++) {
      int R0 = w * 32 + i * 8;
      int row = R0 + srow;
      int cg = sc ^ (row & 7);
      gload_lds16(A + (size_t)(m0 + row) * K + k0 + cg * 8, &As[R0 * 64]);
    }
    #pragma unroll
    for (int i = 0; i < 2; i++) {
      int R0 = w * 16 + i * 8;
      int row = R0 + srow;
      int cg = sc ^ (row & 7);
      gload_lds16(Bt + (size_t)(n0 + row) * K + k0 + cg * 8, &Bs[R0 * 64]);
    }
    __syncthreads();
    #pragma unroll
    for (int kk = 0; kk < 2; kk++) {
      half8 af[4], bf[2];
      #pragma unroll
      for (int t = 0; t < 4; t++) {
        int rr = mh + t * 16 + r;
        af[t] = *(const half8*)&As[rr * 64 + (((kk * 4 + q) ^ (rr & 7)) << 3)];
      }
      #pragma unroll
      for (int t = 0; t < 2; t++) {
        int rr = nh + t * 16 + r;
        bf[t] = *(const half8*)&Bs[rr * 64 + (((kk * 4 + q) ^ (rr & 7)) << 3)];
      }
      #pragma unroll
      for (int ti = 0; ti < 4; ti++)
        #pragma unroll
        for (int tj = 0; tj < 2; tj++)
          acc[ti][tj] = MFMA16(af[ti], bf[tj], acc[ti][tj]);
    }
  }

  #pragma unroll
  for (int tj = 0; tj < 2; tj++) {
    int colc = n0 + nh + tj * 16 + r;
    float bc = bias_per_row ? 0.f : bias[colc];
    #pragma unroll
    for (int ti = 0; ti < 4; ti++) {
      #pragma unroll
      for (int i = 0; i < 4; i++) {
        int row = m0 + mh + ti * 16 + q * 4 + i;
        float bv = bias_per_row ? bias[row] : bc;
        outh[(size_t)row * Nc + colc] = (half_t)(acc[ti][tj][i] + bv);
      }
    }
  }
}

// ---------------- residency-first GAT GEMM: 128x64 tile + fused es/ed ----------------
// FP8O: emit h as OCP fp8 e4m3 bytes; es/ed always from exact fp32 accumulators.
template<int NC, int H, bool FP8O>
__global__ __launch_bounds__(256) void k_gemm_gat(
    const half_t* __restrict__ A, const half_t* __restrict__ Bt,
    half_t* __restrict__ outh, unsigned char* __restrict__ out8, int K,
    const float* __restrict__ aS, const float* __restrict__ aD,
    float* __restrict__ es, float* __restrict__ ed)
{
  __shared__ __align__(16) half_t As[128 * 64];
  __shared__ __align__(16) half_t Bs[64 * 64];
  __shared__ float sRed[2][4][64];
  int w = threadIdx.x >> 6, lane = threadIdx.x & 63;
  int cc = lane & 15, qq = lane >> 4;
  int m0 = blockIdx.y * 128, n0 = blockIdx.x * 64;
  int mh = (w & 1) * 64, nh = (w >> 1) * 32;
  f32x4 acc[4][2];
  #pragma unroll
  for (int i = 0; i < 4; i++)
    #pragma unroll
    for (int j = 0; j < 2; j++) acc[i][j] = f32x4{0.f, 0.f, 0.f, 0.f};

  int srow = lane >> 3, sc = lane & 7;

  for (int k0 = 0; k0 < K; k0 += 64) {
    __syncthreads();
    #pragma unroll
    for (int i = 0; i < 4; i++) {
      int R0 = w * 32 + i * 8;
      int row = R0 + srow;
      int cg = sc ^ (row & 7);
      gload_lds16(A + (size_t)(m0 + row) * K + k0 + cg * 8, &As[R0 * 64]);
    }
    #pragma unroll
    for (int i = 0; i < 2; i++) {
      int R0 = w * 16 + i * 8;
      int row = R0 + srow;
      int cg = sc ^ (row & 7);
      gload_lds16(Bt + (size_t)(n0 + row) * K + k0 + cg * 8, &Bs[R0 * 64]);
    }
    __syncthreads();
    #pragma unroll
    for (int kk = 0; kk < 2; kk++) {
      half8 af[4], bf[2];
      #pragma unroll
      for (int t = 0; t < 4; t++) {
        int rr = mh + t * 16 + cc;
        af[t] = *(const half8*)&As[rr * 64 + (((kk * 4 + qq) ^ (rr & 7)) << 3)];
      }
      #pragma unroll
      for (int t = 0; t < 2; t++) {
        int rr = nh + t * 16 + cc;
        bf[t] = *(const half8*)&Bs[rr * 64 + (((kk * 4 + qq) ^ (rr & 7)) << 3)];
      }
      #pragma unroll
      for (int ti = 0; ti < 4; ti++)
        #pragma unroll
        for (int tj = 0; tj < 2; tj++)
          acc[ti][tj] = MFMA16(af[ti], bf[tj], acc[ti][tj]);
    }
  }

  float aSv[2], aDv[2];
  #pragma unroll
  for (int tj = 0; tj < 2; tj++) {
    int colg = n0 + nh + tj * 16 + cc;
    aSv[tj] = aS[colg];
    aDv[tj] = aD[colg];
  }
  #pragma unroll
  for (int ti = 0; ti < 4; ti++) {
    #pragma unroll
    for (int i = 0; i < 4; i++) {
      int rloc = mh + ti * 16 + qq * 4 + i;      // 0..127
      float ps = 0.f, pd = 0.f;
      #pragma unroll
      for (int tj = 0; tj < 2; tj++) {
        int colg = n0 + nh + tj * 16 + cc;
        float v = acc[ti][tj][i];
        if (FP8O) {
          int pk = __builtin_amdgcn_cvt_pk_fp8_f32(v, v, 0, false);
          out8[(size_t)(m0 + rloc) * NC + colg] = (unsigned char)pk;
        } else {
          outh[(size_t)(m0 + rloc) * NC + colg] = (half_t)v;
        }
        ps += v * aSv[tj];
        pd += v * aDv[tj];
      }
      #pragma unroll
      for (int off = 1; off < 16; off <<= 1) {
        ps += __shfl_xor(ps, off);
        pd += __shfl_xor(pd, off);
      }
      if (cc == 0) {
        sRed[0][w][ti * 16 + qq * 4 + i] = ps;
        sRed[1][w][ti * 16 + qq * 4 + i] = pd;
      }
    }
  }
  __syncthreads();
  if (threadIdx.x < 128) {
    int row = threadIdx.x;
    int wlo = row >> 6, ri = row & 63;
    float ps = sRed[0][wlo][ri] + sRed[0][wlo + 2][ri];
    float pd = sRed[1][wlo][ri] + sRed[1][wlo + 2][ri];
    if (H == 4) {
      int head = n0 >> 6;
      es[(size_t)(m0 + row) * 4 + head] = ps;
      ed[(size_t)(m0 + row) * 4 + head] = pd;
    } else {
      atomicAdd(&es[m0 + row], ps);
      atomicAdd(&ed[m0 + row], pd);
    }
  }
}

// ---------------- fused Wo-GEMM + residual + LayerNorm (+ es/ed zeroing) ----------------
__global__ __launch_bounds__(256) void k_gemm_ln(
    const half_t* __restrict__ A, const half_t* __restrict__ Bt,
    const float* __restrict__ bias, const half_t* __restrict__ res,
    const float* __restrict__ gamma, const float* __restrict__ beta,
    half_t* __restrict__ outh, float* __restrict__ es0, float* __restrict__ ed0)
{
  __shared__ __align__(16) half_t As[64 * 64];
  __shared__ __align__(16) half_t Bs[256 * 64];
  __shared__ float sSum[4][64], sSq[4][64];
  __shared__ float sMR[64][2];
  int w = threadIdx.x >> 6, lane = threadIdx.x & 63;
  int r = lane & 15, q = lane >> 4;
  int m0 = blockIdx.x * 64;
  int nh = w * 64;

  if (threadIdx.x < 64) es0[m0 + threadIdx.x] = 0.f;
  else if (threadIdx.x < 128) ed0[m0 + threadIdx.x - 64] = 0.f;

  f32x4 acc[4][4];
  #pragma unroll
  for (int i = 0; i < 4; i++)
    #pragma unroll
    for (int j = 0; j < 4; j++) acc[i][j] = f32x4{0.f, 0.f, 0.f, 0.f};

  int srow = lane >> 3, sc = lane & 7;

  for (int k0 = 0; k0 < 256; k0 += 64) {
    __syncthreads();
    #pragma unroll
    for (int i = 0; i < 2; i++) {
      int R0 = w * 16 + i * 8;
      int row = R0 + srow;
      int cg = sc ^ (row & 7);
      gload_lds16(A + (size_t)(m0 + row) * 256 + k0 + cg * 8, &As[R0 * 64]);
    }
    #pragma unroll
    for (int i = 0; i < 8; i++) {
      int R0 = w * 64 + i * 8;
      int row = R0 + srow;
      int cg = sc ^ (row & 7);
      gload_lds16(Bt + (size_t)row * 256 + k0 + cg * 8, &Bs[R0 * 64]);
    }
    __syncthreads();
    #pragma unroll
    for (int kk = 0; kk < 2; kk++) {
      half8 af[4], bf[4];
      #pragma unroll
      for (int t = 0; t < 4; t++) {
        int rr = t * 16 + r;
        af[t] = *(const half8*)&As[rr * 64 + (((kk * 4 + q) ^ (rr & 7)) << 3)];
      }
      #pragma unroll
      for (int t = 0; t < 4; t++) {
        int rr = nh + t * 16 + r;
        bf[t] = *(const half8*)&Bs[rr * 64 + (((kk * 4 + q) ^ (rr & 7)) << 3)];
      }
      #pragma unroll
      for (int ti = 0; ti < 4; ti++)
        #pragma unroll
        for (int tj = 0; tj < 4; tj++)
          acc[ti][tj] = MFMA16(af[ti], bf[tj], acc[ti][tj]);
    }
  }

  float gv[4], bv[4];
  #pragma unroll
  for (int tj = 0; tj < 4; tj++) {
    int col = nh + tj * 16 + r;
    gv[tj] = gamma[col];
    bv[tj] = beta[col];
  }
  #pragma unroll
  for (int ti = 0; ti < 4; ti++) {
    #pragma unroll
    for (int i = 0; i < 4; i++) {
      int row = ti * 16 + q * 4 + i;
      float s = 0.f, ss = 0.f;
      #pragma unroll
      for (int tj = 0; tj < 4; tj++) {
        int col = nh + tj * 16 + r;
        float v = acc[ti][tj][i] + bias[col]
                + (float)res[(size_t)(m0 + row) * 256 + col];
        acc[ti][tj][i] = v;
        s += v;
        ss += v * v;
      }
      #pragma unroll
      for (int off = 1; off < 16; off <<= 1) {
        s  += __shfl_xor(s, off);
        ss += __shfl_xor(ss, off);
      }
      if (r == 0) { sSum[w][row] = s; sSq[w][row] = ss; }
    }
  }
  __syncthreads();
  if (threadIdx.x < 64) {
    int row = threadIdx.x;
    float s  = sSum[0][row] + sSum[1][row] + sSum[2][row] + sSum[3][row];
    float ss = sSq[0][row] + sSq[1][row] + sSq[2][row] + sSq[3][row];
    float mean = s * (1.f / 256.f);
    float var  = ss * (1.f / 256.f) - mean * mean;
    sMR[row][0] = mean;
    sMR[row][1] = rsqrtf(var + 1e-5f);
  }
  __syncthreads();
  #pragma unroll
  for (int ti = 0; ti < 4; ti++) {
    #pragma unroll
    for (int i = 0; i < 4; i++) {
      int row = ti * 16 + q * 4 + i;
      float mean = sMR[row][0], rstd = sMR[row][1];
      #pragma unroll
      for (int tj = 0; tj < 4; tj++) {
        int col = nh + tj * 16 + r;
        outh[(size_t)(m0 + row) * 256 + col] =
            (half_t)((acc[ti][tj][i] - mean) * rstd * gv[tj] + bv[tj]);
      }
    }
  }
}

// ---------------- fp16-gather aggregation (HC=256, H=4, fp16 acc, ELU) ----------------
__global__ __launch_bounds__(256) void k_agg_f16(
    const half_t* __restrict__ h, const float* __restrict__ es,
    const float* __restrict__ ed, const float* __restrict__ bias,
    const int* __restrict__ rowptr, const int* __restrict__ col,
    half_t* __restrict__ outh)
{
  int lane = threadIdx.x & 63;
  int g = lane >> 4, li = lane & 15;
  int n = blockIdx.x * 4 + (threadIdx.x >> 6);
  int cbase = li * 16;
  int hl = li >> 2;
  float edn = ed[(size_t)n * 4 + hl];
  int j0 = rowptr[n], j1 = rowptr[n + 1];
  const half_t* hb = h + cbase;

  float sum0 = 0.f, sum1 = 0.f;
  half8 acc0[2], acc1[2];
  #pragma unroll
  for (int i = 0; i < 2; i++) {
    acc0[i] = half8{0, 0, 0, 0, 0, 0, 0, 0};
    acc1[i] = half8{0, 0, 0, 0, 0, 0, 0, 0};
  }
  for (int j = j0 + g; j < j1; j += 8) {
    int jb = j + 4;
    int s0 = col[j];
    int s1 = col[(jb < j1) ? jb : j];
    float e0 = es[(size_t)s0 * 4 + hl] + edn;
    e0 = fmaxf(e0, 0.2f * e0);
    float e1 = es[(size_t)s1 * 4 + hl] + edn;
    e1 = fmaxf(e1, 0.2f * e1);
    e1 = (jb < j1) ? e1 : -1e30f;
    const half_t* hp0 = hb + (size_t)s0 * 256;
    const half_t* hp1 = hb + (size_t)s1 * 256;
    float p0 = exp2f(e0 * 1.44269504f - 8.65617025f);
    float p1 = exp2f(e1 * 1.44269504f - 8.65617025f);
    sum0 += p0; sum1 += p1;
    half_t q0 = (half_t)p0, q1 = (half_t)p1;
    half8 pv0 = {q0, q0, q0, q0, q0, q0, q0, q0};
    half8 pv1 = {q1, q1, q1, q1, q1, q1, q1, q1};
    #pragma unroll
    for (int i = 0; i < 2; i++) {
      half8 v0 = *(const half8*)(hp0 + i * 8);
      half8 v1 = *(const half8*)(hp1 + i * 8);
      acc0[i] += pv0 * v0;
      acc1[i] += pv1 * v1;
    }
  }
  float sum = sum0 + sum1;
  sum += __shfl_xor(sum, 16);
  sum += __shfl_xor(sum, 32);
  float av[16];
  #pragma unroll
  for (int i = 0; i < 16; i++) {
    av[i] = (float)acc0[i >> 3][i & 7] + (float)acc1[i >> 3][i & 7];
    av[i] += __shfl_xor(av[i], 16);
    av[i] += __shfl_xor(av[i], 32);
  }
  float inv = 1.f / sum;
  if (g == 0) {
    size_t obase = (size_t)n * 256 + cbase;
    #pragma unroll
    for (int p8 = 0; p8 < 2; p8++) {
      half8 hv;
      #pragma unroll
      for (int i = 0; i < 8; i++) {
        float t = av[p8 * 8 + i] * inv + bias[cbase + p8 * 8 + i];
        t = (t > 0.f) ? t : __expf(t) - 1.f;     // jax.nn.elu
        hv[i] = (half_t)t;
      }
      *(half8*)(outh + obase + p8 * 8) = hv;
    }
  }
}

// ---------------- fp8-gather aggregation (HC=256, H=4, ELU) ----------------
__global__ __launch_bounds__(256) void k_agg_fp8(
    const unsigned char* __restrict__ hq, const float* __restrict__ es,
    const float* __restrict__ ed, const float* __restrict__ bias,
    const int* __restrict__ rowptr, const int* __restrict__ col,
    half_t* __restrict__ outh)
{
  int lane = threadIdx.x & 63;
  int g = lane >> 4, li = lane & 15;
  int n = blockIdx.x * 4 + (threadIdx.x >> 6);
  int cbase = li * 16;
  int hl = li >> 2;
  float edn = ed[(size_t)n * 4 + hl];
  int j0 = rowptr[n], j1 = rowptr[n + 1];
  const unsigned char* hb = hq + cbase;

  float sum0 = 0.f, sum1 = 0.f;
  half2v a0[8], a1[8];
  #pragma unroll
  for (int i = 0; i < 8; i++) { a0[i] = half2v{0, 0}; a1[i] = half2v{0, 0}; }

  for (int j = j0 + g; j < j1; j += 8) {
    int jb = j + 4;
    int s0 = col[j];
    int s1 = col[(jb < j1) ? jb : j];
    float e0 = es[(size_t)s0 * 4 + hl] + edn;
    e0 = fmaxf(e0, 0.2f * e0);
    float e1 = es[(size_t)s1 * 4 + hl] + edn;
    e1 = fmaxf(e1, 0.2f * e1);
    e1 = (jb < j1) ? e1 : -1e30f;
    int4 d0 = *(const int4*)(hb + (size_t)s0 * 256);
    int4 d1 = *(const int4*)(hb + (size_t)s1 * 256);
    float p0 = exp2f(e0 * 1.44269504f - 8.65617025f);
    float p1 = exp2f(e1 * 1.44269504f - 8.65617025f);
    sum0 += p0; sum1 += p1;
    half_t q0 = (half_t)p0, q1 = (half_t)p1;
    half2v pv0 = {q0, q0}, pv1 = {q1, q1};
    fp8x4_fma(d0.x, pv0, &a0[0]); fp8x4_fma(d0.y, pv0, &a0[2]);
    fp8x4_fma(d0.z, pv0, &a0[4]); fp8x4_fma(d0.w, pv0, &a0[6]);
    fp8x4_fma(d1.x, pv1, &a1[0]); fp8x4_fma(d1.y, pv1, &a1[2]);
    fp8x4_fma(d1.z, pv1, &a1[4]); fp8x4_fma(d1.w, pv1, &a1[6]);
  }

  float sum = sum0 + sum1;
  sum += __shfl_xor(sum, 16);
  sum += __shfl_xor(sum, 32);
  float av[16];
  #pragma unroll
  for (int i = 0; i < 16; i++) {
    av[i] = (float)a0[i >> 1][i & 1] + (float)a1[i >> 1][i & 1];
    av[i] += __shfl_xor(av[i], 16);
    av[i] += __shfl_xor(av[i], 32);
  }
  float inv = 1.f / sum;
  if (g == 0) {
    size_t obase = (size_t)n * 256 + cbase;
    #pragma unroll
    for (int p8 = 0; p8 < 2; p8++) {
      half8 hv;
      #pragma unroll
      for (int i = 0; i < 8; i++) {
        float t = av[p8 * 8 + i] * inv + bias[cbase + p8 * 8 + i];
        t = (t > 0.f) ? t : __expf(t) - 1.f;
        hv[i] = (half_t)t;
      }
      *(half8*)(outh + obase + p8 * 8) = hv;
    }
  }
}

// ---------------- fp16-gather aggregation (GAT3: HC=128, H=1, fp32 acc) ----------------
__global__ __launch_bounds__(256) void k_agg3(
    const half_t* __restrict__ h, const float* __restrict__ es,
    const float* __restrict__ ed, const float* __restrict__ bias,
    const int* __restrict__ rowptr, const int* __restrict__ col,
    float* __restrict__ outf)
{
  constexpr int VPT = 8;
  int lane = threadIdx.x & 63;
  int g = lane >> 4, li = lane & 15;
  int n = blockIdx.x * 4 + (threadIdx.x >> 6);
  int cbase = li * VPT;
  float edn = ed[n];
  int j0 = rowptr[n], j1 = rowptr[n + 1];
  const half_t* hb = h + cbase;

  float sum0 = 0.f, sum1 = 0.f;
  float acc0[VPT], acc1[VPT];
  #pragma unroll
  for (int i = 0; i < VPT; i++) { acc0[i] = 0.f; acc1[i] = 0.f; }
  for (int j = j0 + g; j < j1; j += 8) {
    int jb = j + 4;
    int s0 = col[j];
    int s1 = col[(jb < j1) ? jb : j];
    float e0 = es[s0] + edn;
    e0 = fmaxf(e0, 0.2f * e0);
    float e1 = es[s1] + edn;
    e1 = fmaxf(e1, 0.2f * e1);
    e1 = (jb < j1) ? e1 : -1e30f;
    const half_t* hp0 = hb + (size_t)s0 * 128;
    const half_t* hp1 = hb + (size_t)s1 * 128;
    float p0 = __expf(e0), p1 = __expf(e1);
    sum0 += p0; sum1 += p1;
    half8 v0 = *(const half8*)hp0;
    half8 v1 = *(const half8*)hp1;
    #pragma unroll
    for (int i = 0; i < 8; i++) {
      acc0[i] += p0 * (float)v0[i];
      acc1[i] += p1 * (float)v1[i];
    }
  }
  float sum = sum0 + sum1;
  sum += __shfl_xor(sum, 16);
  sum += __shfl_xor(sum, 32);
  float av[VPT];
  #pragma unroll
  for (int i = 0; i < VPT; i++) {
    av[i] = acc0[i] + acc1[i];
    av[i] += __shfl_xor(av[i], 16);
    av[i] += __shfl_xor(av[i], 32);
  }
  float inv = 1.f / sum;
  if (g == 0) {
    size_t obase = (size_t)n * 128 + cbase;
    #pragma unroll
    for (int p4 = 0; p4 < 2; p4++) {
      float4 fv = {av[p4 * 4] * inv + bias[cbase + p4 * 4],
                   av[p4 * 4 + 1] * inv + bias[cbase + p4 * 4 + 1],
                   av[p4 * 4 + 2] * inv + bias[cbase + p4 * 4 + 2],
                   av[p4 * 4 + 3] * inv + bias[cbase + p4 * 4 + 3]};
      *(float4*)(outf + obase + p4 * 4) = fv;
    }
  }
}

// ---------------- MHA core (R9 known-good: 64-key tiles, 25 KB LDS) ----------------
__global__ __launch_bounds__(256) void k_attn(
    const half_t* __restrict__ qk, const half_t* __restrict__ vt,
    half_t* __restrict__ o)
{
  __shared__ __align__(16) half_t Kt[64 * 64];
  __shared__ __align__(16) half_t Vt[64 * 64];
  __shared__ __align__(16) half_t Pb[4][16][72];

  int pair = blockIdx.x;
  int b = pair >> 2, hh = pair & 3;
  int q0 = blockIdx.y * 64;
  int w = threadIdx.x >> 6, lane = threadIdx.x & 63;
  int cc = lane & 15, qq = lane >> 4;

  const half_t* Qp = qk + ((size_t)(b * NPG_ + q0 + w * 16 + cc) * 512 + hh * 64);
  half8 qa0 = *(const half8*)(Qp + qq * 8);
  half8 qa1 = *(const half8*)(Qp + 32 + qq * 8);

  f32x4 oacc[4];
  #pragma unroll
  for (int t = 0; t < 4; t++) oacc[t] = f32x4{0.f, 0.f, 0.f, 0.f};
  float rs = 0.f;

  const half_t* kb = qk + ((size_t)(b * NPG_) * 512 + 256 + hh * 64);
  const half_t* vb = vt + ((size_t)(hh * 64) * 32768 + b * NPG_);

  int krow = lane >> 3, ksl = lane & 7;

  for (int kt = 0; kt < 8; kt++) {
    __syncthreads();
    #pragma unroll
    for (int i = 0; i < 2; i++) {
      int R = w * 16 + i * 8;
      int kr = R + krow;
      gload_lds16(kb + (size_t)(kt * 64 + kr) * 512 + ((ksl ^ (kr & 7)) * 8),
                  &Kt[R * 64]);
      gload_lds16(vb + (size_t)kr * 32768 + kt * 64 + ((ksl ^ (kr & 7)) * 8),
                  &Vt[R * 64]);
    }
    __syncthreads();

    #pragma unroll
    for (int mt = 0; mt < 4; mt++) {
      int key = mt * 16 + cc;
      half8 k0 = *(const half8*)&Kt[key * 64 + ((qq ^ (key & 7)) << 3)];
      half8 k1 = *(const half8*)&Kt[key * 64 + (((qq + 4) ^ (key & 7)) << 3)];
      f32x4 s = f32x4{0.f, 0.f, 0.f, 0.f};
      s = MFMA16(k0, qa0, s);
      s = MFMA16(k1, qa1, s);
      half4v ph;
      #pragma unroll
      for (int i = 0; i < 4; i++) {
        float p = exp2f(s[i] * 0.180336886f - 11.54156033f);
        rs += p;
        ph[i] = (half_t)p;
      }
      *(half4v*)&Pb[w][cc][mt * 16 + qq * 4] = ph;
    }

    #pragma unroll
    for (int kc = 0; kc < 2; kc++) {
      half8 a = *(const half8*)&Pb[w][cc][kc * 32 + qq * 8];
      #pragma unroll
      for (int nt = 0; nt < 4; nt++) {
        int d = nt * 16 + cc;
        half8 bb = *(const half8*)&Vt[d * 64 + (((kc * 4 + qq) ^ (d & 7)) << 3)];
        oacc[nt] = MFMA16(a, bb, oacc[nt]);
      }
    }
  }

  rs += __shfl_xor(rs, 16);
  rs += __shfl_xor(rs, 32);
  #pragma unroll
  for (int i = 0; i < 4; i++) {
    float rsv = __shfl(rs, qq * 4 + i);
    float inv = 1.f / rsv;
    int node = b * NPG_ + q0 + w * 16 + qq * 4 + i;
    #pragma unroll
    for (int nt = 0; nt < 4; nt++)
      o[(size_t)node * 256 + hh * 64 + nt * 16 + cc] = (half_t)(oacc[nt][i] * inv);
  }
}

// ---------------- host ----------------
extern "C" void kernel_launch(void* const* d_in, const int* in_sizes, int n_in,
                              void* d_out, int out_size, void* d_ws, size_t ws_size,
                              hipStream_t stream)
{
  const float* x    = (const float*)d_in[0];
  const int*   ei   = (const int*)d_in[1];
  const float* W1   = (const float*)d_in[3];
  const float* aS1  = (const float*)d_in[4];
  const float* aD1  = (const float*)d_in[5];
  const float* b1   = (const float*)d_in[6];
  const float* W2   = (const float*)d_in[7];
  const float* aS2  = (const float*)d_in[8];
  const float* aD2  = (const float*)d_in[9];
  const float* b2   = (const float*)d_in[10];
  const float* W3   = (const float*)d_in[11];
  const float* aS3  = (const float*)d_in[12];
  const float* aD3  = (const float*)d_in[13];
  const float* b3   = (const float*)d_in[14];
  const float* Wi   = (const float*)d_in[15];
  const float* bi   = (const float*)d_in[16];
  const float* Wo   = (const float*)d_in[17];
  const float* bo   = (const float*)d_in[18];
  const float* gam  = (const float*)d_in[19];
  const float* bet  = (const float*)d_in[20];
  float* out = (float*)d_out;
  const int N = N_NODES;
  int E = in_sizes[1] / 2;

  char* ws = (char*)d_ws;
  size_t off = 0;
  auto alloc = [&](size_t bytes) -> void* {
    void* p = ws + off;
    off = (off + bytes + 255) & ~(size_t)255;
    return p;
  };
  half_t* x_h    = (half_t*)alloc((size_t)N * 128 * 2);
  half_t* h_h    = (half_t*)alloc((size_t)N * 256 * 2);   // h1 / h3 (fp16)
  unsigned char* hq = (unsigned char*)alloc((size_t)N * 256);  // h2 (fp8)
  half_t* x1_h   = (half_t*)alloc((size_t)N * 256 * 2);
  half_t* x2_h   = (half_t*)alloc((size_t)N * 256 * 2);
  half_t* qk_h   = (half_t*)alloc((size_t)N * 512 * 2);
  half_t* vt_h   = (half_t*)alloc((size_t)256 * N * 2);   // V^T: [256][32768]
  half_t* o_h    = (half_t*)alloc((size_t)N * 256 * 2);
  half_t* x2a_h  = (half_t*)alloc((size_t)N * 256 * 2);
  half_t* W1t    = (half_t*)alloc(256 * 128 * 2);
  half_t* W2t    = (half_t*)alloc(256 * 256 * 2);
  half_t* W3t    = (half_t*)alloc(128 * 256 * 2);
  half_t* Wi_h   = (half_t*)alloc(768 * 256 * 2);
  half_t* Wo_h   = (half_t*)alloc(256 * 256 * 2);
  float*  es     = (float*) alloc((size_t)N * 4 * 4);
  float*  ed     = (float*) alloc((size_t)N * 4 * 4);
  int*    deg    = (int*)   alloc((size_t)N * 4);
  int*    fill   = (int*)   alloc((size_t)N * 4);
  int*    rowptr = (int*)   alloc(((size_t)N + 1) * 4);
  int*    col    = (int*)   alloc((size_t)(N + E) * 4);
  int*    part   = (int*)   alloc((size_t)N * 4);
  int*    bsum   = (int*)   alloc(128 * 4);
  int*    boff   = (int*)   alloc(128 * 4);

  const int* srcE = ei;
  const int* dstE = ei + E;

  // conversions + deg init (one launch), then parallel CSR build
  k_convert<<<18048, 256, 0, stream>>>(x, x_h, W1, W1t, W2, W2t, W3, W3t,
                                       Wi, Wi_h, Wo, Wo_h, deg);
  k_hist<<<(E + 255) / 256, 256, 0, stream>>>(dstE, deg, E);
  k_scan1<<<128, 256, 0, stream>>>(deg, part, bsum);
  k_scan2<<<1, 128, 0, stream>>>(bsum, boff, rowptr);
  k_scan3<<<128, 256, 0, stream>>>(part, boff, rowptr, fill, col);
  k_scatter<<<(E + 255) / 256, 256, 0, stream>>>(srcE, dstE, rowptr, fill, col, E);

  // ---- GAT1 (fp16 path, R13-proven): h1 + es/ed ; fp16 aggregate + ELU -> x1 ----
  k_gemm_gat<256, 4, false><<<dim3(4, N / 128), 256, 0, stream>>>(
      x_h, W1t, h_h, nullptr, 128, aS1, aD1, es, ed);
  k_agg_f16<<<N / 4, 256, 0, stream>>>(h_h, es, ed, b1, rowptr, col, x1_h);

  // ---- GAT2 (fp8 gather path): h2 (fp8) + es/ed ; fp8 aggregate -> x2 ----
  k_gemm_gat<256, 4, true><<<dim3(4, N / 128), 256, 0, stream>>>(
      x1_h, W2t, nullptr, hq, 256, aS2, aD2, es, ed);
  k_agg_fp8<<<N / 4, 256, 0, stream>>>(hq, es, ed, b2, rowptr, col, x2_h);

  // ---- MHA: residency-first GEMMs for QK and V^T projections ----
  k_gemm_wide<<<dim3(8, N / 128), 256, 0, stream>>>(x2_h, Wi_h, bi, 0, qk_h,
                                                    N, 512, 256);
  k_gemm_wide<<<dim3(N / 64, 2), 256, 0, stream>>>(Wi_h + 512 * 256, x2_h, bi + 512, 1,
                                                   vt_h, 256, N, 256);
  k_attn<<<dim3(256, 8), 256, 0, stream>>>(qk_h, vt_h, o_h);

  // ---- Wo-GEMM + residual + LayerNorm fused -> x2a; also zeroes es/ed ----
  k_gemm_ln<<<N / 64, 256, 0, stream>>>(o_h, Wo_h, bo, x2_h, gam, bet, x2a_h, es, ed);

  // ---- GAT3 (H=1, C=128, fp16 h, fp32 acc; atomic es/ed partials) -> d_out ----
  k_gemm_gat<128, 1, false><<<dim3(2, N / 128), 256, 0, stream>>>(
      x2a_h, W3t, h_h, nullptr, 256, aS3, aD3, es, ed);
  k_agg3<<<N / 4, 256, 0, stream>>>(h_h, es, ed, b3, rowptr, col, out);
}

// Round 16
// 396.980 us; speedup vs baseline: 1.1812x; 1.0186x over previous
//
#include <hip/hip_runtime.h>

typedef _Float16 half_t;
typedef _Float16 half8  __attribute__((ext_vector_type(8)));
typedef _Float16 half4v __attribute__((ext_vector_type(4)));
typedef _Float16 half2v __attribute__((ext_vector_type(2)));
typedef float    f32x4  __attribute__((ext_vector_type(4)));
typedef float    f32x2  __attribute__((ext_vector_type(2)));

constexpr int N_NODES = 32768;
constexpr int NPG_    = 512;

#define MFMA16(a, b, c) __builtin_amdgcn_mfma_f32_16x16x32_f16((a), (b), (c), 0, 0, 0)

#if defined(__has_builtin)
#  if __has_builtin(__builtin_amdgcn_cvt_pk_f16_fp8)
#    define HAVE_PK_F16_FP8 1
#  else
#    define HAVE_PK_F16_FP8 0
#  endif
#else
#  define HAVE_PK_F16_FP8 0
#endif

__device__ __forceinline__ void gload_lds16(const half_t* g, half_t* l) {
  __builtin_amdgcn_global_load_lds(
      (const __attribute__((address_space(1))) void*)g,
      (__attribute__((address_space(3))) void*)l, 16, 0, 0);
}

// decode 4 fp8 (one dword) and fma into 2 half2 accumulators with weight p
__device__ __forceinline__ void fp8x4_fma(int wrd, half2v p, half2v* acc) {
#if HAVE_PK_F16_FP8
  half2v lo = __builtin_amdgcn_cvt_pk_f16_fp8((short)(wrd & 0xffff));
  half2v hi = __builtin_amdgcn_cvt_pk_f16_fp8((short)(((unsigned)wrd) >> 16));
#else
  f32x2 flo = __builtin_amdgcn_cvt_pk_f32_fp8(wrd, false);
  f32x2 fhi = __builtin_amdgcn_cvt_pk_f32_fp8(wrd, true);
  half2v lo = {(half_t)flo.x, (half_t)flo.y};
  half2v hi = {(half_t)fhi.x, (half_t)fhi.y};
#endif
  acc[0] += p * lo;
  acc[1] += p * hi;
}

// ---------------- CSR build ----------------
__global__ void k_hist(const int* __restrict__ dst, int* __restrict__ deg, int E) {
  int i = blockIdx.x * 256 + threadIdx.x;
  if (i < E) atomicAdd(&deg[dst[i]], 1);
}

__global__ __launch_bounds__(256) void k_scan1(const int* __restrict__ deg,
                                               int* __restrict__ partial,
                                               int* __restrict__ blockSums) {
  __shared__ int sd[256];
  int t = threadIdx.x;
  int i = blockIdx.x * 256 + t;
  int v = deg[i];
  sd[t] = v;
  __syncthreads();
  int acc = v;
  for (int off = 1; off < 256; off <<= 1) {
    int add = (t >= off) ? sd[t - off] : 0;
    __syncthreads();
    acc += add;
    sd[t] = acc;
    __syncthreads();
  }
  partial[i] = acc - v;
  if (t == 255) blockSums[blockIdx.x] = acc;
}

__global__ __launch_bounds__(128) void k_scan2(const int* __restrict__ blockSums,
                                               int* __restrict__ blockOff,
                                               int* __restrict__ rowptr) {
  __shared__ int sd[128];
  int t = threadIdx.x;
  int v = blockSums[t];
  sd[t] = v;
  __syncthreads();
  for (int off = 1; off < 128; off <<= 1) {
    int add = (t >= off) ? sd[t - off] : 0;
    __syncthreads();
    sd[t] += add;
    __syncthreads();
  }
  blockOff[t] = sd[t] - v;
  if (t == 127) rowptr[N_NODES] = sd[t];
}

__global__ __launch_bounds__(256) void k_scan3(const int* __restrict__ partial,
                                               const int* __restrict__ blockOff,
                                               int* __restrict__ rowptr,
                                               int* __restrict__ fill,
                                               int* __restrict__ col) {
  int i = blockIdx.x * 256 + threadIdx.x;
  int rp = partial[i] + blockOff[blockIdx.x];
  rowptr[i] = rp;
  fill[i] = 1;
  col[rp] = i;
}

__global__ void k_scatter(const int* __restrict__ src, const int* __restrict__ dst,
                          const int* __restrict__ rowptr, int* __restrict__ fill,
                          int* __restrict__ col, int E) {
  int i = blockIdx.x * 256 + threadIdx.x;
  if (i < E) {
    int d = dst[i];
    int pos = rowptr[d] + atomicAdd(&fill[d], 1);
    col[pos] = src[i];
  }
}

// ---------------- fused conversions + deg init ----------------
__global__ void k_convert(
    const float* __restrict__ x,  half_t* __restrict__ x_h,
    const float* __restrict__ W1, half_t* __restrict__ W1t,
    const float* __restrict__ W2, half_t* __restrict__ W2t,
    const float* __restrict__ W3, half_t* __restrict__ W3t,
    const float* __restrict__ Wi, half_t* __restrict__ Wi_h,
    const float* __restrict__ Wo, half_t* __restrict__ Wo_h,
    int* __restrict__ deg)
{
  int bid = blockIdx.x, t = threadIdx.x;
  if (bid < 16384) {
    int i = bid * 256 + t;
    x_h[i] = (half_t)x[i];
  } else if (bid < 16512) {
    int i = (bid - 16384) * 256 + t;
    int o = i >> 7, k = i & 127;
    W1t[i] = (half_t)W1[k * 256 + o];
  } else if (bid < 16768) {
    int i = (bid - 16512) * 256 + t;
    int o = i >> 8, k = i & 255;
    W2t[i] = (half_t)W2[k * 256 + o];
  } else if (bid < 16896) {
    int i = (bid - 16768) * 256 + t;
    int o = i >> 8, k = i & 255;
    W3t[i] = (half_t)W3[k * 128 + o];
  } else if (bid < 17664) {
    int i = (bid - 16896) * 256 + t;
    Wi_h[i] = (half_t)Wi[i];
  } else if (bid < 17920) {
    int i = (bid - 17664) * 256 + t;
    Wo_h[i] = (half_t)Wo[i];
  } else {
    deg[(bid - 17920) * 256 + t] = 1;
  }
}

// ---------------- residency-first GEMM body (tile 128x64, BK=64) ----------------
__device__ __forceinline__ void gemm_wide_body(
    int bx, int by,
    const half_t* __restrict__ A, const half_t* __restrict__ Bt,
    const float* __restrict__ bias, int bias_per_row,
    half_t* __restrict__ outh, int Nc, int K,
    half_t* As, half_t* Bs)
{
  int w = threadIdx.x >> 6, lane = threadIdx.x & 63;
  int r = lane & 15, q = lane >> 4;
  int m0 = by * 128, n0 = bx * 64;
  int mh = (w & 1) * 64, nh = (w >> 1) * 32;
  f32x4 acc[4][2];
  #pragma unroll
  for (int i = 0; i < 4; i++)
    #pragma unroll
    for (int j = 0; j < 2; j++) acc[i][j] = f32x4{0.f, 0.f, 0.f, 0.f};

  int srow = lane >> 3, sc = lane & 7;

  for (int k0 = 0; k0 < K; k0 += 64) {
    __syncthreads();
    #pragma unroll
    for (int i = 0; i < 4; i++) {
      int R0 = w * 32 + i * 8;
      int row = R0 + srow;
      int cg = sc ^ (row & 7);
      gload_lds16(A + (size_t)(m0 + row) * K + k0 + cg * 8, &As[R0 * 64]);
    }
    #pragma unroll
    for (int i = 0; i < 2; i++) {
      int R0 = w * 16 + i * 8;
      int row = R0 + srow;
      int cg = sc ^ (row & 7);
      gload_lds16(Bt + (size_t)(n0 + row) * K + k0 + cg * 8, &Bs[R0 * 64]);
    }
    __syncthreads();
    #pragma unroll
    for (int kk = 0; kk < 2; kk++) {
      half8 af[4], bf[2];
      #pragma unroll
      for (int t = 0; t < 4; t++) {
        int rr = mh + t * 16 + r;
        af[t] = *(const half8*)&As[rr * 64 + (((kk * 4 + q) ^ (rr & 7)) << 3)];
      }
      #pragma unroll
      for (int t = 0; t < 2; t++) {
        int rr = nh + t * 16 + r;
        bf[t] = *(const half8*)&Bs[rr * 64 + (((kk * 4 + q) ^ (rr & 7)) << 3)];
      }
      #pragma unroll
      for (int ti = 0; ti < 4; ti++)
        #pragma unroll
        for (int tj = 0; tj < 2; tj++)
          acc[ti][tj] = MFMA16(af[ti], bf[tj], acc[ti][tj]);
    }
  }

  #pragma unroll
  for (int tj = 0; tj < 2; tj++) {
    int colc = n0 + nh + tj * 16 + r;
    float bc = bias_per_row ? 0.f : bias[colc];
    #pragma unroll
    for (int ti = 0; ti < 4; ti++) {
      #pragma unroll
      for (int i = 0; i < 4; i++) {
        int row = m0 + mh + ti * 16 + q * 4 + i;
        float bv = bias_per_row ? bias[row] : bc;
        outh[(size_t)row * Nc + colc] = (half_t)(acc[ti][tj][i] + bv);
      }
    }
  }
}

// merged QK-projection (2048 blocks) + V^T-projection (1024 blocks): the two
// GEMMs are independent -> one launch overlaps their tails.
__global__ __launch_bounds__(256) void k_gemm_qkv2(
    const half_t* __restrict__ x2, const half_t* __restrict__ Wi_h,
    const float* __restrict__ bi,
    half_t* __restrict__ qk, half_t* __restrict__ vt)
{
  __shared__ __align__(16) half_t As[128 * 64];
  __shared__ __align__(16) half_t Bs[64 * 64];
  int id = blockIdx.x;
  if (id < 2048) {
    // QK: C[32768,512] = x2 @ Wi[0:512]^T, bias per-col
    gemm_wide_body(id & 7, id >> 3, x2, Wi_h, bi, 0, qk, 512, 256, As, Bs);
  } else {
    int id2 = id - 2048;
    // V^T: C[256,32768] = Wv @ x2^T, bias per-row
    gemm_wide_body(id2 & 511, id2 >> 9, Wi_h + 512 * 256, x2, bi + 512, 1,
                   vt, 32768, 256, As, Bs);
  }
}

// ---------------- residency-first GAT GEMM: 128x64 tile + fused es/ed ----------------
template<int NC, int H, bool FP8O>
__global__ __launch_bounds__(256) void k_gemm_gat(
    const half_t* __restrict__ A, const half_t* __restrict__ Bt,
    half_t* __restrict__ outh, unsigned char* __restrict__ out8, int K,
    const float* __restrict__ aS, const float* __restrict__ aD,
    float* __restrict__ es, float* __restrict__ ed)
{
  __shared__ __align__(16) half_t As[128 * 64];
  __shared__ __align__(16) half_t Bs[64 * 64];
  __shared__ float sRed[2][4][64];
  int w = threadIdx.x >> 6, lane = threadIdx.x & 63;
  int cc = lane & 15, qq = lane >> 4;
  int m0 = blockIdx.y * 128, n0 = blockIdx.x * 64;
  int mh = (w & 1) * 64, nh = (w >> 1) * 32;
  f32x4 acc[4][2];
  #pragma unroll
  for (int i = 0; i < 4; i++)
    #pragma unroll
    for (int j = 0; j < 2; j++) acc[i][j] = f32x4{0.f, 0.f, 0.f, 0.f};

  int srow = lane >> 3, sc = lane & 7;

  for (int k0 = 0; k0 < K; k0 += 64) {
    __syncthreads();
    #pragma unroll
    for (int i = 0; i < 4; i++) {
      int R0 = w * 32 + i * 8;
      int row = R0 + srow;
      int cg = sc ^ (row & 7);
      gload_lds16(A + (size_t)(m0 + row) * K + k0 + cg * 8, &As[R0 * 64]);
    }
    #pragma unroll
    for (int i = 0; i < 2; i++) {
      int R0 = w * 16 + i * 8;
      int row = R0 + srow;
      int cg = sc ^ (row & 7);
      gload_lds16(Bt + (size_t)(n0 + row) * K + k0 + cg * 8, &Bs[R0 * 64]);
    }
    __syncthreads();
    #pragma unroll
    for (int kk = 0; kk < 2; kk++) {
      half8 af[4], bf[2];
      #pragma unroll
      for (int t = 0; t < 4; t++) {
        int rr = mh + t * 16 + cc;
        af[t] = *(const half8*)&As[rr * 64 + (((kk * 4 + qq) ^ (rr & 7)) << 3)];
      }
      #pragma unroll
      for (int t = 0; t < 2; t++) {
        int rr = nh + t * 16 + cc;
        bf[t] = *(const half8*)&Bs[rr * 64 + (((kk * 4 + qq) ^ (rr & 7)) << 3)];
      }
      #pragma unroll
      for (int ti = 0; ti < 4; ti++)
        #pragma unroll
        for (int tj = 0; tj < 2; tj++)
          acc[ti][tj] = MFMA16(af[ti], bf[tj], acc[ti][tj]);
    }
  }

  float aSv[2], aDv[2];
  #pragma unroll
  for (int tj = 0; tj < 2; tj++) {
    int colg = n0 + nh + tj * 16 + cc;
    aSv[tj] = aS[colg];
    aDv[tj] = aD[colg];
  }
  #pragma unroll
  for (int ti = 0; ti < 4; ti++) {
    #pragma unroll
    for (int i = 0; i < 4; i++) {
      int rloc = mh + ti * 16 + qq * 4 + i;      // 0..127
      float ps = 0.f, pd = 0.f;
      #pragma unroll
      for (int tj = 0; tj < 2; tj++) {
        int colg = n0 + nh + tj * 16 + cc;
        float v = acc[ti][tj][i];
        if (FP8O) {
          int pk = __builtin_amdgcn_cvt_pk_fp8_f32(v, v, 0, false);
          out8[(size_t)(m0 + rloc) * NC + colg] = (unsigned char)pk;
        } else {
          outh[(size_t)(m0 + rloc) * NC + colg] = (half_t)v;
        }
        ps += v * aSv[tj];
        pd += v * aDv[tj];
      }
      #pragma unroll
      for (int off = 1; off < 16; off <<= 1) {
        ps += __shfl_xor(ps, off);
        pd += __shfl_xor(pd, off);
      }
      if (cc == 0) {
        sRed[0][w][ti * 16 + qq * 4 + i] = ps;
        sRed[1][w][ti * 16 + qq * 4 + i] = pd;
      }
    }
  }
  __syncthreads();
  if (threadIdx.x < 128) {
    int row = threadIdx.x;
    int wlo = row >> 6, ri = row & 63;
    float ps = sRed[0][wlo][ri] + sRed[0][wlo + 2][ri];
    float pd = sRed[1][wlo][ri] + sRed[1][wlo + 2][ri];
    if (H == 4) {
      int head = n0 >> 6;
      es[(size_t)(m0 + row) * 4 + head] = ps;
      ed[(size_t)(m0 + row) * 4 + head] = pd;
    } else {
      atomicAdd(&es[m0 + row], ps);
      atomicAdd(&ed[m0 + row], pd);
    }
  }
}

// ---------------- fused Wo-GEMM + residual + LayerNorm (+ es/ed zeroing) ----------------
__global__ __launch_bounds__(256) void k_gemm_ln(
    const half_t* __restrict__ A, const half_t* __restrict__ Bt,
    const float* __restrict__ bias, const half_t* __restrict__ res,
    const float* __restrict__ gamma, const float* __restrict__ beta,
    half_t* __restrict__ outh, float* __restrict__ es0, float* __restrict__ ed0)
{
  __shared__ __align__(16) half_t As[64 * 64];
  __shared__ __align__(16) half_t Bs[256 * 64];
  __shared__ float sSum[4][64], sSq[4][64];
  __shared__ float sMR[64][2];
  int w = threadIdx.x >> 6, lane = threadIdx.x & 63;
  int r = lane & 15, q = lane >> 4;
  int m0 = blockIdx.x * 64;
  int nh = w * 64;

  if (threadIdx.x < 64) es0[m0 + threadIdx.x] = 0.f;
  else if (threadIdx.x < 128) ed0[m0 + threadIdx.x - 64] = 0.f;

  f32x4 acc[4][4];
  #pragma unroll
  for (int i = 0; i < 4; i++)
    #pragma unroll
    for (int j = 0; j < 4; j++) acc[i][j] = f32x4{0.f, 0.f, 0.f, 0.f};

  int srow = lane >> 3, sc = lane & 7;

  for (int k0 = 0; k0 < 256; k0 += 64) {
    __syncthreads();
    #pragma unroll
    for (int i = 0; i < 2; i++) {
      int R0 = w * 16 + i * 8;
      int row = R0 + srow;
      int cg = sc ^ (row & 7);
      gload_lds16(A + (size_t)(m0 + row) * 256 + k0 + cg * 8, &As[R0 * 64]);
    }
    #pragma unroll
    for (int i = 0; i < 8; i++) {
      int R0 = w * 64 + i * 8;
      int row = R0 + srow;
      int cg = sc ^ (row & 7);
      gload_lds16(Bt + (size_t)row * 256 + k0 + cg * 8, &Bs[R0 * 64]);
    }
    __syncthreads();
    #pragma unroll
    for (int kk = 0; kk < 2; kk++) {
      half8 af[4], bf[4];
      #pragma unroll
      for (int t = 0; t < 4; t++) {
        int rr = t * 16 + r;
        af[t] = *(const half8*)&As[rr * 64 + (((kk * 4 + q) ^ (rr & 7)) << 3)];
      }
      #pragma unroll
      for (int t = 0; t < 4; t++) {
        int rr = nh + t * 16 + r;
        bf[t] = *(const half8*)&Bs[rr * 64 + (((kk * 4 + q) ^ (rr & 7)) << 3)];
      }
      #pragma unroll
      for (int ti = 0; ti < 4; ti++)
        #pragma unroll
        for (int tj = 0; tj < 4; tj++)
          acc[ti][tj] = MFMA16(af[ti], bf[tj], acc[ti][tj]);
    }
  }

  float gv[4], bv[4];
  #pragma unroll
  for (int tj = 0; tj < 4; tj++) {
    int col = nh + tj * 16 + r;
    gv[tj] = gamma[col];
    bv[tj] = beta[col];
  }
  #pragma unroll
  for (int ti = 0; ti < 4; ti++) {
    #pragma unroll
    for (int i = 0; i < 4; i++) {
      int row = ti * 16 + q * 4 + i;
      float s = 0.f, ss = 0.f;
      #pragma unroll
      for (int tj = 0; tj < 4; tj++) {
        int col = nh + tj * 16 + r;
        float v = acc[ti][tj][i] + bias[col]
                + (float)res[(size_t)(m0 + row) * 256 + col];
        acc[ti][tj][i] = v;
        s += v;
        ss += v * v;
      }
      #pragma unroll
      for (int off = 1; off < 16; off <<= 1) {
        s  += __shfl_xor(s, off);
        ss += __shfl_xor(ss, off);
      }
      if (r == 0) { sSum[w][row] = s; sSq[w][row] = ss; }
    }
  }
  __syncthreads();
  if (threadIdx.x < 64) {
    int row = threadIdx.x;
    float s  = sSum[0][row] + sSum[1][row] + sSum[2][row] + sSum[3][row];
    float ss = sSq[0][row] + sSq[1][row] + sSq[2][row] + sSq[3][row];
    float mean = s * (1.f / 256.f);
    float var  = ss * (1.f / 256.f) - mean * mean;
    sMR[row][0] = mean;
    sMR[row][1] = rsqrtf(var + 1e-5f);
  }
  __syncthreads();
  #pragma unroll
  for (int ti = 0; ti < 4; ti++) {
    #pragma unroll
    for (int i = 0; i < 4; i++) {
      int row = ti * 16 + q * 4 + i;
      float mean = sMR[row][0], rstd = sMR[row][1];
      #pragma unroll
      for (int tj = 0; tj < 4; tj++) {
        int col = nh + tj * 16 + r;
        outh[(size_t)(m0 + row) * 256 + col] =
            (half_t)((acc[ti][tj][i] - mean) * rstd * gv[tj] + bv[tj]);
      }
    }
  }
}

// ---------------- fp16-gather aggregation (HC=256, H=4, fp16 acc, ELU) ----------------
__global__ __launch_bounds__(256) void k_agg_f16(
    const half_t* __restrict__ h, const float* __restrict__ es,
    const float* __restrict__ ed, const float* __restrict__ bias,
    const int* __restrict__ rowptr, const int* __restrict__ col,
    half_t* __restrict__ outh)
{
  int lane = threadIdx.x & 63;
  int g = lane >> 4, li = lane & 15;
  int n = blockIdx.x * 4 + (threadIdx.x >> 6);
  int cbase = li * 16;
  int hl = li >> 2;
  float edn = ed[(size_t)n * 4 + hl];
  int j0 = rowptr[n], j1 = rowptr[n + 1];
  const half_t* hb = h + cbase;

  float sum0 = 0.f, sum1 = 0.f;
  half8 acc0[2], acc1[2];
  #pragma unroll
  for (int i = 0; i < 2; i++) {
    acc0[i] = half8{0, 0, 0, 0, 0, 0, 0, 0};
    acc1[i] = half8{0, 0, 0, 0, 0, 0, 0, 0};
  }
  for (int j = j0 + g; j < j1; j += 8) {
    int jb = j + 4;
    int s0 = col[j];
    int s1 = col[(jb < j1) ? jb : j];
    float e0 = es[(size_t)s0 * 4 + hl] + edn;
    e0 = fmaxf(e0, 0.2f * e0);
    float e1 = es[(size_t)s1 * 4 + hl] + edn;
    e1 = fmaxf(e1, 0.2f * e1);
    e1 = (jb < j1) ? e1 : -1e30f;
    const half_t* hp0 = hb + (size_t)s0 * 256;
    const half_t* hp1 = hb + (size_t)s1 * 256;
    float p0 = exp2f(e0 * 1.44269504f - 8.65617025f);
    float p1 = exp2f(e1 * 1.44269504f - 8.65617025f);
    sum0 += p0; sum1 += p1;
    half_t q0 = (half_t)p0, q1 = (half_t)p1;
    half8 pv0 = {q0, q0, q0, q0, q0, q0, q0, q0};
    half8 pv1 = {q1, q1, q1, q1, q1, q1, q1, q1};
    #pragma unroll
    for (int i = 0; i < 2; i++) {
      half8 v0 = *(const half8*)(hp0 + i * 8);
      half8 v1 = *(const half8*)(hp1 + i * 8);
      acc0[i] += pv0 * v0;
      acc1[i] += pv1 * v1;
    }
  }
  float sum = sum0 + sum1;
  sum += __shfl_xor(sum, 16);
  sum += __shfl_xor(sum, 32);
  float av[16];
  #pragma unroll
  for (int i = 0; i < 16; i++) {
    av[i] = (float)acc0[i >> 3][i & 7] + (float)acc1[i >> 3][i & 7];
    av[i] += __shfl_xor(av[i], 16);
    av[i] += __shfl_xor(av[i], 32);
  }
  float inv = 1.f / sum;
  if (g == 0) {
    size_t obase = (size_t)n * 256 + cbase;
    #pragma unroll
    for (int p8 = 0; p8 < 2; p8++) {
      half8 hv;
      #pragma unroll
      for (int i = 0; i < 8; i++) {
        float t = av[p8 * 8 + i] * inv + bias[cbase + p8 * 8 + i];
        t = (t > 0.f) ? t : __expf(t) - 1.f;     // jax.nn.elu
        hv[i] = (half_t)t;
      }
      *(half8*)(outh + obase + p8 * 8) = hv;
    }
  }
}

// ---------------- fp8-gather aggregation (HC=256, H=4, ELU) ----------------
__global__ __launch_bounds__(256) void k_agg_fp8(
    const unsigned char* __restrict__ hq, const float* __restrict__ es,
    const float* __restrict__ ed, const float* __restrict__ bias,
    const int* __restrict__ rowptr, const int* __restrict__ col,
    half_t* __restrict__ outh)
{
  int lane = threadIdx.x & 63;
  int g = lane >> 4, li = lane & 15;
  int n = blockIdx.x * 4 + (threadIdx.x >> 6);
  int cbase = li * 16;
  int hl = li >> 2;
  float edn = ed[(size_t)n * 4 + hl];
  int j0 = rowptr[n], j1 = rowptr[n + 1];
  const unsigned char* hb = hq + cbase;

  float sum0 = 0.f, sum1 = 0.f;
  half2v a0[8], a1[8];
  #pragma unroll
  for (int i = 0; i < 8; i++) { a0[i] = half2v{0, 0}; a1[i] = half2v{0, 0}; }

  for (int j = j0 + g; j < j1; j += 8) {
    int jb = j + 4;
    int s0 = col[j];
    int s1 = col[(jb < j1) ? jb : j];
    float e0 = es[(size_t)s0 * 4 + hl] + edn;
    e0 = fmaxf(e0, 0.2f * e0);
    float e1 = es[(size_t)s1 * 4 + hl] + edn;
    e1 = fmaxf(e1, 0.2f * e1);
    e1 = (jb < j1) ? e1 : -1e30f;
    int4 d0 = *(const int4*)(hb + (size_t)s0 * 256);
    int4 d1 = *(const int4*)(hb + (size_t)s1 * 256);
    float p0 = exp2f(e0 * 1.44269504f - 8.65617025f);
    float p1 = exp2f(e1 * 1.44269504f - 8.65617025f);
    sum0 += p0; sum1 += p1;
    half_t q0 = (half_t)p0, q1 = (half_t)p1;
    half2v pv0 = {q0, q0}, pv1 = {q1, q1};
    fp8x4_fma(d0.x, pv0, &a0[0]); fp8x4_fma(d0.y, pv0, &a0[2]);
    fp8x4_fma(d0.z, pv0, &a0[4]); fp8x4_fma(d0.w, pv0, &a0[6]);
    fp8x4_fma(d1.x, pv1, &a1[0]); fp8x4_fma(d1.y, pv1, &a1[2]);
    fp8x4_fma(d1.z, pv1, &a1[4]); fp8x4_fma(d1.w, pv1, &a1[6]);
  }

  float sum = sum0 + sum1;
  sum += __shfl_xor(sum, 16);
  sum += __shfl_xor(sum, 32);
  float av[16];
  #pragma unroll
  for (int i = 0; i < 16; i++) {
    av[i] = (float)a0[i >> 1][i & 1] + (float)a1[i >> 1][i & 1];
    av[i] += __shfl_xor(av[i], 16);
    av[i] += __shfl_xor(av[i], 32);
  }
  float inv = 1.f / sum;
  if (g == 0) {
    size_t obase = (size_t)n * 256 + cbase;
    #pragma unroll
    for (int p8 = 0; p8 < 2; p8++) {
      half8 hv;
      #pragma unroll
      for (int i = 0; i < 8; i++) {
        float t = av[p8 * 8 + i] * inv + bias[cbase + p8 * 8 + i];
        t = (t > 0.f) ? t : __expf(t) - 1.f;
        hv[i] = (half_t)t;
      }
      *(half8*)(outh + obase + p8 * 8) = hv;
    }
  }
}

// ---------------- fp16-gather aggregation (GAT3: HC=128, H=1, fp32 acc) ----------------
__global__ __launch_bounds__(256) void k_agg3(
    const half_t* __restrict__ h, const float* __restrict__ es,
    const float* __restrict__ ed, const float* __restrict__ bias,
    const int* __restrict__ rowptr, const int* __restrict__ col,
    float* __restrict__ outf)
{
  constexpr int VPT = 8;
  int lane = threadIdx.x & 63;
  int g = lane >> 4, li = lane & 15;
  int n = blockIdx.x * 4 + (threadIdx.x >> 6);
  int cbase = li * VPT;
  float edn = ed[n];
  int j0 = rowptr[n], j1 = rowptr[n + 1];
  const half_t* hb = h + cbase;

  float sum0 = 0.f, sum1 = 0.f;
  float acc0[VPT], acc1[VPT];
  #pragma unroll
  for (int i = 0; i < VPT; i++) { acc0[i] = 0.f; acc1[i] = 0.f; }
  for (int j = j0 + g; j < j1; j += 8) {
    int jb = j + 4;
    int s0 = col[j];
    int s1 = col[(jb < j1) ? jb : j];
    float e0 = es[s0] + edn;
    e0 = fmaxf(e0, 0.2f * e0);
    float e1 = es[s1] + edn;
    e1 = fmaxf(e1, 0.2f * e1);
    e1 = (jb < j1) ? e1 : -1e30f;
    const half_t* hp0 = hb + (size_t)s0 * 128;
    const half_t* hp1 = hb + (size_t)s1 * 128;
    float p0 = __expf(e0), p1 = __expf(e1);
    sum0 += p0; sum1 += p1;
    half8 v0 = *(const half8*)hp0;
    half8 v1 = *(const half8*)hp1;
    #pragma unroll
    for (int i = 0; i < 8; i++) {
      acc0[i] += p0 * (float)v0[i];
      acc1[i] += p1 * (float)v1[i];
    }
  }
  float sum = sum0 + sum1;
  sum += __shfl_xor(sum, 16);
  sum += __shfl_xor(sum, 32);
  float av[VPT];
  #pragma unroll
  for (int i = 0; i < VPT; i++) {
    av[i] = acc0[i] + acc1[i];
    av[i] += __shfl_xor(av[i], 16);
    av[i] += __shfl_xor(av[i], 32);
  }
  float inv = 1.f / sum;
  if (g == 0) {
    size_t obase = (size_t)n * 128 + cbase;
    #pragma unroll
    for (int p4 = 0; p4 < 2; p4++) {
      float4 fv = {av[p4 * 4] * inv + bias[cbase + p4 * 4],
                   av[p4 * 4 + 1] * inv + bias[cbase + p4 * 4 + 1],
                   av[p4 * 4 + 2] * inv + bias[cbase + p4 * 4 + 2],
                   av[p4 * 4 + 3] * inv + bias[cbase + p4 * 4 + 3]};
      *(float4*)(outf + obase + p4 * 4) = fv;
    }
  }
}

// ---------------- MHA core (R9 known-good: 64-key tiles, 25 KB LDS) ----------------
__global__ __launch_bounds__(256) void k_attn(
    const half_t* __restrict__ qk, const half_t* __restrict__ vt,
    half_t* __restrict__ o)
{
  __shared__ __align__(16) half_t Kt[64 * 64];
  __shared__ __align__(16) half_t Vt[64 * 64];
  __shared__ __align__(16) half_t Pb[4][16][72];

  int pair = blockIdx.x;
  int b = pair >> 2, hh = pair & 3;
  int q0 = blockIdx.y * 64;
  int w = threadIdx.x >> 6, lane = threadIdx.x & 63;
  int cc = lane & 15, qq = lane >> 4;

  const half_t* Qp = qk + ((size_t)(b * NPG_ + q0 + w * 16 + cc) * 512 + hh * 64);
  half8 qa0 = *(const half8*)(Qp + qq * 8);
  half8 qa1 = *(const half8*)(Qp + 32 + qq * 8);

  f32x4 oacc[4];
  #pragma unroll
  for (int t = 0; t < 4; t++) oacc[t] = f32x4{0.f, 0.f, 0.f, 0.f};
  float rs = 0.f;

  const half_t* kb = qk + ((size_t)(b * NPG_) * 512 + 256 + hh * 64);
  const half_t* vb = vt + ((size_t)(hh * 64) * 32768 + b * NPG_);

  int krow = lane >> 3, ksl = lane & 7;

  for (int kt = 0; kt < 8; kt++) {
    __syncthreads();
    #pragma unroll
    for (int i = 0; i < 2; i++) {
      int R = w * 16 + i * 8;
      int kr = R + krow;
      gload_lds16(kb + (size_t)(kt * 64 + kr) * 512 + ((ksl ^ (kr & 7)) * 8),
                  &Kt[R * 64]);
      gload_lds16(vb + (size_t)kr * 32768 + kt * 64 + ((ksl ^ (kr & 7)) * 8),
                  &Vt[R * 64]);
    }
    __syncthreads();

    #pragma unroll
    for (int mt = 0; mt < 4; mt++) {
      int key = mt * 16 + cc;
      half8 k0 = *(const half8*)&Kt[key * 64 + ((qq ^ (key & 7)) << 3)];
      half8 k1 = *(const half8*)&Kt[key * 64 + (((qq + 4) ^ (key & 7)) << 3)];
      f32x4 s = f32x4{0.f, 0.f, 0.f, 0.f};
      s = MFMA16(k0, qa0, s);
      s = MFMA16(k1, qa1, s);
      half4v ph;
      #pragma unroll
      for (int i = 0; i < 4; i++) {
        float p = exp2f(s[i] * 0.180336886f - 11.54156033f);
        rs += p;
        ph[i] = (half_t)p;
      }
      *(half4v*)&Pb[w][cc][mt * 16 + qq * 4] = ph;
    }

    #pragma unroll
    for (int kc = 0; kc < 2; kc++) {
      half8 a = *(const half8*)&Pb[w][cc][kc * 32 + qq * 8];
      #pragma unroll
      for (int nt = 0; nt < 4; nt++) {
        int d = nt * 16 + cc;
        half8 bb = *(const half8*)&Vt[d * 64 + (((kc * 4 + qq) ^ (d & 7)) << 3)];
        oacc[nt] = MFMA16(a, bb, oacc[nt]);
      }
    }
  }

  rs += __shfl_xor(rs, 16);
  rs += __shfl_xor(rs, 32);
  #pragma unroll
  for (int i = 0; i < 4; i++) {
    float rsv = __shfl(rs, qq * 4 + i);
    float inv = 1.f / rsv;
    int node = b * NPG_ + q0 + w * 16 + qq * 4 + i;
    #pragma unroll
    for (int nt = 0; nt < 4; nt++)
      o[(size_t)node * 256 + hh * 64 + nt * 16 + cc] = (half_t)(oacc[nt][i] * inv);
  }
}

// ---------------- host ----------------
extern "C" void kernel_launch(void* const* d_in, const int* in_sizes, int n_in,
                              void* d_out, int out_size, void* d_ws, size_t ws_size,
                              hipStream_t stream)
{
  const float* x    = (const float*)d_in[0];
  const int*   ei   = (const int*)d_in[1];
  const float* W1   = (const float*)d_in[3];
  const float* aS1  = (const float*)d_in[4];
  const float* aD1  = (const float*)d_in[5];
  const float* b1   = (const float*)d_in[6];
  const float* W2   = (const float*)d_in[7];
  const float* aS2  = (const float*)d_in[8];
  const float* aD2  = (const float*)d_in[9];
  const float* b2   = (const float*)d_in[10];
  const float* W3   = (const float*)d_in[11];
  const float* aS3  = (const float*)d_in[12];
  const float* aD3  = (const float*)d_in[13];
  const float* b3   = (const float*)d_in[14];
  const float* Wi   = (const float*)d_in[15];
  const float* bi   = (const float*)d_in[16];
  const float* Wo   = (const float*)d_in[17];
  const float* bo   = (const float*)d_in[18];
  const float* gam  = (const float*)d_in[19];
  const float* bet  = (const float*)d_in[20];
  float* out = (float*)d_out;
  const int N = N_NODES;
  int E = in_sizes[1] / 2;

  char* ws = (char*)d_ws;
  size_t off = 0;
  auto alloc = [&](size_t bytes) -> void* {
    void* p = ws + off;
    off = (off + bytes + 255) & ~(size_t)255;
    return p;
  };
  half_t* x_h    = (half_t*)alloc((size_t)N * 128 * 2);
  half_t* h_h    = (half_t*)alloc((size_t)N * 256 * 2);   // h1 / h3 (fp16)
  unsigned char* hq = (unsigned char*)alloc((size_t)N * 256);  // h2 (fp8)
  half_t* x1_h   = (half_t*)alloc((size_t)N * 256 * 2);
  half_t* x2_h   = (half_t*)alloc((size_t)N * 256 * 2);
  half_t* qk_h   = (half_t*)alloc((size_t)N * 512 * 2);
  half_t* vt_h   = (half_t*)alloc((size_t)256 * N * 2);   // V^T: [256][32768]
  half_t* o_h    = (half_t*)alloc((size_t)N * 256 * 2);
  half_t* x2a_h  = (half_t*)alloc((size_t)N * 256 * 2);
  half_t* W1t    = (half_t*)alloc(256 * 128 * 2);
  half_t* W2t    = (half_t*)alloc(256 * 256 * 2);
  half_t* W3t    = (half_t*)alloc(128 * 256 * 2);
  half_t* Wi_h   = (half_t*)alloc(768 * 256 * 2);
  half_t* Wo_h   = (half_t*)alloc(256 * 256 * 2);
  float*  es     = (float*) alloc((size_t)N * 4 * 4);
  float*  ed     = (float*) alloc((size_t)N * 4 * 4);
  int*    deg    = (int*)   alloc((size_t)N * 4);
  int*    fill   = (int*)   alloc((size_t)N * 4);
  int*    rowptr = (int*)   alloc(((size_t)N + 1) * 4);
  int*    col    = (int*)   alloc((size_t)(N + E) * 4);
  int*    part   = (int*)   alloc((size_t)N * 4);
  int*    bsum   = (int*)   alloc(128 * 4);
  int*    boff   = (int*)   alloc(128 * 4);

  const int* srcE = ei;
  const int* dstE = ei + E;

  // conversions + deg init (one launch), then parallel CSR build
  k_convert<<<18048, 256, 0, stream>>>(x, x_h, W1, W1t, W2, W2t, W3, W3t,
                                       Wi, Wi_h, Wo, Wo_h, deg);
  k_hist<<<(E + 255) / 256, 256, 0, stream>>>(dstE, deg, E);
  k_scan1<<<128, 256, 0, stream>>>(deg, part, bsum);
  k_scan2<<<1, 128, 0, stream>>>(bsum, boff, rowptr);
  k_scan3<<<128, 256, 0, stream>>>(part, boff, rowptr, fill, col);
  k_scatter<<<(E + 255) / 256, 256, 0, stream>>>(srcE, dstE, rowptr, fill, col, E);

  // ---- GAT1 (fp16 path): h1 + es/ed ; fp16 aggregate + ELU -> x1 ----
  k_gemm_gat<256, 4, false><<<dim3(4, N / 128), 256, 0, stream>>>(
      x_h, W1t, h_h, nullptr, 128, aS1, aD1, es, ed);
  k_agg_f16<<<N / 4, 256, 0, stream>>>(h_h, es, ed, b1, rowptr, col, x1_h);

  // ---- GAT2 (fp8 gather path): h2 (fp8) + es/ed ; fp8 aggregate -> x2 ----
  k_gemm_gat<256, 4, true><<<dim3(4, N / 128), 256, 0, stream>>>(
      x1_h, W2t, nullptr, hq, 256, aS2, aD2, es, ed);
  k_agg_fp8<<<N / 4, 256, 0, stream>>>(hq, es, ed, b2, rowptr, col, x2_h);

  // ---- MHA: merged QK + V^T projections (independent -> one launch) ----
  k_gemm_qkv2<<<3072, 256, 0, stream>>>(x2_h, Wi_h, bi, qk_h, vt_h);
  k_attn<<<dim3(256, 8), 256, 0, stream>>>(qk_h, vt_h, o_h);

  // ---- Wo-GEMM + residual + LayerNorm fused -> x2a; also zeroes es/ed ----
  k_gemm_ln<<<N / 64, 256, 0, stream>>>(o_h, Wo_h, bo, x2_h, gam, bet, x2a_h, es, ed);

  // ---- GAT3 (H=1, C=128, fp16 h, fp32 acc; atomic es/ed partials) -> d_out ----
  k_gemm_gat<128, 1, false><<<dim3(2, N / 128), 256, 0, stream>>>(
      x2a_h, W3t, h_h, nullptr, 256, aS3, aD3, es, ed);
  k_agg3<<<N / 4, 256, 0, stream>>>(h_h, es, ed, b3, rowptr, col, out);
}